// Round 1
// baseline (284.796 us; speedup 1.0000x reference)
//
#include <hip/hip_runtime.h>

// Problem: B=4, N=2048, C=256, H=4, d=64
// Pipeline: wconv -> gemm(q) -> gemm(k) -> gemm(vt) -> flash_attn -> energy ->
//           chan_softmax -> assemble_x -> gemm_proj
// Workspace layout (bytes):
//   Qb   bf16 [16][2048][64]   @ 0        (4 MB)
//   Kb   bf16 [16][2048][64]   @ 4 MB     (4 MB)
//   Vt   bf16 [16][64][2048]   @ 8 MB     (4 MB)
//   Xf   bf16 [8192][256]      @ 12 MB    (4 MB)
//   AO   f32  [16][2048][64]   @ 16 MB    (8 MB)
//   Wqt  bf16 [256][256]       @ 24 MB
//   Wkvt bf16 [768... 512][256]@ 24 MB+128K
//   Wpt  bf16 [256][256]       @ 24 MB+384K
//   energy f32 [4][64][64]     @ 24 MB+512K
//   attnc  f32 [4][64][64]     @ 24 MB+576K
// Total ~24.7 MB.

typedef __attribute__((ext_vector_type(8))) short short8_t;
typedef __attribute__((ext_vector_type(4))) float f32x4;

#define NSEQ 2048
#define NROW 8192
#define ATT_SCALE 0.125f

static __device__ __forceinline__ short f2bf(float f) {
  union { float f; unsigned u; } v; v.f = f;
  unsigned u = v.u;
  unsigned r = (u + 0x7FFFu + ((u >> 16) & 1u)) >> 16;
  return (short)r;
}
static __device__ __forceinline__ float bf2f(short s) {
  union { unsigned u; float f; } v;
  v.u = ((unsigned)(unsigned short)s) << 16;
  return v.f;
}

// ---------------------------------------------------------------- weights
__global__ __launch_bounds__(256) void wconv(
    const float* __restrict__ Wq, const float* __restrict__ Wkv,
    const float* __restrict__ Wp, short* __restrict__ Wqt,
    short* __restrict__ Wkvt, short* __restrict__ Wpt) {
  int tid = blockIdx.x * 256 + threadIdx.x;
  if (tid < 65536) {
    int n = tid >> 8, k = tid & 255;
    Wqt[tid] = f2bf(Wq[k * 256 + n]);
  } else if (tid < 196608) {
    int i = tid - 65536;
    int n = i >> 8, k = i & 255;
    Wkvt[i] = f2bf(Wkv[k * 512 + n]);
  } else {
    int i = tid - 196608;
    int n = i >> 8, k = i & 255;
    Wpt[i] = f2bf(Wp[k * 256 + n]);
  }
}

// ------------------------------------------------- q/k GEMM: (8192x256)@(256x256)
// A f32 row-major, Bt bf16 [n][k]; out written to [b*4+h][n][d] bf16
__global__ __launch_bounds__(256) void gemm_rowout(
    const float* __restrict__ A, const short* __restrict__ Bt,
    short* __restrict__ Ob) {
  int w = threadIdx.x >> 6, l = threadIdx.x & 63, lr = l & 15, lg = l >> 4;
  int m0 = blockIdx.x * 64 + w * 16;
  int n0 = blockIdx.y * 64;
  short8_t af[8];
  const float* ar = A + (size_t)(m0 + lr) * 256 + lg * 8;
#pragma unroll
  for (int ks = 0; ks < 8; ks++) {
    f32x4 v0 = *(const f32x4*)(ar + ks * 32);
    f32x4 v1 = *(const f32x4*)(ar + ks * 32 + 4);
#pragma unroll
    for (int j = 0; j < 4; j++) { af[ks][j] = f2bf(v0[j]); af[ks][4 + j] = f2bf(v1[j]); }
  }
  for (int ct = 0; ct < 4; ct++) {
    f32x4 acc = {0.f, 0.f, 0.f, 0.f};
    const short* br = Bt + (size_t)(n0 + ct * 16 + lr) * 256 + lg * 8;
#pragma unroll
    for (int ks = 0; ks < 8; ks++) {
      short8_t bf = *(const short8_t*)(br + ks * 32);
      acc = __builtin_amdgcn_mfma_f32_16x16x32_bf16(af[ks], bf, acc, 0, 0, 0);
    }
    int c = n0 + ct * 16 + lr;
    int h = c >> 6, dd = c & 63;
#pragma unroll
    for (int r = 0; r < 4; r++) {
      int m = m0 + lg * 4 + r;
      int bb = m >> 11, n = m & 2047;
      Ob[(size_t)(((bb << 2) + h) * NSEQ + n) * 64 + dd] = f2bf(acc[r]);
    }
  }
}

// ------------------------------------------- Vt GEMM: Wv^T(256x256) @ t1^T(256x8192)
// A = Wkvt rows [256..512) (bf16 [c][k]); B = t1 (f32, read as columns); out Vt[bh][d][n]
__global__ __launch_bounds__(256) void gemm_vt(
    const float* __restrict__ T1, const short* __restrict__ Wvt,
    short* __restrict__ Vt) {
  int w = threadIdx.x >> 6, l = threadIdx.x & 63, lr = l & 15, lg = l >> 4;
  int c0 = blockIdx.y * 64 + w * 16;
  int m0 = blockIdx.x * 64;
  short8_t af[8];
  const short* ar = Wvt + (size_t)(c0 + lr) * 256 + lg * 8;
#pragma unroll
  for (int ks = 0; ks < 8; ks++) af[ks] = *(const short8_t*)(ar + ks * 32);
  for (int ct = 0; ct < 4; ct++) {
    f32x4 acc = {0.f, 0.f, 0.f, 0.f};
    const float* br = T1 + (size_t)(m0 + ct * 16 + lr) * 256 + lg * 8;
#pragma unroll
    for (int ks = 0; ks < 8; ks++) {
      f32x4 v0 = *(const f32x4*)(br + ks * 32);
      f32x4 v1 = *(const f32x4*)(br + ks * 32 + 4);
      short8_t bf;
#pragma unroll
      for (int j = 0; j < 4; j++) { bf[j] = f2bf(v0[j]); bf[4 + j] = f2bf(v1[j]); }
      acc = __builtin_amdgcn_mfma_f32_16x16x32_bf16(af[ks], bf, acc, 0, 0, 0);
    }
    int m = m0 + ct * 16 + lr;  // output column (sequence position)
    int bb = m >> 11, n = m & 2047;
#pragma unroll
    for (int r = 0; r < 4; r++) {
      int c = c0 + lg * 4 + r;
      int h = c >> 6, dd = c & 63;
      Vt[(size_t)(((bb << 2) + h) * 64 + dd) * NSEQ + n] = f2bf(acc[r]);
    }
  }
}

// ---------------------------------------------------------- flash attention
// grid (32 qtiles, 16 bh), 4 waves; wave handles 16 q rows, KBLK=64
__global__ __launch_bounds__(256) void flash_attn(
    const short* __restrict__ Qb, const short* __restrict__ Kb,
    const short* __restrict__ Vt, float* __restrict__ AO) {
  __shared__ short ldsP[4][16][72];  // 72*2=144B rows: 16B aligned, bank-spread
  int w = threadIdx.x >> 6, l = threadIdx.x & 63, lr = l & 15, lg = l >> 4;
  int bh = blockIdx.y;
  int q0 = blockIdx.x * 64 + w * 16;
  const short* qptr = Qb + ((size_t)bh * NSEQ + q0 + lr) * 64 + lg * 8;
  short8_t qf0 = *(const short8_t*)qptr;
  short8_t qf1 = *(const short8_t*)(qptr + 32);
  const short* kbase = Kb + (size_t)bh * NSEQ * 64;
  const short* vbase = Vt + (size_t)bh * 64 * NSEQ;
  f32x4 o[4] = {};
  float mi[4], li[4];
#pragma unroll
  for (int r = 0; r < 4; r++) { mi[r] = -1e30f; li[r] = 0.f; }
  for (int kb = 0; kb < NSEQ / 64; kb++) {
    f32x4 s[4];
#pragma unroll
    for (int t = 0; t < 4; t++) {
      const short* kptr = kbase + (size_t)(kb * 64 + t * 16 + lr) * 64 + lg * 8;
      short8_t kf0 = *(const short8_t*)kptr;
      short8_t kf1 = *(const short8_t*)(kptr + 32);
      f32x4 z = {0.f, 0.f, 0.f, 0.f};
      z = __builtin_amdgcn_mfma_f32_16x16x32_bf16(qf0, kf0, z, 0, 0, 0);
      s[t] = __builtin_amdgcn_mfma_f32_16x16x32_bf16(qf1, kf1, z, 0, 0, 0);
    }
    float alpha[4];
#pragma unroll
    for (int r = 0; r < 4; r++) {
      float mx = fmaxf(fmaxf(s[0][r], s[1][r]), fmaxf(s[2][r], s[3][r]));
#pragma unroll
      for (int x = 1; x < 16; x <<= 1) mx = fmaxf(mx, __shfl_xor(mx, x, 16));
      mx *= ATT_SCALE;
      float mnew = fmaxf(mi[r], mx);
      alpha[r] = __expf(mi[r] - mnew);
      float ps = 0.f;
#pragma unroll
      for (int t = 0; t < 4; t++) {
        float p = __expf(s[t][r] * ATT_SCALE - mnew);
        s[t][r] = p;
        ps += p;
      }
#pragma unroll
      for (int x = 1; x < 16; x <<= 1) ps += __shfl_xor(ps, x, 16);
      li[r] = li[r] * alpha[r] + ps;
      mi[r] = mnew;
#pragma unroll
      for (int t = 0; t < 4; t++) ldsP[w][lg * 4 + r][t * 16 + lr] = f2bf(s[t][r]);
    }
#pragma unroll
    for (int dt = 0; dt < 4; dt++)
#pragma unroll
      for (int r = 0; r < 4; r++) o[dt][r] *= alpha[r];
    __syncthreads();
    short8_t pa0 = *(const short8_t*)&ldsP[w][lr][lg * 8];
    short8_t pa1 = *(const short8_t*)&ldsP[w][lr][32 + lg * 8];
#pragma unroll
    for (int dt = 0; dt < 4; dt++) {
      const short* vptr = vbase + (size_t)(dt * 16 + lr) * NSEQ + kb * 64 + lg * 8;
      short8_t vf0 = *(const short8_t*)vptr;
      short8_t vf1 = *(const short8_t*)(vptr + 32);
      o[dt] = __builtin_amdgcn_mfma_f32_16x16x32_bf16(pa0, vf0, o[dt], 0, 0, 0);
      o[dt] = __builtin_amdgcn_mfma_f32_16x16x32_bf16(pa1, vf1, o[dt], 0, 0, 0);
    }
  }
#pragma unroll
  for (int dt = 0; dt < 4; dt++)
#pragma unroll
    for (int r = 0; r < 4; r++)
      AO[((size_t)bh * NSEQ + q0 + lg * 4 + r) * 64 + dt * 16 + lr] = o[dt][r] / li[r];
}

// ------------------------------------------------------- lam: energy (partial+atomic)
__global__ __launch_bounds__(256) void energy_partial(
    const float* __restrict__ AO, float* __restrict__ energy) {
  __shared__ float tile[128][68];
  int b = blockIdx.y, ch = blockIdx.x;
  const float* src = AO + ((size_t)b * 8192 + (size_t)ch * 128) * 64;
#pragma unroll
  for (int i = 0; i < 8; i++) {
    int idx = (i * 256 + threadIdx.x) * 4;
    f32x4 v = *(const f32x4*)(src + idx);
    int mrow = idx >> 6, col = idx & 63;
    tile[mrow][col + 0] = v[0]; tile[mrow][col + 1] = v[1];
    tile[mrow][col + 2] = v[2]; tile[mrow][col + 3] = v[3];
  }
  __syncthreads();
  int t = threadIdx.x;
  int dd = t >> 2, e0 = (t & 3) * 16;
  f32x4 acc[4] = {};
  for (int m = 0; m < 128; m++) {
    float a = tile[m][dd];
#pragma unroll
    for (int j = 0; j < 4; j++) {
      f32x4 x = *(const f32x4*)&tile[m][e0 + j * 4];
      acc[j] += a * x;
    }
  }
#pragma unroll
  for (int j = 0; j < 4; j++)
#pragma unroll
    for (int c = 0; c < 4; c++)
      atomicAdd(&energy[b * 4096 + dd * 64 + e0 + j * 4 + c], acc[j][c]);
}

// ------------------------------------------------------------ channel softmax
__global__ __launch_bounds__(64) void chan_softmax(
    const float* __restrict__ energy, float* __restrict__ attnc) {
  int row = blockIdx.x, t = threadIdx.x;
  float v = energy[row * 64 + t];
  float mx = v;
#pragma unroll
  for (int x = 1; x < 64; x <<= 1) mx = fmaxf(mx, __shfl_xor(mx, x, 64));
  float e = __expf(v - mx);
  float s = e;
#pragma unroll
  for (int x = 1; x < 64; x <<= 1) s += __shfl_xor(s, x, 64);
  attnc[row * 64 + t] = e / s;
}

// ------------------------------------- lam apply + residuals + bf16 x assembly
__global__ __launch_bounds__(256) void assemble_x(
    const float* __restrict__ AO, const float* __restrict__ attnc,
    const float* __restrict__ t2, const short* __restrict__ Qb,
    const float* __restrict__ gamma, short* __restrict__ Xf) {
  __shared__ f32x4 At4[1024];  // attnc[b] as 64 rows x 16 f32x4
  int b = blockIdx.y, tid = threadIdx.x;
  const f32x4* ac = (const f32x4*)(attnc + (size_t)b * 4096);
#pragma unroll
  for (int i = 0; i < 4; i++) At4[i * 256 + tid] = ac[i * 256 + tid];
  __syncthreads();
  int rowb = blockIdx.x * 256 + tid;
  int h = rowb >> 11, n = rowb & 2047;
  float g = gamma[0];
  const float* xop = AO + ((size_t)b * 8192 + rowb) * 64;
  f32x4 xv[16];
#pragma unroll
  for (int i = 0; i < 16; i++) xv[i] = *(const f32x4*)(xop + i * 4);
  const short* qp = Qb + ((size_t)b * 8192 + rowb) * 64;
  const float* t2p = t2 + ((size_t)b * 2048 + n) * 256 + h * 64;
  short* xfp = Xf + ((size_t)b * 2048 + n) * 256 + h * 64;
#pragma unroll
  for (int dd = 0; dd < 64; dd++) {
    f32x4 a = {0.f, 0.f, 0.f, 0.f};
#pragma unroll
    for (int j = 0; j < 16; j++) a += At4[dd * 16 + j] * xv[j];
    float o = a[0] + a[1] + a[2] + a[3];
    float xdd = xv[dd >> 2][dd & 3];
    float val = t2p[dd] + g * o + xdd + bf2f(qp[dd]);
    xfp[dd] = f2bf(val);
  }
}

// -------------------------------------------------- final projection + bias
__global__ __launch_bounds__(256) void gemm_proj(
    const short* __restrict__ Xf, const short* __restrict__ Wpt,
    const float* __restrict__ bias, float* __restrict__ out) {
  int w = threadIdx.x >> 6, l = threadIdx.x & 63, lr = l & 15, lg = l >> 4;
  int m0 = blockIdx.x * 64 + w * 16;
  int n0 = blockIdx.y * 64;
  short8_t af[8];
  const short* ar = Xf + (size_t)(m0 + lr) * 256 + lg * 8;
#pragma unroll
  for (int ks = 0; ks < 8; ks++) af[ks] = *(const short8_t*)(ar + ks * 32);
  for (int ct = 0; ct < 4; ct++) {
    f32x4 acc = {0.f, 0.f, 0.f, 0.f};
    const short* br = Wpt + (size_t)(n0 + ct * 16 + lr) * 256 + lg * 8;
#pragma unroll
    for (int ks = 0; ks < 8; ks++) {
      short8_t bf = *(const short8_t*)(br + ks * 32);
      acc = __builtin_amdgcn_mfma_f32_16x16x32_bf16(af[ks], bf, acc, 0, 0, 0);
    }
    int c = n0 + ct * 16 + lr;
    float bc = bias[c];
#pragma unroll
    for (int r = 0; r < 4; r++) {
      int m = m0 + lg * 4 + r;
      out[(size_t)m * 256 + c] = acc[r] + bc;
    }
  }
}

extern "C" void kernel_launch(void* const* d_in, const int* in_sizes, int n_in,
                              void* d_out, int out_size, void* d_ws, size_t ws_size,
                              hipStream_t stream) {
  const float* t2 = (const float*)d_in[0];
  const float* t1 = (const float*)d_in[1];
  const float* Wq = (const float*)d_in[2];
  const float* Wkv = (const float*)d_in[3];
  const float* Wp = (const float*)d_in[4];
  const float* bproj = (const float*)d_in[5];
  const float* gamma = (const float*)d_in[6];
  float* out = (float*)d_out;
  char* ws = (char*)d_ws;

  const size_t MB = 1024ull * 1024ull;
  short* Qb = (short*)(ws + 0);
  short* Kb = (short*)(ws + 4 * MB);
  short* Vt = (short*)(ws + 8 * MB);
  short* Xf = (short*)(ws + 12 * MB);
  float* AO = (float*)(ws + 16 * MB);
  short* Wqt = (short*)(ws + 24 * MB);
  short* Wkvt = (short*)(ws + 24 * MB + 128 * 1024);
  short* Wpt = (short*)(ws + 24 * MB + 384 * 1024);
  float* energy = (float*)(ws + 24 * MB + 512 * 1024);
  float* attnc = (float*)(ws + 24 * MB + 576 * 1024);

  hipMemsetAsync(energy, 0, 4 * 64 * 64 * sizeof(float), stream);
  wconv<<<1024, 256, 0, stream>>>(Wq, Wkv, Wp, Wqt, Wkvt, Wpt);
  gemm_rowout<<<dim3(128, 4), 256, 0, stream>>>(t2, Wqt, Qb);
  gemm_rowout<<<dim3(128, 4), 256, 0, stream>>>(t1, Wkvt, Kb);
  gemm_vt<<<dim3(128, 4), 256, 0, stream>>>(t1, Wkvt + 256 * 256, Vt);
  flash_attn<<<dim3(32, 16), 256, 0, stream>>>(Qb, Kb, Vt, AO);
  energy_partial<<<dim3(64, 4), 256, 0, stream>>>(AO, energy);
  chan_softmax<<<256, 64, 0, stream>>>(energy, attnc);
  assemble_x<<<dim3(32, 4), 256, 0, stream>>>(AO, attnc, t2, Qb, gamma, Xf);
  gemm_proj<<<dim3(128, 4), 256, 0, stream>>>(Xf, Wpt, bproj, out);
}

// Round 2
// 270.496 us; speedup vs baseline: 1.0529x; 1.0529x over previous
//
#include <hip/hip_runtime.h>

// Problem: B=4, N=2048, C=256, H=4, d=64
// Pipeline: wconv -> gemm(q) -> gemm(k) -> gemm(vt) -> flash_attn -> energy ->
//           chan_softmax -> assemble_x -> gemm_proj
// Workspace layout (bytes):
//   Qb   bf16 [16][2048][64]   @ 0        (4 MB)
//   Kb   bf16 [16][2048][64]   @ 4 MB     (4 MB)
//   Vt   bf16 [16][64][2048]   @ 8 MB     (4 MB)
//   Xf   bf16 [8192][256]      @ 12 MB    (4 MB)
//   AO   f32  [16][2048][64]   @ 16 MB    (8 MB)
//   Wqt  bf16 [256][256]       @ 24 MB
//   Wkvt bf16 [512][256]       @ 24 MB+128K
//   Wpt  bf16 [256][256]       @ 24 MB+384K
//   energy f32 [4][64][64]     @ 24 MB+512K
//   attnc  f32 [4][64][64]     @ 24 MB+576K

typedef __attribute__((ext_vector_type(8))) short short8_t;
typedef __attribute__((ext_vector_type(4))) float f32x4;

#define NSEQ 2048
#define NROW 8192

static __device__ __forceinline__ short f2bf(float f) {
  union { float f; unsigned u; } v; v.f = f;
  unsigned u = v.u;
  unsigned r = (u + 0x7FFFu + ((u >> 16) & 1u)) >> 16;
  return (short)r;
}
static __device__ __forceinline__ float bf2f(short s) {
  union { unsigned u; float f; } v;
  v.u = ((unsigned)(unsigned short)s) << 16;
  return v.f;
}

// DPP row_ror butterfly max over each 16-lane row (no LDS pipe, pure VALU).
template <int CTRL>
static __device__ __forceinline__ float dpp_max_step(float x) {
  int v = __builtin_bit_cast(int, x);
  int p = __builtin_amdgcn_update_dpp(v, v, CTRL, 0xF, 0xF, false);
  return fmaxf(x, __builtin_bit_cast(float, p));
}
static __device__ __forceinline__ float rowmax16(float x) {
  x = dpp_max_step<0x121>(x);  // row_ror:1
  x = dpp_max_step<0x122>(x);  // row_ror:2
  x = dpp_max_step<0x124>(x);  // row_ror:4
  x = dpp_max_step<0x128>(x);  // row_ror:8
  return x;
}

// ---------------------------------------------------------------- weights
__global__ __launch_bounds__(256) void wconv(
    const float* __restrict__ Wq, const float* __restrict__ Wkv,
    const float* __restrict__ Wp, short* __restrict__ Wqt,
    short* __restrict__ Wkvt, short* __restrict__ Wpt) {
  int tid = blockIdx.x * 256 + threadIdx.x;
  if (tid < 65536) {
    int n = tid >> 8, k = tid & 255;
    Wqt[tid] = f2bf(Wq[k * 256 + n]);
  } else if (tid < 196608) {
    int i = tid - 65536;
    int n = i >> 8, k = i & 255;
    Wkvt[i] = f2bf(Wkv[k * 512 + n]);
  } else {
    int i = tid - 196608;
    int n = i >> 8, k = i & 255;
    Wpt[i] = f2bf(Wp[k * 256 + n]);
  }
}

// ------------------------------------------------- q/k GEMM: (8192x256)@(256x256)
__global__ __launch_bounds__(256) void gemm_rowout(
    const float* __restrict__ A, const short* __restrict__ Bt,
    short* __restrict__ Ob) {
  int w = threadIdx.x >> 6, l = threadIdx.x & 63, lr = l & 15, lg = l >> 4;
  int m0 = blockIdx.x * 64 + w * 16;
  int n0 = blockIdx.y * 64;
  short8_t af[8];
  const float* ar = A + (size_t)(m0 + lr) * 256 + lg * 8;
#pragma unroll
  for (int ks = 0; ks < 8; ks++) {
    f32x4 v0 = *(const f32x4*)(ar + ks * 32);
    f32x4 v1 = *(const f32x4*)(ar + ks * 32 + 4);
#pragma unroll
    for (int j = 0; j < 4; j++) { af[ks][j] = f2bf(v0[j]); af[ks][4 + j] = f2bf(v1[j]); }
  }
  for (int ct = 0; ct < 4; ct++) {
    f32x4 acc = {0.f, 0.f, 0.f, 0.f};
    const short* br = Bt + (size_t)(n0 + ct * 16 + lr) * 256 + lg * 8;
#pragma unroll
    for (int ks = 0; ks < 8; ks++) {
      short8_t bf = *(const short8_t*)(br + ks * 32);
      acc = __builtin_amdgcn_mfma_f32_16x16x32_bf16(af[ks], bf, acc, 0, 0, 0);
    }
    int c = n0 + ct * 16 + lr;
    int h = c >> 6, dd = c & 63;
#pragma unroll
    for (int r = 0; r < 4; r++) {
      int m = m0 + lg * 4 + r;
      int bb = m >> 11, n = m & 2047;
      Ob[(size_t)(((bb << 2) + h) * NSEQ + n) * 64 + dd] = f2bf(acc[r]);
    }
  }
}

// ------------------------------------------- Vt GEMM: Wv^T(256x256) @ t1^T(256x8192)
__global__ __launch_bounds__(256) void gemm_vt(
    const float* __restrict__ T1, const short* __restrict__ Wvt,
    short* __restrict__ Vt) {
  int w = threadIdx.x >> 6, l = threadIdx.x & 63, lr = l & 15, lg = l >> 4;
  int c0 = blockIdx.y * 64 + w * 16;
  int m0 = blockIdx.x * 64;
  short8_t af[8];
  const short* ar = Wvt + (size_t)(c0 + lr) * 256 + lg * 8;
#pragma unroll
  for (int ks = 0; ks < 8; ks++) af[ks] = *(const short8_t*)(ar + ks * 32);
  for (int ct = 0; ct < 4; ct++) {
    f32x4 acc = {0.f, 0.f, 0.f, 0.f};
    const float* br = T1 + (size_t)(m0 + ct * 16 + lr) * 256 + lg * 8;
#pragma unroll
    for (int ks = 0; ks < 8; ks++) {
      f32x4 v0 = *(const f32x4*)(br + ks * 32);
      f32x4 v1 = *(const f32x4*)(br + ks * 32 + 4);
      short8_t bf;
#pragma unroll
      for (int j = 0; j < 4; j++) { bf[j] = f2bf(v0[j]); bf[4 + j] = f2bf(v1[j]); }
      acc = __builtin_amdgcn_mfma_f32_16x16x32_bf16(af[ks], bf, acc, 0, 0, 0);
    }
    int m = m0 + ct * 16 + lr;
    int bb = m >> 11, n = m & 2047;
#pragma unroll
    for (int r = 0; r < 4; r++) {
      int c = c0 + lg * 4 + r;
      int h = c >> 6, dd = c & 63;
      Vt[(size_t)(((bb << 2) + h) * 64 + dd) * NSEQ + n] = f2bf(acc[r]);
    }
  }
}

// ---------------------------------------------------------- flash attention
// grid (32 qtiles, 16 bh), 4 waves; wave handles 16 q rows, KBLK=64.
// No __syncthreads (LDS slices are wave-private). DPP row-max, ones-MFMA
// for the softmax denominator, V hoisted pre-softmax, next-K prefetch.
__global__ __launch_bounds__(256) void flash_attn(
    const short* __restrict__ Qb, const short* __restrict__ Kb,
    const short* __restrict__ Vt, float* __restrict__ AO) {
  __shared__ short ldsP[4][16][72];
  int w = threadIdx.x >> 6, l = threadIdx.x & 63, lr = l & 15, lg = l >> 4;
  int bh = blockIdx.y;
  int q0 = blockIdx.x * 64 + w * 16;
  const short* qptr = Qb + ((size_t)bh * NSEQ + q0 + lr) * 64 + lg * 8;
  short8_t qf0 = *(const short8_t*)qptr;
  short8_t qf1 = *(const short8_t*)(qptr + 32);
  const short* kbase = Kb + (size_t)bh * NSEQ * 64;
  const short* vbase = Vt + (size_t)bh * 64 * NSEQ;

  short8_t ones;
#pragma unroll
  for (int j = 0; j < 8; j++) ones[j] = (short)0x3F80;  // bf16 1.0

  f32x4 o[4] = {};
  f32x4 osum = {0.f, 0.f, 0.f, 0.f};
  float m2[4];
#pragma unroll
  for (int r = 0; r < 4; r++) m2[r] = -1e30f;

  const float C = 0.125f * 1.44269504089f;  // SCALE * log2(e)

  // preload K tile 0
  short8_t kf0[4], kf1[4];
#pragma unroll
  for (int t = 0; t < 4; t++) {
    const short* kptr = kbase + (size_t)(t * 16 + lr) * 64 + lg * 8;
    kf0[t] = *(const short8_t*)kptr;
    kf1[t] = *(const short8_t*)(kptr + 32);
  }

  for (int kb = 0; kb < NSEQ / 64; kb++) {
    // QK^T with current K regs
    f32x4 s[4];
#pragma unroll
    for (int t = 0; t < 4; t++) {
      f32x4 z = {0.f, 0.f, 0.f, 0.f};
      z = __builtin_amdgcn_mfma_f32_16x16x32_bf16(qf0, kf0[t], z, 0, 0, 0);
      s[t] = __builtin_amdgcn_mfma_f32_16x16x32_bf16(qf1, kf1[t], z, 0, 0, 0);
    }
    // issue V loads now (consumed after softmax -> latency hidden)
    short8_t vf0[4], vf1[4];
#pragma unroll
    for (int dt = 0; dt < 4; dt++) {
      const short* vptr = vbase + (size_t)(dt * 16 + lr) * NSEQ + kb * 64 + lg * 8;
      vf0[dt] = *(const short8_t*)vptr;
      vf1[dt] = *(const short8_t*)(vptr + 32);
    }
    // prefetch next K tile (overwrites kf regs already consumed by QK)
    if (kb + 1 < NSEQ / 64) {
#pragma unroll
      for (int t = 0; t < 4; t++) {
        const short* kptr = kbase + (size_t)((kb + 1) * 64 + t * 16 + lr) * 64 + lg * 8;
        kf0[t] = *(const short8_t*)kptr;
        kf1[t] = *(const short8_t*)(kptr + 32);
      }
    }
    // softmax: DPP row-max, exp2, pack P to LDS (wave-private slice)
    float alpha[4];
#pragma unroll
    for (int r = 0; r < 4; r++) {
      float mx = fmaxf(fmaxf(s[0][r], s[1][r]), fmaxf(s[2][r], s[3][r]));
      mx = rowmax16(mx) * C;
      float mnew = fmaxf(m2[r], mx);
      alpha[r] = __builtin_amdgcn_exp2f(m2[r] - mnew);
      m2[r] = mnew;
#pragma unroll
      for (int t = 0; t < 4; t++) {
        float p = __builtin_amdgcn_exp2f(s[t][r] * C - mnew);
        ldsP[w][lg * 4 + r][t * 16 + lr] = f2bf(p);
      }
    }
#pragma unroll
    for (int dt = 0; dt < 4; dt++)
#pragma unroll
      for (int r = 0; r < 4; r++) o[dt][r] *= alpha[r];
#pragma unroll
    for (int r = 0; r < 4; r++) osum[r] *= alpha[r];
    // read P as A-fragment (same wave wrote it; lgkmcnt ordering suffices)
    short8_t pa0 = *(const short8_t*)&ldsP[w][lr][lg * 8];
    short8_t pa1 = *(const short8_t*)&ldsP[w][lr][32 + lg * 8];
    // denominator via ones-MFMA (replaces sum-shfl chain + li recurrence)
    osum = __builtin_amdgcn_mfma_f32_16x16x32_bf16(pa0, ones, osum, 0, 0, 0);
    osum = __builtin_amdgcn_mfma_f32_16x16x32_bf16(pa1, ones, osum, 0, 0, 0);
#pragma unroll
    for (int dt = 0; dt < 4; dt++) {
      o[dt] = __builtin_amdgcn_mfma_f32_16x16x32_bf16(pa0, vf0[dt], o[dt], 0, 0, 0);
      o[dt] = __builtin_amdgcn_mfma_f32_16x16x32_bf16(pa1, vf1[dt], o[dt], 0, 0, 0);
    }
  }
  float inv[4];
#pragma unroll
  for (int r = 0; r < 4; r++) inv[r] = __builtin_amdgcn_rcpf(osum[r]);
#pragma unroll
  for (int dt = 0; dt < 4; dt++)
#pragma unroll
    for (int r = 0; r < 4; r++)
      AO[((size_t)bh * NSEQ + q0 + lg * 4 + r) * 64 + dt * 16 + lr] = o[dt][r] * inv[r];
}

// ------------------------------------------------------- lam: energy (partial+atomic)
__global__ __launch_bounds__(256) void energy_partial(
    const float* __restrict__ AO, float* __restrict__ energy) {
  __shared__ float tile[128][68];
  int b = blockIdx.y, ch = blockIdx.x;
  const float* src = AO + ((size_t)b * 8192 + (size_t)ch * 128) * 64;
#pragma unroll
  for (int i = 0; i < 8; i++) {
    int idx = (i * 256 + threadIdx.x) * 4;
    f32x4 v = *(const f32x4*)(src + idx);
    int mrow = idx >> 6, col = idx & 63;
    tile[mrow][col + 0] = v[0]; tile[mrow][col + 1] = v[1];
    tile[mrow][col + 2] = v[2]; tile[mrow][col + 3] = v[3];
  }
  __syncthreads();
  int t = threadIdx.x;
  int dd = t >> 2, e0 = (t & 3) * 16;
  f32x4 acc[4] = {};
  for (int m = 0; m < 128; m++) {
    float a = tile[m][dd];
#pragma unroll
    for (int j = 0; j < 4; j++) {
      f32x4 x = *(const f32x4*)&tile[m][e0 + j * 4];
      acc[j] += a * x;
    }
  }
#pragma unroll
  for (int j = 0; j < 4; j++)
#pragma unroll
    for (int c = 0; c < 4; c++)
      atomicAdd(&energy[b * 4096 + dd * 64 + e0 + j * 4 + c], acc[j][c]);
}

// ------------------------------------------------------------ channel softmax
__global__ __launch_bounds__(64) void chan_softmax(
    const float* __restrict__ energy, float* __restrict__ attnc) {
  int row = blockIdx.x, t = threadIdx.x;
  float v = energy[row * 64 + t];
  float mx = v;
#pragma unroll
  for (int x = 1; x < 64; x <<= 1) mx = fmaxf(mx, __shfl_xor(mx, x, 64));
  float e = __expf(v - mx);
  float s = e;
#pragma unroll
  for (int x = 1; x < 64; x <<= 1) s += __shfl_xor(s, x, 64);
  attnc[row * 64 + t] = e / s;
}

// ------------------------------------- lam apply + residuals + bf16 x assembly
__global__ __launch_bounds__(256) void assemble_x(
    const float* __restrict__ AO, const float* __restrict__ attnc,
    const float* __restrict__ t2, const short* __restrict__ Qb,
    const float* __restrict__ gamma, short* __restrict__ Xf) {
  __shared__ f32x4 At4[1024];
  int b = blockIdx.y, tid = threadIdx.x;
  const f32x4* ac = (const f32x4*)(attnc + (size_t)b * 4096);
#pragma unroll
  for (int i = 0; i < 4; i++) At4[i * 256 + tid] = ac[i * 256 + tid];
  __syncthreads();
  int rowb = blockIdx.x * 256 + tid;
  int h = rowb >> 11, n = rowb & 2047;
  float g = gamma[0];
  const float* xop = AO + ((size_t)b * 8192 + rowb) * 64;
  f32x4 xv[16];
#pragma unroll
  for (int i = 0; i < 16; i++) xv[i] = *(const f32x4*)(xop + i * 4);
  const short* qp = Qb + ((size_t)b * 8192 + rowb) * 64;
  const float* t2p = t2 + ((size_t)b * 2048 + n) * 256 + h * 64;
  short* xfp = Xf + ((size_t)b * 2048 + n) * 256 + h * 64;
#pragma unroll
  for (int dd = 0; dd < 64; dd++) {
    f32x4 a = {0.f, 0.f, 0.f, 0.f};
#pragma unroll
    for (int j = 0; j < 16; j++) a += At4[dd * 16 + j] * xv[j];
    float o = a[0] + a[1] + a[2] + a[3];
    float xdd = xv[dd >> 2][dd & 3];
    float val = t2p[dd] + g * o + xdd + bf2f(qp[dd]);
    xfp[dd] = f2bf(val);
  }
}

// -------------------------------------------------- final projection + bias
__global__ __launch_bounds__(256) void gemm_proj(
    const short* __restrict__ Xf, const short* __restrict__ Wpt,
    const float* __restrict__ bias, float* __restrict__ out) {
  int w = threadIdx.x >> 6, l = threadIdx.x & 63, lr = l & 15, lg = l >> 4;
  int m0 = blockIdx.x * 64 + w * 16;
  int n0 = blockIdx.y * 64;
  short8_t af[8];
  const short* ar = Xf + (size_t)(m0 + lr) * 256 + lg * 8;
#pragma unroll
  for (int ks = 0; ks < 8; ks++) af[ks] = *(const short8_t*)(ar + ks * 32);
  for (int ct = 0; ct < 4; ct++) {
    f32x4 acc = {0.f, 0.f, 0.f, 0.f};
    const short* br = Wpt + (size_t)(n0 + ct * 16 + lr) * 256 + lg * 8;
#pragma unroll
    for (int ks = 0; ks < 8; ks++) {
      short8_t bf = *(const short8_t*)(br + ks * 32);
      acc = __builtin_amdgcn_mfma_f32_16x16x32_bf16(af[ks], bf, acc, 0, 0, 0);
    }
    int c = n0 + ct * 16 + lr;
    float bc = bias[c];
#pragma unroll
    for (int r = 0; r < 4; r++) {
      int m = m0 + lg * 4 + r;
      out[(size_t)m * 256 + c] = acc[r] + bc;
    }
  }
}

extern "C" void kernel_launch(void* const* d_in, const int* in_sizes, int n_in,
                              void* d_out, int out_size, void* d_ws, size_t ws_size,
                              hipStream_t stream) {
  const float* t2 = (const float*)d_in[0];
  const float* t1 = (const float*)d_in[1];
  const float* Wq = (const float*)d_in[2];
  const float* Wkv = (const float*)d_in[3];
  const float* Wp = (const float*)d_in[4];
  const float* bproj = (const float*)d_in[5];
  const float* gamma = (const float*)d_in[6];
  float* out = (float*)d_out;
  char* ws = (char*)d_ws;

  const size_t MB = 1024ull * 1024ull;
  short* Qb = (short*)(ws + 0);
  short* Kb = (short*)(ws + 4 * MB);
  short* Vt = (short*)(ws + 8 * MB);
  short* Xf = (short*)(ws + 12 * MB);
  float* AO = (float*)(ws + 16 * MB);
  short* Wqt = (short*)(ws + 24 * MB);
  short* Wkvt = (short*)(ws + 24 * MB + 128 * 1024);
  short* Wpt = (short*)(ws + 24 * MB + 384 * 1024);
  float* energy = (float*)(ws + 24 * MB + 512 * 1024);
  float* attnc = (float*)(ws + 24 * MB + 576 * 1024);

  hipMemsetAsync(energy, 0, 4 * 64 * 64 * sizeof(float), stream);
  wconv<<<1024, 256, 0, stream>>>(Wq, Wkv, Wp, Wqt, Wkvt, Wpt);
  gemm_rowout<<<dim3(128, 4), 256, 0, stream>>>(t2, Wqt, Qb);
  gemm_rowout<<<dim3(128, 4), 256, 0, stream>>>(t1, Wkvt, Kb);
  gemm_vt<<<dim3(128, 4), 256, 0, stream>>>(t1, Wkvt + 256 * 256, Vt);
  flash_attn<<<dim3(32, 16), 256, 0, stream>>>(Qb, Kb, Vt, AO);
  energy_partial<<<dim3(64, 4), 256, 0, stream>>>(AO, energy);
  chan_softmax<<<256, 64, 0, stream>>>(energy, attnc);
  assemble_x<<<dim3(32, 4), 256, 0, stream>>>(AO, attnc, t2, Qb, gamma, Xf);
  gemm_proj<<<dim3(128, 4), 256, 0, stream>>>(Xf, Wpt, bproj, out);
}

// Round 3
// 207.121 us; speedup vs baseline: 1.3750x; 1.3060x over previous
//
#include <hip/hip_runtime.h>

// Problem: B=4, N=2048, C=256, H=4, d=64
// Pipeline: wconv -> gemm(q) -> gemm(k) -> gemm(vt) -> flash_attn -> energy ->
//           chan_softmax -> assemble_x -> gemm_proj
// Workspace layout (bytes):
//   Qb   bf16 [16][2048][64]   @ 0        (4 MB)
//   Kb   bf16 [16][2048][64]   @ 4 MB     (4 MB)
//   Vt   bf16 [16][64][2048]   @ 8 MB     (4 MB)
//   Xf   bf16 [8192][256]      @ 12 MB    (4 MB)
//   AO   f32  [16][2048][64]   @ 16 MB    (8 MB)
//   Wqt  bf16 [256][256]       @ 24 MB
//   Wkvt bf16 [512][256]       @ 24 MB+128K
//   Wpt  bf16 [256][256]       @ 24 MB+384K
//   energy f32 [4][64][64]     @ 24 MB+512K
//   attnc  f32 [4][64][64]     @ 24 MB+576K

typedef __attribute__((ext_vector_type(8))) short short8_t;
typedef __attribute__((ext_vector_type(4))) float f32x4;

#define NSEQ 2048
#define NROW 8192

static __device__ __forceinline__ short f2bf(float f) {
  union { float f; unsigned u; } v; v.f = f;
  unsigned u = v.u;
  unsigned r = (u + 0x7FFFu + ((u >> 16) & 1u)) >> 16;
  return (short)r;
}
static __device__ __forceinline__ float bf2f(short s) {
  union { unsigned u; float f; } v;
  v.u = ((unsigned)(unsigned short)s) << 16;
  return v.f;
}

// DPP row_ror butterfly max over each 16-lane row (no LDS pipe, pure VALU).
template <int CTRL>
static __device__ __forceinline__ float dpp_max_step(float x) {
  int v = __builtin_bit_cast(int, x);
  int p = __builtin_amdgcn_update_dpp(v, v, CTRL, 0xF, 0xF, false);
  return fmaxf(x, __builtin_bit_cast(float, p));
}
static __device__ __forceinline__ float rowmax16(float x) {
  x = dpp_max_step<0x121>(x);  // row_ror:1
  x = dpp_max_step<0x122>(x);  // row_ror:2
  x = dpp_max_step<0x124>(x);  // row_ror:4
  x = dpp_max_step<0x128>(x);  // row_ror:8
  return x;
}

// async global->LDS, 16B per lane; lds base must be wave-uniform.
static __device__ __forceinline__ void gload_lds16(const short* src, short* ldst) {
  __builtin_amdgcn_global_load_lds(
      (const __attribute__((address_space(1))) unsigned*)src,
      (__attribute__((address_space(3))) unsigned*)ldst, 16, 0, 0);
}

// ---------------------------------------------------------------- weights
__global__ __launch_bounds__(256) void wconv(
    const float* __restrict__ Wq, const float* __restrict__ Wkv,
    const float* __restrict__ Wp, short* __restrict__ Wqt,
    short* __restrict__ Wkvt, short* __restrict__ Wpt) {
  int tid = blockIdx.x * 256 + threadIdx.x;
  if (tid < 65536) {
    int n = tid >> 8, k = tid & 255;
    Wqt[tid] = f2bf(Wq[k * 256 + n]);
  } else if (tid < 196608) {
    int i = tid - 65536;
    int n = i >> 8, k = i & 255;
    Wkvt[i] = f2bf(Wkv[k * 512 + n]);
  } else {
    int i = tid - 196608;
    int n = i >> 8, k = i & 255;
    Wpt[i] = f2bf(Wp[k * 256 + n]);
  }
}

// ------------------------------------------------- q/k GEMM: (8192x256)@(256x256)
__global__ __launch_bounds__(256) void gemm_rowout(
    const float* __restrict__ A, const short* __restrict__ Bt,
    short* __restrict__ Ob) {
  int w = threadIdx.x >> 6, l = threadIdx.x & 63, lr = l & 15, lg = l >> 4;
  int m0 = blockIdx.x * 64 + w * 16;
  int n0 = blockIdx.y * 64;
  short8_t af[8];
  const float* ar = A + (size_t)(m0 + lr) * 256 + lg * 8;
#pragma unroll
  for (int ks = 0; ks < 8; ks++) {
    f32x4 v0 = *(const f32x4*)(ar + ks * 32);
    f32x4 v1 = *(const f32x4*)(ar + ks * 32 + 4);
#pragma unroll
    for (int j = 0; j < 4; j++) { af[ks][j] = f2bf(v0[j]); af[ks][4 + j] = f2bf(v1[j]); }
  }
  for (int ct = 0; ct < 4; ct++) {
    f32x4 acc = {0.f, 0.f, 0.f, 0.f};
    const short* br = Bt + (size_t)(n0 + ct * 16 + lr) * 256 + lg * 8;
#pragma unroll
    for (int ks = 0; ks < 8; ks++) {
      short8_t bf = *(const short8_t*)(br + ks * 32);
      acc = __builtin_amdgcn_mfma_f32_16x16x32_bf16(af[ks], bf, acc, 0, 0, 0);
    }
    int c = n0 + ct * 16 + lr;
    int h = c >> 6, dd = c & 63;
#pragma unroll
    for (int r = 0; r < 4; r++) {
      int m = m0 + lg * 4 + r;
      int bb = m >> 11, n = m & 2047;
      Ob[(size_t)(((bb << 2) + h) * NSEQ + n) * 64 + dd] = f2bf(acc[r]);
    }
  }
}

// ------------------------------------------- Vt GEMM: Wv^T(256x256) @ t1^T(256x8192)
__global__ __launch_bounds__(256) void gemm_vt(
    const float* __restrict__ T1, const short* __restrict__ Wvt,
    short* __restrict__ Vt) {
  int w = threadIdx.x >> 6, l = threadIdx.x & 63, lr = l & 15, lg = l >> 4;
  int c0 = blockIdx.y * 64 + w * 16;
  int m0 = blockIdx.x * 64;
  short8_t af[8];
  const short* ar = Wvt + (size_t)(c0 + lr) * 256 + lg * 8;
#pragma unroll
  for (int ks = 0; ks < 8; ks++) af[ks] = *(const short8_t*)(ar + ks * 32);
  for (int ct = 0; ct < 4; ct++) {
    f32x4 acc = {0.f, 0.f, 0.f, 0.f};
    const float* br = T1 + (size_t)(m0 + ct * 16 + lr) * 256 + lg * 8;
#pragma unroll
    for (int ks = 0; ks < 8; ks++) {
      f32x4 v0 = *(const f32x4*)(br + ks * 32);
      f32x4 v1 = *(const f32x4*)(br + ks * 32 + 4);
      short8_t bf;
#pragma unroll
      for (int j = 0; j < 4; j++) { bf[j] = f2bf(v0[j]); bf[4 + j] = f2bf(v1[j]); }
      acc = __builtin_amdgcn_mfma_f32_16x16x32_bf16(af[ks], bf, acc, 0, 0, 0);
    }
    int m = m0 + ct * 16 + lr;
    int bb = m >> 11, n = m & 2047;
#pragma unroll
    for (int r = 0; r < 4; r++) {
      int c = c0 + lg * 4 + r;
      int h = c >> 6, dd = c & 63;
      Vt[(size_t)(((bb << 2) + h) * 64 + dd) * NSEQ + n] = f2bf(acc[r]);
    }
  }
}

// ---------------------------------------------------------- flash attention
// grid (32 qtiles, 16 bh), 4 waves; wave handles 16 q rows, KBLK=64.
// 2-phase double-buffered LDS pipeline: K/V tiles staged via global_load_lds
// (16B) with pre-swizzled global source (chunk ^= row&7); all 4 waves share
// the tiles. DPP row-max softmax, ones-MFMA denominator.
__global__ __launch_bounds__(256) void flash_attn(
    const short* __restrict__ Qb, const short* __restrict__ Kb,
    const short* __restrict__ Vt, float* __restrict__ AO) {
  __shared__ __align__(16) short ldsK[2][4096];  // [64 rows][64 cols] bf16, swizzled
  __shared__ __align__(16) short ldsV[2][4096];
  __shared__ __align__(16) short ldsP[4][16][72];
  int tid = threadIdx.x;
  int w = tid >> 6, l = tid & 63, lr = l & 15, lg = l >> 4;
  int bh = blockIdx.y;
  int q0 = blockIdx.x * 64 + w * 16;
  const short* qptr = Qb + ((size_t)bh * NSEQ + q0 + lr) * 64 + lg * 8;
  short8_t qf0 = *(const short8_t*)qptr;
  short8_t qf1 = *(const short8_t*)(qptr + 32);
  const short* kbase = Kb + (size_t)bh * NSEQ * 64;  // [n][64]
  const short* vbase = Vt + (size_t)bh * 64 * NSEQ;  // [d][2048]

  // staging geometry: tile = 64 rows x 128B = 512 chunks of 16B.
  // thread stages chunks c = i*256 + tid (i=0,1) for K and V.
  // LDS is linear in c; global source chunk-in-row is (c&7) ^ (row&7).
  int c0c = tid, c1c = 256 + tid;
  int r0 = c0c >> 3, ch0 = (c0c & 7) ^ (r0 & 7);
  int r1 = c1c >> 3, ch1 = (c1c & 7) ^ (r1 & 7);
  short* ldK0w = &ldsK[0][0] + (size_t)(w * 64) * 8;          // + i*256 chunks
  short* ldV0w = &ldsV[0][0] + (size_t)(w * 64) * 8;
  short* ldK1w = &ldsK[1][0] + (size_t)(w * 64) * 8;
  short* ldV1w = &ldsV[1][0] + (size_t)(w * 64) * 8;

#define STAGE(bufsel, kb_)                                                     \
  {                                                                            \
    const short* kb8 = kbase + (size_t)((kb_)*64) * 64;                        \
    short* lk = (bufsel) ? ldK1w : ldK0w;                                      \
    short* lv = (bufsel) ? ldV1w : ldV0w;                                      \
    gload_lds16(kb8 + (size_t)r0 * 64 + ch0 * 8, lk);                          \
    gload_lds16(kb8 + (size_t)r1 * 64 + ch1 * 8, lk + 2048);                   \
    gload_lds16(vbase + (size_t)r0 * NSEQ + (kb_)*64 + ch0 * 8, lv);           \
    gload_lds16(vbase + (size_t)r1 * NSEQ + (kb_)*64 + ch1 * 8, lv + 2048);    \
  }

  short8_t ones;
#pragma unroll
  for (int j = 0; j < 8; j++) ones[j] = (short)0x3F80;  // bf16 1.0

  f32x4 o[4] = {};
  f32x4 osum = {0.f, 0.f, 0.f, 0.f};
  float m2[4];
#pragma unroll
  for (int r = 0; r < 4; r++) m2[r] = -1e30f;
  const float C = 0.125f * 1.44269504089f;  // SCALE * log2(e)

  // read-side swizzle: chunk j of row -> LDS chunk j ^ (row&7); row = *16+lr
  int sw = lr & 7;
  int rdA = (lg ^ sw) * 8;        // chunk lg   (cols 0..31 piece)
  int rdB = ((lg + 4) ^ sw) * 8;  // chunk lg+4 (cols 32..63 piece)

  STAGE(0, 0);
  asm volatile("s_waitcnt vmcnt(0)" ::: "memory");
  __syncthreads();

  for (int kb = 0; kb < NSEQ / 64; kb++) {
    int buf = kb & 1;
    if (kb + 1 < NSEQ / 64) STAGE(buf ^ 1, kb + 1);
    const short* lK = buf ? &ldsK[1][0] : &ldsK[0][0];
    const short* lV = buf ? &ldsV[1][0] : &ldsV[0][0];
    // QK^T from LDS
    f32x4 s[4];
#pragma unroll
    for (int t = 0; t < 4; t++) {
      const short* kr = lK + (t * 16 + lr) * 64;
      short8_t kf0 = *(const short8_t*)(kr + rdA);
      short8_t kf1 = *(const short8_t*)(kr + rdB);
      f32x4 z = {0.f, 0.f, 0.f, 0.f};
      z = __builtin_amdgcn_mfma_f32_16x16x32_bf16(qf0, kf0, z, 0, 0, 0);
      s[t] = __builtin_amdgcn_mfma_f32_16x16x32_bf16(qf1, kf1, z, 0, 0, 0);
    }
    // softmax: DPP row-max, exp2, pack P to LDS (wave-private slice)
    float alpha[4];
#pragma unroll
    for (int r = 0; r < 4; r++) {
      float mx = fmaxf(fmaxf(s[0][r], s[1][r]), fmaxf(s[2][r], s[3][r]));
      mx = rowmax16(mx) * C;
      float mnew = fmaxf(m2[r], mx);
      alpha[r] = __builtin_amdgcn_exp2f(m2[r] - mnew);
      m2[r] = mnew;
#pragma unroll
      for (int t = 0; t < 4; t++) {
        float p = __builtin_amdgcn_exp2f(s[t][r] * C - mnew);
        ldsP[w][lg * 4 + r][t * 16 + lr] = f2bf(p);
      }
    }
#pragma unroll
    for (int dt = 0; dt < 4; dt++)
#pragma unroll
      for (int r = 0; r < 4; r++) o[dt][r] *= alpha[r];
#pragma unroll
    for (int r = 0; r < 4; r++) osum[r] *= alpha[r];
    // P as A-fragment (same wave wrote it; lgkmcnt ordering suffices)
    short8_t pa0 = *(const short8_t*)&ldsP[w][lr][lg * 8];
    short8_t pa1 = *(const short8_t*)&ldsP[w][lr][32 + lg * 8];
    osum = __builtin_amdgcn_mfma_f32_16x16x32_bf16(pa0, ones, osum, 0, 0, 0);
    osum = __builtin_amdgcn_mfma_f32_16x16x32_bf16(pa1, ones, osum, 0, 0, 0);
#pragma unroll
    for (int dt = 0; dt < 4; dt++) {
      const short* vr = lV + (dt * 16 + lr) * 64;
      short8_t vf0 = *(const short8_t*)(vr + rdA);
      short8_t vf1 = *(const short8_t*)(vr + rdB);
      o[dt] = __builtin_amdgcn_mfma_f32_16x16x32_bf16(pa0, vf0, o[dt], 0, 0, 0);
      o[dt] = __builtin_amdgcn_mfma_f32_16x16x32_bf16(pa1, vf1, o[dt], 0, 0, 0);
    }
    asm volatile("s_waitcnt vmcnt(0)" ::: "memory");
    __syncthreads();
  }
#undef STAGE
  float inv[4];
#pragma unroll
  for (int r = 0; r < 4; r++) inv[r] = __builtin_amdgcn_rcpf(osum[r]);
#pragma unroll
  for (int dt = 0; dt < 4; dt++)
#pragma unroll
    for (int r = 0; r < 4; r++)
      AO[((size_t)bh * NSEQ + q0 + lg * 4 + r) * 64 + dt * 16 + lr] = o[dt][r] * inv[r];
}

// ------------------------------------------------------- lam: energy (partial+atomic)
__global__ __launch_bounds__(256) void energy_partial(
    const float* __restrict__ AO, float* __restrict__ energy) {
  __shared__ float tile[128][68];
  int b = blockIdx.y, ch = blockIdx.x;
  const float* src = AO + ((size_t)b * 8192 + (size_t)ch * 128) * 64;
#pragma unroll
  for (int i = 0; i < 8; i++) {
    int idx = (i * 256 + threadIdx.x) * 4;
    f32x4 v = *(const f32x4*)(src + idx);
    int mrow = idx >> 6, col = idx & 63;
    tile[mrow][col + 0] = v[0]; tile[mrow][col + 1] = v[1];
    tile[mrow][col + 2] = v[2]; tile[mrow][col + 3] = v[3];
  }
  __syncthreads();
  int t = threadIdx.x;
  int dd = t >> 2, e0 = (t & 3) * 16;
  f32x4 acc[4] = {};
  for (int m = 0; m < 128; m++) {
    float a = tile[m][dd];
#pragma unroll
    for (int j = 0; j < 4; j++) {
      f32x4 x = *(const f32x4*)&tile[m][e0 + j * 4];
      acc[j] += a * x;
    }
  }
#pragma unroll
  for (int j = 0; j < 4; j++)
#pragma unroll
    for (int c = 0; c < 4; c++)
      atomicAdd(&energy[b * 4096 + dd * 64 + e0 + j * 4 + c], acc[j][c]);
}

// ------------------------------------------------------------ channel softmax
__global__ __launch_bounds__(64) void chan_softmax(
    const float* __restrict__ energy, float* __restrict__ attnc) {
  int row = blockIdx.x, t = threadIdx.x;
  float v = energy[row * 64 + t];
  float mx = v;
#pragma unroll
  for (int x = 1; x < 64; x <<= 1) mx = fmaxf(mx, __shfl_xor(mx, x, 64));
  float e = __expf(v - mx);
  float s = e;
#pragma unroll
  for (int x = 1; x < 64; x <<= 1) s += __shfl_xor(s, x, 64);
  attnc[row * 64 + t] = e / s;
}

// ------------------------------------- lam apply + residuals + bf16 x assembly
__global__ __launch_bounds__(256) void assemble_x(
    const float* __restrict__ AO, const float* __restrict__ attnc,
    const float* __restrict__ t2, const short* __restrict__ Qb,
    const float* __restrict__ gamma, short* __restrict__ Xf) {
  __shared__ f32x4 At4[1024];
  int b = blockIdx.y, tid = threadIdx.x;
  const f32x4* ac = (const f32x4*)(attnc + (size_t)b * 4096);
#pragma unroll
  for (int i = 0; i < 4; i++) At4[i * 256 + tid] = ac[i * 256 + tid];
  __syncthreads();
  int rowb = blockIdx.x * 256 + tid;
  int h = rowb >> 11, n = rowb & 2047;
  float g = gamma[0];
  const float* xop = AO + ((size_t)b * 8192 + rowb) * 64;
  f32x4 xv[16];
#pragma unroll
  for (int i = 0; i < 16; i++) xv[i] = *(const f32x4*)(xop + i * 4);
  const short* qp = Qb + ((size_t)b * 8192 + rowb) * 64;
  const float* t2p = t2 + ((size_t)b * 2048 + n) * 256 + h * 64;
  short* xfp = Xf + ((size_t)b * 2048 + n) * 256 + h * 64;
#pragma unroll
  for (int dd = 0; dd < 64; dd++) {
    f32x4 a = {0.f, 0.f, 0.f, 0.f};
#pragma unroll
    for (int j = 0; j < 16; j++) a += At4[dd * 16 + j] * xv[j];
    float o = a[0] + a[1] + a[2] + a[3];
    float xdd = xv[dd >> 2][dd & 3];
    float val = t2p[dd] + g * o + xdd + bf2f(qp[dd]);
    xfp[dd] = f2bf(val);
  }
}

// -------------------------------------------------- final projection + bias
__global__ __launch_bounds__(256) void gemm_proj(
    const short* __restrict__ Xf, const short* __restrict__ Wpt,
    const float* __restrict__ bias, float* __restrict__ out) {
  int w = threadIdx.x >> 6, l = threadIdx.x & 63, lr = l & 15, lg = l >> 4;
  int m0 = blockIdx.x * 64 + w * 16;
  int n0 = blockIdx.y * 64;
  short8_t af[8];
  const short* ar = Xf + (size_t)(m0 + lr) * 256 + lg * 8;
#pragma unroll
  for (int ks = 0; ks < 8; ks++) af[ks] = *(const short8_t*)(ar + ks * 32);
  for (int ct = 0; ct < 4; ct++) {
    f32x4 acc = {0.f, 0.f, 0.f, 0.f};
    const short* br = Wpt + (size_t)(n0 + ct * 16 + lr) * 256 + lg * 8;
#pragma unroll
    for (int ks = 0; ks < 8; ks++) {
      short8_t bf = *(const short8_t*)(br + ks * 32);
      acc = __builtin_amdgcn_mfma_f32_16x16x32_bf16(af[ks], bf, acc, 0, 0, 0);
    }
    int c = n0 + ct * 16 + lr;
    float bc = bias[c];
#pragma unroll
    for (int r = 0; r < 4; r++) {
      int m = m0 + lg * 4 + r;
      out[(size_t)m * 256 + c] = acc[r] + bc;
    }
  }
}

extern "C" void kernel_launch(void* const* d_in, const int* in_sizes, int n_in,
                              void* d_out, int out_size, void* d_ws, size_t ws_size,
                              hipStream_t stream) {
  const float* t2 = (const float*)d_in[0];
  const float* t1 = (const float*)d_in[1];
  const float* Wq = (const float*)d_in[2];
  const float* Wkv = (const float*)d_in[3];
  const float* Wp = (const float*)d_in[4];
  const float* bproj = (const float*)d_in[5];
  const float* gamma = (const float*)d_in[6];
  float* out = (float*)d_out;
  char* ws = (char*)d_ws;

  const size_t MB = 1024ull * 1024ull;
  short* Qb = (short*)(ws + 0);
  short* Kb = (short*)(ws + 4 * MB);
  short* Vt = (short*)(ws + 8 * MB);
  short* Xf = (short*)(ws + 12 * MB);
  float* AO = (float*)(ws + 16 * MB);
  short* Wqt = (short*)(ws + 24 * MB);
  short* Wkvt = (short*)(ws + 24 * MB + 128 * 1024);
  short* Wpt = (short*)(ws + 24 * MB + 384 * 1024);
  float* energy = (float*)(ws + 24 * MB + 512 * 1024);
  float* attnc = (float*)(ws + 24 * MB + 576 * 1024);

  hipMemsetAsync(energy, 0, 4 * 64 * 64 * sizeof(float), stream);
  wconv<<<1024, 256, 0, stream>>>(Wq, Wkv, Wp, Wqt, Wkvt, Wpt);
  gemm_rowout<<<dim3(128, 4), 256, 0, stream>>>(t2, Wqt, Qb);
  gemm_rowout<<<dim3(128, 4), 256, 0, stream>>>(t1, Wkvt, Kb);
  gemm_vt<<<dim3(128, 4), 256, 0, stream>>>(t1, Wkvt + 256 * 256, Vt);
  flash_attn<<<dim3(32, 16), 256, 0, stream>>>(Qb, Kb, Vt, AO);
  energy_partial<<<dim3(64, 4), 256, 0, stream>>>(AO, energy);
  chan_softmax<<<256, 64, 0, stream>>>(energy, attnc);
  assemble_x<<<dim3(32, 4), 256, 0, stream>>>(AO, attnc, t2, Qb, gamma, Xf);
  gemm_proj<<<dim3(128, 4), 256, 0, stream>>>(Xf, Wpt, bproj, out);
}

// Round 4
// 146.489 us; speedup vs baseline: 1.9441x; 1.4139x over previous
//
#include <hip/hip_runtime.h>

// Problem: B=4, N=2048, C=256, H=4, d=64
// Pipeline: wconv -> gemm(q) -> gemm(k) -> gemm(vt) -> flash_attn ->
//           energy_mfma -> energy_reduce_softmax -> assemble_x -> gemm_proj
// Workspace layout (bytes):
//   Qb   bf16 [16][2048][64]   @ 0        (4 MB)
//   Kb   bf16 [16][2048][64]   @ 4 MB     (4 MB)  (aliased by partials after flash)
//   partials f32 [4][64][4096] @ 4 MB     (4 MB)
//   Vt   bf16 [16][64][2048]   @ 8 MB     (4 MB)
//   Xf   bf16 [8192][256]      @ 12 MB    (4 MB)
//   AO   f32  [16][2048][64]   @ 16 MB    (8 MB)
//   Wqt  bf16 [256][256]       @ 24 MB
//   Wkvt bf16 [512][256]       @ 24 MB+128K
//   Wpt  bf16 [256][256]       @ 24 MB+384K
//   attnc  f32 [4][64][64]     @ 24 MB+576K

typedef __attribute__((ext_vector_type(8))) short short8_t;
typedef __attribute__((ext_vector_type(4))) float f32x4;

#define NSEQ 2048
#define NROW 8192

static __device__ __forceinline__ short f2bf(float f) {
  union { float f; unsigned u; } v; v.f = f;
  unsigned u = v.u;
  unsigned r = (u + 0x7FFFu + ((u >> 16) & 1u)) >> 16;
  return (short)r;
}
static __device__ __forceinline__ float bf2f(short s) {
  union { unsigned u; float f; } v;
  v.u = ((unsigned)(unsigned short)s) << 16;
  return v.f;
}

// DPP row_ror butterfly max over each 16-lane row (no LDS pipe, pure VALU).
template <int CTRL>
static __device__ __forceinline__ float dpp_max_step(float x) {
  int v = __builtin_bit_cast(int, x);
  int p = __builtin_amdgcn_update_dpp(v, v, CTRL, 0xF, 0xF, false);
  return fmaxf(x, __builtin_bit_cast(float, p));
}
static __device__ __forceinline__ float rowmax16(float x) {
  x = dpp_max_step<0x121>(x);  // row_ror:1
  x = dpp_max_step<0x122>(x);  // row_ror:2
  x = dpp_max_step<0x124>(x);  // row_ror:4
  x = dpp_max_step<0x128>(x);  // row_ror:8
  return x;
}

// async global->LDS, 16B per lane; lds base must be wave-uniform.
static __device__ __forceinline__ void gload_lds16(const short* src, short* ldst) {
  __builtin_amdgcn_global_load_lds(
      (const __attribute__((address_space(1))) unsigned*)src,
      (__attribute__((address_space(3))) unsigned*)ldst, 16, 0, 0);
}

// ---------------------------------------------------------------- weights
__global__ __launch_bounds__(256) void wconv(
    const float* __restrict__ Wq, const float* __restrict__ Wkv,
    const float* __restrict__ Wp, short* __restrict__ Wqt,
    short* __restrict__ Wkvt, short* __restrict__ Wpt) {
  int tid = blockIdx.x * 256 + threadIdx.x;
  if (tid < 65536) {
    int n = tid >> 8, k = tid & 255;
    Wqt[tid] = f2bf(Wq[k * 256 + n]);
  } else if (tid < 196608) {
    int i = tid - 65536;
    int n = i >> 8, k = i & 255;
    Wkvt[i] = f2bf(Wkv[k * 512 + n]);
  } else {
    int i = tid - 196608;
    int n = i >> 8, k = i & 255;
    Wpt[i] = f2bf(Wp[k * 256 + n]);
  }
}

// ------------------------------------------------- q/k GEMM: (8192x256)@(256x256)
__global__ __launch_bounds__(256) void gemm_rowout(
    const float* __restrict__ A, const short* __restrict__ Bt,
    short* __restrict__ Ob) {
  int w = threadIdx.x >> 6, l = threadIdx.x & 63, lr = l & 15, lg = l >> 4;
  int m0 = blockIdx.x * 64 + w * 16;
  int n0 = blockIdx.y * 64;
  short8_t af[8];
  const float* ar = A + (size_t)(m0 + lr) * 256 + lg * 8;
#pragma unroll
  for (int ks = 0; ks < 8; ks++) {
    f32x4 v0 = *(const f32x4*)(ar + ks * 32);
    f32x4 v1 = *(const f32x4*)(ar + ks * 32 + 4);
#pragma unroll
    for (int j = 0; j < 4; j++) { af[ks][j] = f2bf(v0[j]); af[ks][4 + j] = f2bf(v1[j]); }
  }
  for (int ct = 0; ct < 4; ct++) {
    f32x4 acc = {0.f, 0.f, 0.f, 0.f};
    const short* br = Bt + (size_t)(n0 + ct * 16 + lr) * 256 + lg * 8;
#pragma unroll
    for (int ks = 0; ks < 8; ks++) {
      short8_t bf = *(const short8_t*)(br + ks * 32);
      acc = __builtin_amdgcn_mfma_f32_16x16x32_bf16(af[ks], bf, acc, 0, 0, 0);
    }
    int c = n0 + ct * 16 + lr;
    int h = c >> 6, dd = c & 63;
#pragma unroll
    for (int r = 0; r < 4; r++) {
      int m = m0 + lg * 4 + r;
      int bb = m >> 11, n = m & 2047;
      Ob[(size_t)(((bb << 2) + h) * NSEQ + n) * 64 + dd] = f2bf(acc[r]);
    }
  }
}

// ------------------------------------------- Vt GEMM: Wv^T(256x256) @ t1^T(256x8192)
__global__ __launch_bounds__(256) void gemm_vt(
    const float* __restrict__ T1, const short* __restrict__ Wvt,
    short* __restrict__ Vt) {
  int w = threadIdx.x >> 6, l = threadIdx.x & 63, lr = l & 15, lg = l >> 4;
  int c0 = blockIdx.y * 64 + w * 16;
  int m0 = blockIdx.x * 64;
  short8_t af[8];
  const short* ar = Wvt + (size_t)(c0 + lr) * 256 + lg * 8;
#pragma unroll
  for (int ks = 0; ks < 8; ks++) af[ks] = *(const short8_t*)(ar + ks * 32);
  for (int ct = 0; ct < 4; ct++) {
    f32x4 acc = {0.f, 0.f, 0.f, 0.f};
    const float* br = T1 + (size_t)(m0 + ct * 16 + lr) * 256 + lg * 8;
#pragma unroll
    for (int ks = 0; ks < 8; ks++) {
      f32x4 v0 = *(const f32x4*)(br + ks * 32);
      f32x4 v1 = *(const f32x4*)(br + ks * 32 + 4);
      short8_t bf;
#pragma unroll
      for (int j = 0; j < 4; j++) { bf[j] = f2bf(v0[j]); bf[4 + j] = f2bf(v1[j]); }
      acc = __builtin_amdgcn_mfma_f32_16x16x32_bf16(af[ks], bf, acc, 0, 0, 0);
    }
    int m = m0 + ct * 16 + lr;
    int bb = m >> 11, n = m & 2047;
#pragma unroll
    for (int r = 0; r < 4; r++) {
      int c = c0 + lg * 4 + r;
      int h = c >> 6, dd = c & 63;
      Vt[(size_t)(((bb << 2) + h) * 64 + dd) * NSEQ + n] = f2bf(acc[r]);
    }
  }
}

// ---------------------------------------------------------- flash attention
// grid (32 qtiles, 16 bh), 4 waves; wave handles 16 q rows, KBLK=64.
// 2-phase double-buffered LDS pipeline: K/V tiles staged via global_load_lds
// (16B) with pre-swizzled global source (chunk ^= row&7); all 4 waves share
// the tiles. DPP row-max softmax, ones-MFMA denominator.
__global__ __launch_bounds__(256) void flash_attn(
    const short* __restrict__ Qb, const short* __restrict__ Kb,
    const short* __restrict__ Vt, float* __restrict__ AO) {
  __shared__ __align__(16) short ldsK[2][4096];  // [64 rows][64 cols] bf16, swizzled
  __shared__ __align__(16) short ldsV[2][4096];
  __shared__ __align__(16) short ldsP[4][16][72];
  int tid = threadIdx.x;
  int w = tid >> 6, l = tid & 63, lr = l & 15, lg = l >> 4;
  int bh = blockIdx.y;
  int q0 = blockIdx.x * 64 + w * 16;
  const short* qptr = Qb + ((size_t)bh * NSEQ + q0 + lr) * 64 + lg * 8;
  short8_t qf0 = *(const short8_t*)qptr;
  short8_t qf1 = *(const short8_t*)(qptr + 32);
  const short* kbase = Kb + (size_t)bh * NSEQ * 64;  // [n][64]
  const short* vbase = Vt + (size_t)bh * 64 * NSEQ;  // [d][2048]

  int c0c = tid, c1c = 256 + tid;
  int r0 = c0c >> 3, ch0 = (c0c & 7) ^ (r0 & 7);
  int r1 = c1c >> 3, ch1 = (c1c & 7) ^ (r1 & 7);
  short* ldK0w = &ldsK[0][0] + (size_t)(w * 64) * 8;
  short* ldV0w = &ldsV[0][0] + (size_t)(w * 64) * 8;
  short* ldK1w = &ldsK[1][0] + (size_t)(w * 64) * 8;
  short* ldV1w = &ldsV[1][0] + (size_t)(w * 64) * 8;

#define STAGE(bufsel, kb_)                                                     \
  {                                                                            \
    const short* kb8 = kbase + (size_t)((kb_)*64) * 64;                        \
    short* lk = (bufsel) ? ldK1w : ldK0w;                                      \
    short* lv = (bufsel) ? ldV1w : ldV0w;                                      \
    gload_lds16(kb8 + (size_t)r0 * 64 + ch0 * 8, lk);                          \
    gload_lds16(kb8 + (size_t)r1 * 64 + ch1 * 8, lk + 2048);                   \
    gload_lds16(vbase + (size_t)r0 * NSEQ + (kb_)*64 + ch0 * 8, lv);           \
    gload_lds16(vbase + (size_t)r1 * NSEQ + (kb_)*64 + ch1 * 8, lv + 2048);    \
  }

  short8_t ones;
#pragma unroll
  for (int j = 0; j < 8; j++) ones[j] = (short)0x3F80;  // bf16 1.0

  f32x4 o[4] = {};
  f32x4 osum = {0.f, 0.f, 0.f, 0.f};
  float m2[4];
#pragma unroll
  for (int r = 0; r < 4; r++) m2[r] = -1e30f;
  const float C = 0.125f * 1.44269504089f;  // SCALE * log2(e)

  int sw = lr & 7;
  int rdA = (lg ^ sw) * 8;
  int rdB = ((lg + 4) ^ sw) * 8;

  STAGE(0, 0);
  asm volatile("s_waitcnt vmcnt(0)" ::: "memory");
  __syncthreads();

  for (int kb = 0; kb < NSEQ / 64; kb++) {
    int buf = kb & 1;
    if (kb + 1 < NSEQ / 64) STAGE(buf ^ 1, kb + 1);
    const short* lK = buf ? &ldsK[1][0] : &ldsK[0][0];
    const short* lV = buf ? &ldsV[1][0] : &ldsV[0][0];
    f32x4 s[4];
#pragma unroll
    for (int t = 0; t < 4; t++) {
      const short* kr = lK + (t * 16 + lr) * 64;
      short8_t kf0 = *(const short8_t*)(kr + rdA);
      short8_t kf1 = *(const short8_t*)(kr + rdB);
      f32x4 z = {0.f, 0.f, 0.f, 0.f};
      z = __builtin_amdgcn_mfma_f32_16x16x32_bf16(qf0, kf0, z, 0, 0, 0);
      s[t] = __builtin_amdgcn_mfma_f32_16x16x32_bf16(qf1, kf1, z, 0, 0, 0);
    }
    float alpha[4];
#pragma unroll
    for (int r = 0; r < 4; r++) {
      float mx = fmaxf(fmaxf(s[0][r], s[1][r]), fmaxf(s[2][r], s[3][r]));
      mx = rowmax16(mx) * C;
      float mnew = fmaxf(m2[r], mx);
      alpha[r] = __builtin_amdgcn_exp2f(m2[r] - mnew);
      m2[r] = mnew;
#pragma unroll
      for (int t = 0; t < 4; t++) {
        float p = __builtin_amdgcn_exp2f(s[t][r] * C - mnew);
        ldsP[w][lg * 4 + r][t * 16 + lr] = f2bf(p);
      }
    }
#pragma unroll
    for (int dt = 0; dt < 4; dt++)
#pragma unroll
      for (int r = 0; r < 4; r++) o[dt][r] *= alpha[r];
#pragma unroll
    for (int r = 0; r < 4; r++) osum[r] *= alpha[r];
    short8_t pa0 = *(const short8_t*)&ldsP[w][lr][lg * 8];
    short8_t pa1 = *(const short8_t*)&ldsP[w][lr][32 + lg * 8];
    osum = __builtin_amdgcn_mfma_f32_16x16x32_bf16(pa0, ones, osum, 0, 0, 0);
    osum = __builtin_amdgcn_mfma_f32_16x16x32_bf16(pa1, ones, osum, 0, 0, 0);
#pragma unroll
    for (int dt = 0; dt < 4; dt++) {
      const short* vr = lV + (dt * 16 + lr) * 64;
      short8_t vf0 = *(const short8_t*)(vr + rdA);
      short8_t vf1 = *(const short8_t*)(vr + rdB);
      o[dt] = __builtin_amdgcn_mfma_f32_16x16x32_bf16(pa0, vf0, o[dt], 0, 0, 0);
      o[dt] = __builtin_amdgcn_mfma_f32_16x16x32_bf16(pa1, vf1, o[dt], 0, 0, 0);
    }
    asm volatile("s_waitcnt vmcnt(0)" ::: "memory");
    __syncthreads();
  }
#undef STAGE
  float inv[4];
#pragma unroll
  for (int r = 0; r < 4; r++) inv[r] = __builtin_amdgcn_rcpf(osum[r]);
#pragma unroll
  for (int dt = 0; dt < 4; dt++)
#pragma unroll
    for (int r = 0; r < 4; r++)
      AO[((size_t)bh * NSEQ + q0 + lg * 4 + r) * 64 + dt * 16 + lr] = o[dt][r] * inv[r];
}

// ---------------------------------------- lam energy via MFMA (per-kchunk partials)
// energy[b] = flat @ flat^T, flat[b][dd][m], m = h*2048+n; K split into 64
// chunks of 128. Each block: stage AO chunk transposed into LDS bf16 with
// 4-bit XOR chunk swizzle, 16 MFMAs/wave, write partials (non-atomic).
__global__ __launch_bounds__(256) void energy_mfma(
    const float* __restrict__ AO, float* __restrict__ partials) {
  __shared__ __align__(16) short tileT[64][128];  // [dd][m], chunk-swizzled
  int tid = threadIdx.x;
  int b = blockIdx.y, kc = blockIdx.x;  // kc: 0..63 = h*16 + nblk
  int h = kc >> 4, n0 = (kc & 15) * 128;
  const float* src = AO + ((size_t)((b << 2) + h) * NSEQ + n0) * 64;
  int p = tid >> 4, dd0 = (tid & 15) * 4;
#pragma unroll
  for (int i = 0; i < 4; i++) {
    int m = 2 * p + 32 * i;
    f32x4 v0 = *(const f32x4*)(src + (size_t)m * 64 + dd0);
    f32x4 v1 = *(const f32x4*)(src + (size_t)(m + 1) * 64 + dd0);
#pragma unroll
    for (int j = 0; j < 4; j++) {
      int row = dd0 + j;
      int col = ((m >> 3) ^ (row & 15)) * 8 + (m & 7);
      unsigned pk = ((unsigned)(unsigned short)f2bf(v1[j]) << 16) |
                    (unsigned short)f2bf(v0[j]);
      *(unsigned*)&tileT[row][col] = pk;
    }
  }
  __syncthreads();
  int w = tid >> 6, l = tid & 63, lr = l & 15, lg = l >> 4;
  f32x4 acc[4] = {};
#pragma unroll
  for (int ks = 0; ks < 4; ks++) {
    short8_t af = *(const short8_t*)&tileT[w * 16 + lr][((ks * 4 + lg) ^ lr) * 8];
#pragma unroll
    for (int e = 0; e < 4; e++) {
      short8_t bf = *(const short8_t*)&tileT[e * 16 + lr][((ks * 4 + lg) ^ lr) * 8];
      acc[e] = __builtin_amdgcn_mfma_f32_16x16x32_bf16(af, bf, acc[e], 0, 0, 0);
    }
  }
  float* dst = partials + ((size_t)b * 64 + kc) * 4096;
#pragma unroll
  for (int e = 0; e < 4; e++)
#pragma unroll
    for (int r = 0; r < 4; r++)
      dst[(w * 16 + lg * 4 + r) * 64 + e * 16 + lr] = acc[e][r];
}

// -------------------------------- reduce partials over kc + channel softmax
__global__ __launch_bounds__(64) void energy_reduce_softmax(
    const float* __restrict__ partials, float* __restrict__ attnc) {
  int row = blockIdx.x;  // 0..255 = b*64 + d
  int b = row >> 6, d = row & 63;
  int e = threadIdx.x;
  const float* src = partials + (size_t)b * 64 * 4096 + d * 64 + e;
  float s = 0.f;
#pragma unroll 8
  for (int kc = 0; kc < 64; kc++) s += src[(size_t)kc * 4096];
  float mx = s;
#pragma unroll
  for (int x = 1; x < 64; x <<= 1) mx = fmaxf(mx, __shfl_xor(mx, x, 64));
  float ev = __expf(s - mx);
  float sum = ev;
#pragma unroll
  for (int x = 1; x < 64; x <<= 1) sum += __shfl_xor(sum, x, 64);
  attnc[row * 64 + e] = ev / sum;
}

// ------------------------------------- lam apply + residuals + bf16 x assembly
__global__ __launch_bounds__(256) void assemble_x(
    const float* __restrict__ AO, const float* __restrict__ attnc,
    const float* __restrict__ t2, const short* __restrict__ Qb,
    const float* __restrict__ gamma, short* __restrict__ Xf) {
  __shared__ f32x4 At4[1024];
  int b = blockIdx.y, tid = threadIdx.x;
  const f32x4* ac = (const f32x4*)(attnc + (size_t)b * 4096);
#pragma unroll
  for (int i = 0; i < 4; i++) At4[i * 256 + tid] = ac[i * 256 + tid];
  __syncthreads();
  int rowb = blockIdx.x * 256 + tid;
  int h = rowb >> 11, n = rowb & 2047;
  float g = gamma[0];
  const float* xop = AO + ((size_t)b * 8192 + rowb) * 64;
  f32x4 xv[16];
#pragma unroll
  for (int i = 0; i < 16; i++) xv[i] = *(const f32x4*)(xop + i * 4);
  const short* qp = Qb + ((size_t)b * 8192 + rowb) * 64;
  const float* t2p = t2 + ((size_t)b * 2048 + n) * 256 + h * 64;
  short* xfp = Xf + ((size_t)b * 2048 + n) * 256 + h * 64;
#pragma unroll
  for (int dd = 0; dd < 64; dd++) {
    f32x4 a = {0.f, 0.f, 0.f, 0.f};
#pragma unroll
    for (int j = 0; j < 16; j++) a += At4[dd * 16 + j] * xv[j];
    float o = a[0] + a[1] + a[2] + a[3];
    float xdd = xv[dd >> 2][dd & 3];
    float val = t2p[dd] + g * o + xdd + bf2f(qp[dd]);
    xfp[dd] = f2bf(val);
  }
}

// -------------------------------------------------- final projection + bias
__global__ __launch_bounds__(256) void gemm_proj(
    const short* __restrict__ Xf, const short* __restrict__ Wpt,
    const float* __restrict__ bias, float* __restrict__ out) {
  int w = threadIdx.x >> 6, l = threadIdx.x & 63, lr = l & 15, lg = l >> 4;
  int m0 = blockIdx.x * 64 + w * 16;
  int n0 = blockIdx.y * 64;
  short8_t af[8];
  const short* ar = Xf + (size_t)(m0 + lr) * 256 + lg * 8;
#pragma unroll
  for (int ks = 0; ks < 8; ks++) af[ks] = *(const short8_t*)(ar + ks * 32);
  for (int ct = 0; ct < 4; ct++) {
    f32x4 acc = {0.f, 0.f, 0.f, 0.f};
    const short* br = Wpt + (size_t)(n0 + ct * 16 + lr) * 256 + lg * 8;
#pragma unroll
    for (int ks = 0; ks < 8; ks++) {
      short8_t bf = *(const short8_t*)(br + ks * 32);
      acc = __builtin_amdgcn_mfma_f32_16x16x32_bf16(af[ks], bf, acc, 0, 0, 0);
    }
    int c = n0 + ct * 16 + lr;
    float bc = bias[c];
#pragma unroll
    for (int r = 0; r < 4; r++) {
      int m = m0 + lg * 4 + r;
      out[(size_t)m * 256 + c] = acc[r] + bc;
    }
  }
}

extern "C" void kernel_launch(void* const* d_in, const int* in_sizes, int n_in,
                              void* d_out, int out_size, void* d_ws, size_t ws_size,
                              hipStream_t stream) {
  const float* t2 = (const float*)d_in[0];
  const float* t1 = (const float*)d_in[1];
  const float* Wq = (const float*)d_in[2];
  const float* Wkv = (const float*)d_in[3];
  const float* Wp = (const float*)d_in[4];
  const float* bproj = (const float*)d_in[5];
  const float* gamma = (const float*)d_in[6];
  float* out = (float*)d_out;
  char* ws = (char*)d_ws;

  const size_t MB = 1024ull * 1024ull;
  short* Qb = (short*)(ws + 0);
  short* Kb = (short*)(ws + 4 * MB);
  float* partials = (float*)(ws + 4 * MB);  // aliases Kb (dead after flash)
  short* Vt = (short*)(ws + 8 * MB);
  short* Xf = (short*)(ws + 12 * MB);
  float* AO = (float*)(ws + 16 * MB);
  short* Wqt = (short*)(ws + 24 * MB);
  short* Wkvt = (short*)(ws + 24 * MB + 128 * 1024);
  short* Wpt = (short*)(ws + 24 * MB + 384 * 1024);
  float* attnc = (float*)(ws + 24 * MB + 576 * 1024);

  wconv<<<1024, 256, 0, stream>>>(Wq, Wkv, Wp, Wqt, Wkvt, Wpt);
  gemm_rowout<<<dim3(128, 4), 256, 0, stream>>>(t2, Wqt, Qb);
  gemm_rowout<<<dim3(128, 4), 256, 0, stream>>>(t1, Wkvt, Kb);
  gemm_vt<<<dim3(128, 4), 256, 0, stream>>>(t1, Wkvt + 256 * 256, Vt);
  flash_attn<<<dim3(32, 16), 256, 0, stream>>>(Qb, Kb, Vt, AO);
  energy_mfma<<<dim3(64, 4), 256, 0, stream>>>(AO, partials);
  energy_reduce_softmax<<<256, 64, 0, stream>>>(partials, attnc);
  assemble_x<<<dim3(32, 4), 256, 0, stream>>>(AO, attnc, t2, Qb, gamma, Xf);
  gemm_proj<<<dim3(128, 4), 256, 0, stream>>>(Xf, Wpt, bproj, out);
}

// Round 5
// 143.917 us; speedup vs baseline: 1.9789x; 1.0179x over previous
//
#include <hip/hip_runtime.h>

// Problem: B=4, N=2048, C=256, H=4, d=64
// Pipeline: wconv -> gemm(q) -> gemm(k) -> gemm(vt) -> flash_attn_split(x2 kv)
//           -> flash_combine -> energy_mfma -> energy_reduce_softmax ->
//           assemble_x -> gemm_proj
// Workspace layout (bytes):
//   Qb   bf16 [16][2048][64]   @ 0        (4 MB)
//   Kb   bf16 [16][2048][64]   @ 4 MB     (4 MB)  (aliased by partials after flash)
//   partials f32 [4][64][4096] @ 4 MB     (4 MB)
//   Vt   bf16 [16][64][2048]   @ 8 MB     (4 MB)
//   Xf   bf16 [8192][256]      @ 12 MB    (4 MB)  (aliased by O1 before assemble_x)
//   AO   f32  [16][2048][64]   @ 16 MB    (8 MB)
//   Wqt  bf16 [256][256]       @ 24 MB
//   Wkvt bf16 [512][256]       @ 24 MB+128K
//   Wpt  bf16 [256][256]       @ 24 MB+384K
//   attnc  f32 [4][64][64]     @ 24 MB+576K
//   ML   f32  [16][2048][2][2] @ 24 MB+640K (512 KB)

typedef __attribute__((ext_vector_type(8))) short short8_t;
typedef __attribute__((ext_vector_type(4))) float f32x4;

#define NSEQ 2048
#define NROW 8192

static __device__ __forceinline__ short f2bf(float f) {
  union { float f; unsigned u; } v; v.f = f;
  unsigned u = v.u;
  unsigned r = (u + 0x7FFFu + ((u >> 16) & 1u)) >> 16;
  return (short)r;
}
static __device__ __forceinline__ float bf2f(short s) {
  union { unsigned u; float f; } v;
  v.u = ((unsigned)(unsigned short)s) << 16;
  return v.f;
}

// DPP row_ror butterfly max over each 16-lane row (no LDS pipe, pure VALU).
template <int CTRL>
static __device__ __forceinline__ float dpp_max_step(float x) {
  int v = __builtin_bit_cast(int, x);
  int p = __builtin_amdgcn_update_dpp(v, v, CTRL, 0xF, 0xF, false);
  return fmaxf(x, __builtin_bit_cast(float, p));
}
static __device__ __forceinline__ float rowmax16(float x) {
  x = dpp_max_step<0x121>(x);  // row_ror:1
  x = dpp_max_step<0x122>(x);  // row_ror:2
  x = dpp_max_step<0x124>(x);  // row_ror:4
  x = dpp_max_step<0x128>(x);  // row_ror:8
  return x;
}

// async global->LDS, 16B per lane; lds base must be wave-uniform.
static __device__ __forceinline__ void gload_lds16(const short* src, short* ldst) {
  __builtin_amdgcn_global_load_lds(
      (const __attribute__((address_space(1))) unsigned*)src,
      (__attribute__((address_space(3))) unsigned*)ldst, 16, 0, 0);
}

// ---------------------------------------------------------------- weights
__global__ __launch_bounds__(256) void wconv(
    const float* __restrict__ Wq, const float* __restrict__ Wkv,
    const float* __restrict__ Wp, short* __restrict__ Wqt,
    short* __restrict__ Wkvt, short* __restrict__ Wpt) {
  int tid = blockIdx.x * 256 + threadIdx.x;
  if (tid < 65536) {
    int n = tid >> 8, k = tid & 255;
    Wqt[tid] = f2bf(Wq[k * 256 + n]);
  } else if (tid < 196608) {
    int i = tid - 65536;
    int n = i >> 8, k = i & 255;
    Wkvt[i] = f2bf(Wkv[k * 512 + n]);
  } else {
    int i = tid - 196608;
    int n = i >> 8, k = i & 255;
    Wpt[i] = f2bf(Wp[k * 256 + n]);
  }
}

// ------------------------------------------------- q/k GEMM: (8192x256)@(256x256)
__global__ __launch_bounds__(256) void gemm_rowout(
    const float* __restrict__ A, const short* __restrict__ Bt,
    short* __restrict__ Ob) {
  int w = threadIdx.x >> 6, l = threadIdx.x & 63, lr = l & 15, lg = l >> 4;
  int m0 = blockIdx.x * 64 + w * 16;
  int n0 = blockIdx.y * 64;
  short8_t af[8];
  const float* ar = A + (size_t)(m0 + lr) * 256 + lg * 8;
#pragma unroll
  for (int ks = 0; ks < 8; ks++) {
    f32x4 v0 = *(const f32x4*)(ar + ks * 32);
    f32x4 v1 = *(const f32x4*)(ar + ks * 32 + 4);
#pragma unroll
    for (int j = 0; j < 4; j++) { af[ks][j] = f2bf(v0[j]); af[ks][4 + j] = f2bf(v1[j]); }
  }
  for (int ct = 0; ct < 4; ct++) {
    f32x4 acc = {0.f, 0.f, 0.f, 0.f};
    const short* br = Bt + (size_t)(n0 + ct * 16 + lr) * 256 + lg * 8;
#pragma unroll
    for (int ks = 0; ks < 8; ks++) {
      short8_t bf = *(const short8_t*)(br + ks * 32);
      acc = __builtin_amdgcn_mfma_f32_16x16x32_bf16(af[ks], bf, acc, 0, 0, 0);
    }
    int c = n0 + ct * 16 + lr;
    int h = c >> 6, dd = c & 63;
#pragma unroll
    for (int r = 0; r < 4; r++) {
      int m = m0 + lg * 4 + r;
      int bb = m >> 11, n = m & 2047;
      Ob[(size_t)(((bb << 2) + h) * NSEQ + n) * 64 + dd] = f2bf(acc[r]);
    }
  }
}

// ------------------------------------------- Vt GEMM: Wv^T(256x256) @ t1^T(256x8192)
__global__ __launch_bounds__(256) void gemm_vt(
    const float* __restrict__ T1, const short* __restrict__ Wvt,
    short* __restrict__ Vt) {
  int w = threadIdx.x >> 6, l = threadIdx.x & 63, lr = l & 15, lg = l >> 4;
  int c0 = blockIdx.y * 64 + w * 16;
  int m0 = blockIdx.x * 64;
  short8_t af[8];
  const short* ar = Wvt + (size_t)(c0 + lr) * 256 + lg * 8;
#pragma unroll
  for (int ks = 0; ks < 8; ks++) af[ks] = *(const short8_t*)(ar + ks * 32);
  for (int ct = 0; ct < 4; ct++) {
    f32x4 acc = {0.f, 0.f, 0.f, 0.f};
    const float* br = T1 + (size_t)(m0 + ct * 16 + lr) * 256 + lg * 8;
#pragma unroll
    for (int ks = 0; ks < 8; ks++) {
      f32x4 v0 = *(const f32x4*)(br + ks * 32);
      f32x4 v1 = *(const f32x4*)(br + ks * 32 + 4);
      short8_t bf;
#pragma unroll
      for (int j = 0; j < 4; j++) { bf[j] = f2bf(v0[j]); bf[4 + j] = f2bf(v1[j]); }
      acc = __builtin_amdgcn_mfma_f32_16x16x32_bf16(af[ks], bf, acc, 0, 0, 0);
    }
    int m = m0 + ct * 16 + lr;
    int bb = m >> 11, n = m & 2047;
#pragma unroll
    for (int r = 0; r < 4; r++) {
      int c = c0 + lg * 4 + r;
      int h = c >> 6, dd = c & 63;
      Vt[(size_t)(((bb << 2) + h) * 64 + dd) * NSEQ + n] = f2bf(acc[r]);
    }
  }
}

// ---------------------------------------------------------- flash attention
// grid (64 = qtile*2+split, 16 bh), 4 waves; wave: 16 q rows, KBLK=64,
// 16 k-tiles per split. LDS exactly 40KB -> 4 blocks/CU. Defer-max (THR=8
// log2), truncated bf16 P, ones-MFMA denominator. Split outputs are
// self-normalized; (m, osum) per row per split go to ML for flash_combine.
__global__ __launch_bounds__(256) void flash_attn_split(
    const short* __restrict__ Qb, const short* __restrict__ Kb,
    const short* __restrict__ Vt, float* __restrict__ AO,
    short* __restrict__ O1, float* __restrict__ ML) {
  __shared__ __align__(16) short ldsK[2][4096];  // [64][64] bf16, chunk-swizzled
  __shared__ __align__(16) short ldsV[2][4096];
  __shared__ __align__(16) short ldsP[4][1024];  // [w][16 rows][64], chunk-swizzled
  int tid = threadIdx.x;
  int w = tid >> 6, l = tid & 63, lr = l & 15, lg = l >> 4;
  int bh = blockIdx.y;
  int qt = blockIdx.x >> 1, split = blockIdx.x & 1;
  int q0 = qt * 64 + w * 16;
  const short* qptr = Qb + ((size_t)bh * NSEQ + q0 + lr) * 64 + lg * 8;
  short8_t qf0 = *(const short8_t*)qptr;
  short8_t qf1 = *(const short8_t*)(qptr + 32);
  const short* kbase = Kb + (size_t)bh * NSEQ * 64;  // [n][64]
  const short* vbase = Vt + (size_t)bh * 64 * NSEQ;  // [d][2048]

  int c0c = tid, c1c = 256 + tid;
  int r0 = c0c >> 3, ch0 = (c0c & 7) ^ (r0 & 7);
  int r1 = c1c >> 3, ch1 = (c1c & 7) ^ (r1 & 7);
  short* ldK0w = &ldsK[0][0] + (size_t)(w * 64) * 8;
  short* ldV0w = &ldsV[0][0] + (size_t)(w * 64) * 8;
  short* ldK1w = &ldsK[1][0] + (size_t)(w * 64) * 8;
  short* ldV1w = &ldsV[1][0] + (size_t)(w * 64) * 8;

#define STAGE(bufsel, kb_)                                                     \
  {                                                                            \
    const short* kb8 = kbase + (size_t)((kb_)*64) * 64;                        \
    short* lk = (bufsel) ? ldK1w : ldK0w;                                      \
    short* lv = (bufsel) ? ldV1w : ldV0w;                                      \
    gload_lds16(kb8 + (size_t)r0 * 64 + ch0 * 8, lk);                          \
    gload_lds16(kb8 + (size_t)r1 * 64 + ch1 * 8, lk + 2048);                   \
    gload_lds16(vbase + (size_t)r0 * NSEQ + (kb_)*64 + ch0 * 8, lv);           \
    gload_lds16(vbase + (size_t)r1 * NSEQ + (kb_)*64 + ch1 * 8, lv + 2048);    \
  }

  short8_t ones;
#pragma unroll
  for (int j = 0; j < 8; j++) ones[j] = (short)0x3F80;  // bf16 1.0

  f32x4 o[4] = {};
  f32x4 osum = {0.f, 0.f, 0.f, 0.f};
  float m2[4];
#pragma unroll
  for (int r = 0; r < 4; r++) m2[r] = -1e30f;
  const float C = 0.125f * 1.44269504089f;  // SCALE * log2(e)

  int sw = lr & 7;
  int rdA = (lg ^ sw) * 8;
  int rdB = ((lg + 4) ^ sw) * 8;
  short* Pw = &ldsP[w][0];
  // P read addresses (row lr, logical chunks lg and 4+lg)
  const short* paddr0 = Pw + lr * 64 + (lg ^ sw) * 8;
  const short* paddr1 = Pw + lr * 64 + ((4 + lg) ^ sw) * 8;

  int kb0 = split * 16;
  STAGE(0, kb0);
  asm volatile("s_waitcnt vmcnt(0)" ::: "memory");
  __syncthreads();

  for (int i = 0; i < 16; i++) {
    int buf = i & 1;
    if (i + 1 < 16) STAGE(buf ^ 1, kb0 + i + 1);
    const short* lK = buf ? &ldsK[1][0] : &ldsK[0][0];
    const short* lV = buf ? &ldsV[1][0] : &ldsV[0][0];
    f32x4 s[4];
#pragma unroll
    for (int t = 0; t < 4; t++) {
      const short* kr = lK + (t * 16 + lr) * 64;
      short8_t kf0 = *(const short8_t*)(kr + rdA);
      short8_t kf1 = *(const short8_t*)(kr + rdB);
      f32x4 z = {0.f, 0.f, 0.f, 0.f};
      z = __builtin_amdgcn_mfma_f32_16x16x32_bf16(qf0, kf0, z, 0, 0, 0);
      s[t] = __builtin_amdgcn_mfma_f32_16x16x32_bf16(qf1, kf1, z, 0, 0, 0);
    }
    // row max (log2 domain) + defer-max check
    float mnew[4], need = -1.f;
#pragma unroll
    for (int r = 0; r < 4; r++) {
      float mx = fmaxf(fmaxf(s[0][r], s[1][r]), fmaxf(s[2][r], s[3][r]));
      mx = rowmax16(mx) * C;
      mnew[r] = fmaxf(m2[r], mx);
      need = fmaxf(need, mnew[r] - m2[r] - 8.f);
    }
    if (__any(need > 0.f)) {
#pragma unroll
      for (int r = 0; r < 4; r++) {
        float alpha = __builtin_amdgcn_exp2f(m2[r] - mnew[r]);
        m2[r] = mnew[r];
        osum[r] *= alpha;
#pragma unroll
        for (int dt = 0; dt < 4; dt++) o[dt][r] *= alpha;
      }
    }
    // P = exp2(s*C - m2), truncated bf16, chunk-swizzled LDS (wave-private)
#pragma unroll
    for (int r = 0; r < 4; r++) {
      int row = lg * 4 + r;
      int rsw = row & 7;
#pragma unroll
      for (int t = 0; t < 4; t++) {
        float p = __builtin_amdgcn_exp2f(__builtin_fmaf(s[t][r], C, -m2[r]));
        unsigned u = __builtin_bit_cast(unsigned, p);
        Pw[row * 64 + (((t * 2 + (lr >> 3)) ^ rsw) * 8 + (lr & 7))] =
            (short)(u >> 16);
      }
    }
    short8_t pa0 = *(const short8_t*)paddr0;
    short8_t pa1 = *(const short8_t*)paddr1;
    osum = __builtin_amdgcn_mfma_f32_16x16x32_bf16(pa0, ones, osum, 0, 0, 0);
    osum = __builtin_amdgcn_mfma_f32_16x16x32_bf16(pa1, ones, osum, 0, 0, 0);
#pragma unroll
    for (int dt = 0; dt < 4; dt++) {
      const short* vr = lV + (dt * 16 + lr) * 64;
      short8_t vf0 = *(const short8_t*)(vr + rdA);
      short8_t vf1 = *(const short8_t*)(vr + rdB);
      o[dt] = __builtin_amdgcn_mfma_f32_16x16x32_bf16(pa0, vf0, o[dt], 0, 0, 0);
      o[dt] = __builtin_amdgcn_mfma_f32_16x16x32_bf16(pa1, vf1, o[dt], 0, 0, 0);
    }
    asm volatile("s_waitcnt vmcnt(0)" ::: "memory");
    __syncthreads();
  }
#undef STAGE
  float inv[4];
#pragma unroll
  for (int r = 0; r < 4; r++) inv[r] = __builtin_amdgcn_rcpf(osum[r]);
  if (split == 0) {
#pragma unroll
    for (int dt = 0; dt < 4; dt++)
#pragma unroll
      for (int r = 0; r < 4; r++)
        AO[((size_t)bh * NSEQ + q0 + lg * 4 + r) * 64 + dt * 16 + lr] =
            o[dt][r] * inv[r];
  } else {
#pragma unroll
    for (int dt = 0; dt < 4; dt++)
#pragma unroll
      for (int r = 0; r < 4; r++)
        O1[((size_t)bh * NSEQ + q0 + lg * 4 + r) * 64 + dt * 16 + lr] =
            f2bf(o[dt][r] * inv[r]);
  }
  if (lr == 0) {
#pragma unroll
    for (int r = 0; r < 4; r++) {
      int row = q0 + lg * 4 + r;
      float2 v = {m2[r], osum[r]};
      *(float2*)&ML[((size_t)bh * NSEQ + row) * 4 + split * 2] = v;
    }
  }
}

// ------------------------------------------- merge the two kv-split partials
__global__ __launch_bounds__(256) void flash_combine(
    float* __restrict__ AO, const short* __restrict__ O1,
    const float* __restrict__ ML) {
  int tid = threadIdx.x;
  int row = blockIdx.x * 64 + (tid >> 2);
  int c0 = (tid & 3) * 16;
  float2 ml0 = *(const float2*)&ML[(size_t)row * 4];
  float2 ml1 = *(const float2*)&ML[(size_t)row * 4 + 2];
  float M = fmaxf(ml0.x, ml1.x);
  float w0 = ml0.y * __builtin_amdgcn_exp2f(ml0.x - M);
  float w1 = ml1.y * __builtin_amdgcn_exp2f(ml1.x - M);
  float inv = __builtin_amdgcn_rcpf(w0 + w1);
  float a0 = w0 * inv, a1 = w1 * inv;
  float* ao = AO + (size_t)row * 64 + c0;
  const short* o1 = O1 + (size_t)row * 64 + c0;
#pragma unroll
  for (int jj = 0; jj < 2; jj++) {
    short8_t ov = *(const short8_t*)(o1 + jj * 8);
    f32x4 v0 = *(const f32x4*)(ao + jj * 8);
    f32x4 v1 = *(const f32x4*)(ao + jj * 8 + 4);
#pragma unroll
    for (int j = 0; j < 4; j++) {
      v0[j] = v0[j] * a0 + bf2f(ov[j]) * a1;
      v1[j] = v1[j] * a0 + bf2f(ov[4 + j]) * a1;
    }
    *(f32x4*)(ao + jj * 8) = v0;
    *(f32x4*)(ao + jj * 8 + 4) = v1;
  }
}

// ---------------------------------------- lam energy via MFMA (per-kchunk partials)
__global__ __launch_bounds__(256) void energy_mfma(
    const float* __restrict__ AO, float* __restrict__ partials) {
  __shared__ __align__(16) short tileT[64][128];  // [dd][m], chunk-swizzled
  int tid = threadIdx.x;
  int b = blockIdx.y, kc = blockIdx.x;  // kc: 0..63 = h*16 + nblk
  int h = kc >> 4, n0 = (kc & 15) * 128;
  const float* src = AO + ((size_t)((b << 2) + h) * NSEQ + n0) * 64;
  int p = tid >> 4, dd0 = (tid & 15) * 4;
#pragma unroll
  for (int i = 0; i < 4; i++) {
    int m = 2 * p + 32 * i;
    f32x4 v0 = *(const f32x4*)(src + (size_t)m * 64 + dd0);
    f32x4 v1 = *(const f32x4*)(src + (size_t)(m + 1) * 64 + dd0);
#pragma unroll
    for (int j = 0; j < 4; j++) {
      int row = dd0 + j;
      int col = ((m >> 3) ^ (row & 15)) * 8 + (m & 7);
      unsigned pk = ((unsigned)(unsigned short)f2bf(v1[j]) << 16) |
                    (unsigned short)f2bf(v0[j]);
      *(unsigned*)&tileT[row][col] = pk;
    }
  }
  __syncthreads();
  int w = tid >> 6, l = tid & 63, lr = l & 15, lg = l >> 4;
  f32x4 acc[4] = {};
#pragma unroll
  for (int ks = 0; ks < 4; ks++) {
    short8_t af = *(const short8_t*)&tileT[w * 16 + lr][((ks * 4 + lg) ^ lr) * 8];
#pragma unroll
    for (int e = 0; e < 4; e++) {
      short8_t bf = *(const short8_t*)&tileT[e * 16 + lr][((ks * 4 + lg) ^ lr) * 8];
      acc[e] = __builtin_amdgcn_mfma_f32_16x16x32_bf16(af, bf, acc[e], 0, 0, 0);
    }
  }
  float* dst = partials + ((size_t)b * 64 + kc) * 4096;
#pragma unroll
  for (int e = 0; e < 4; e++)
#pragma unroll
    for (int r = 0; r < 4; r++)
      dst[(w * 16 + lg * 4 + r) * 64 + e * 16 + lr] = acc[e][r];
}

// -------------------------------- reduce partials over kc + channel softmax
__global__ __launch_bounds__(64) void energy_reduce_softmax(
    const float* __restrict__ partials, float* __restrict__ attnc) {
  int row = blockIdx.x;  // 0..255 = b*64 + d
  int b = row >> 6, d = row & 63;
  int e = threadIdx.x;
  const float* src = partials + (size_t)b * 64 * 4096 + d * 64 + e;
  float s = 0.f;
#pragma unroll 8
  for (int kc = 0; kc < 64; kc++) s += src[(size_t)kc * 4096];
  float mx = s;
#pragma unroll
  for (int x = 1; x < 64; x <<= 1) mx = fmaxf(mx, __shfl_xor(mx, x, 64));
  float ev = __expf(s - mx);
  float sum = ev;
#pragma unroll
  for (int x = 1; x < 64; x <<= 1) sum += __shfl_xor(sum, x, 64);
  attnc[row * 64 + e] = ev / sum;
}

// ------------------------------------- lam apply + residuals + bf16 x assembly
__global__ __launch_bounds__(256) void assemble_x(
    const float* __restrict__ AO, const float* __restrict__ attnc,
    const float* __restrict__ t2, const short* __restrict__ Qb,
    const float* __restrict__ gamma, short* __restrict__ Xf) {
  __shared__ f32x4 At4[1024];
  int b = blockIdx.y, tid = threadIdx.x;
  const f32x4* ac = (const f32x4*)(attnc + (size_t)b * 4096);
#pragma unroll
  for (int i = 0; i < 4; i++) At4[i * 256 + tid] = ac[i * 256 + tid];
  __syncthreads();
  int rowb = blockIdx.x * 256 + tid;
  int h = rowb >> 11, n = rowb & 2047;
  float g = gamma[0];
  const float* xop = AO + ((size_t)b * 8192 + rowb) * 64;
  f32x4 xv[16];
#pragma unroll
  for (int i = 0; i < 16; i++) xv[i] = *(const f32x4*)(xop + i * 4);
  const short* qp = Qb + ((size_t)b * 8192 + rowb) * 64;
  const float* t2p = t2 + ((size_t)b * 2048 + n) * 256 + h * 64;
  short* xfp = Xf + ((size_t)b * 2048 + n) * 256 + h * 64;
#pragma unroll
  for (int dd = 0; dd < 64; dd++) {
    f32x4 a = {0.f, 0.f, 0.f, 0.f};
#pragma unroll
    for (int j = 0; j < 16; j++) a += At4[dd * 16 + j] * xv[j];
    float o = a[0] + a[1] + a[2] + a[3];
    float xdd = xv[dd >> 2][dd & 3];
    float val = t2p[dd] + g * o + xdd + bf2f(qp[dd]);
    xfp[dd] = f2bf(val);
  }
}

// -------------------------------------------------- final projection + bias
__global__ __launch_bounds__(256) void gemm_proj(
    const short* __restrict__ Xf, const short* __restrict__ Wpt,
    const float* __restrict__ bias, float* __restrict__ out) {
  int w = threadIdx.x >> 6, l = threadIdx.x & 63, lr = l & 15, lg = l >> 4;
  int m0 = blockIdx.x * 64 + w * 16;
  int n0 = blockIdx.y * 64;
  short8_t af[8];
  const short* ar = Xf + (size_t)(m0 + lr) * 256 + lg * 8;
#pragma unroll
  for (int ks = 0; ks < 8; ks++) af[ks] = *(const short8_t*)(ar + ks * 32);
  for (int ct = 0; ct < 4; ct++) {
    f32x4 acc = {0.f, 0.f, 0.f, 0.f};
    const short* br = Wpt + (size_t)(n0 + ct * 16 + lr) * 256 + lg * 8;
#pragma unroll
    for (int ks = 0; ks < 8; ks++) {
      short8_t bf = *(const short8_t*)(br + ks * 32);
      acc = __builtin_amdgcn_mfma_f32_16x16x32_bf16(af[ks], bf, acc, 0, 0, 0);
    }
    int c = n0 + ct * 16 + lr;
    float bc = bias[c];
#pragma unroll
    for (int r = 0; r < 4; r++) {
      int m = m0 + lg * 4 + r;
      out[(size_t)m * 256 + c] = acc[r] + bc;
    }
  }
}

extern "C" void kernel_launch(void* const* d_in, const int* in_sizes, int n_in,
                              void* d_out, int out_size, void* d_ws, size_t ws_size,
                              hipStream_t stream) {
  const float* t2 = (const float*)d_in[0];
  const float* t1 = (const float*)d_in[1];
  const float* Wq = (const float*)d_in[2];
  const float* Wkv = (const float*)d_in[3];
  const float* Wp = (const float*)d_in[4];
  const float* bproj = (const float*)d_in[5];
  const float* gamma = (const float*)d_in[6];
  float* out = (float*)d_out;
  char* ws = (char*)d_ws;

  const size_t MB = 1024ull * 1024ull;
  short* Qb = (short*)(ws + 0);
  short* Kb = (short*)(ws + 4 * MB);
  float* partials = (float*)(ws + 4 * MB);  // aliases Kb (dead after flash)
  short* Vt = (short*)(ws + 8 * MB);
  short* Xf = (short*)(ws + 12 * MB);
  short* O1 = (short*)(ws + 12 * MB);       // aliases Xf (dead until assemble_x)
  float* AO = (float*)(ws + 16 * MB);
  short* Wqt = (short*)(ws + 24 * MB);
  short* Wkvt = (short*)(ws + 24 * MB + 128 * 1024);
  short* Wpt = (short*)(ws + 24 * MB + 384 * 1024);
  float* attnc = (float*)(ws + 24 * MB + 576 * 1024);
  float* ML = (float*)(ws + 24 * MB + 640 * 1024);

  wconv<<<1024, 256, 0, stream>>>(Wq, Wkv, Wp, Wqt, Wkvt, Wpt);
  gemm_rowout<<<dim3(128, 4), 256, 0, stream>>>(t2, Wqt, Qb);
  gemm_rowout<<<dim3(128, 4), 256, 0, stream>>>(t1, Wkvt, Kb);
  gemm_vt<<<dim3(128, 4), 256, 0, stream>>>(t1, Wkvt + 256 * 256, Vt);
  flash_attn_split<<<dim3(64, 16), 256, 0, stream>>>(Qb, Kb, Vt, AO, O1, ML);
  flash_combine<<<512, 256, 0, stream>>>(AO, O1, ML);
  energy_mfma<<<dim3(64, 4), 256, 0, stream>>>(AO, partials);
  energy_reduce_softmax<<<256, 64, 0, stream>>>(partials, attnc);
  assemble_x<<<dim3(32, 4), 256, 0, stream>>>(AO, attnc, t2, Qb, gamma, Xf);
  gemm_proj<<<dim3(128, 4), 256, 0, stream>>>(Xf, Wpt, bproj, out);
}

// Round 6
// 139.254 us; speedup vs baseline: 2.0451x; 1.0335x over previous
//
#include <hip/hip_runtime.h>

// Problem: B=4, N=2048, C=256, H=4, d=64
// Pipeline: wconv -> gemm_qkv(z=0,1,2) -> flash_attn_split<NS> (swapped-operand,
//           O^T output) -> flash_combine<NS> -> energy_mfma ->
//           energy_reduce_softmax -> assemble_x -> gemm_proj
// Workspace layout (bytes):
//   Qb   bf16 [16][2048][64]   @ 0        (4 MB)
//   Kb   bf16 [16][2048][64]   @ 4 MB     (4 MB)  (aliased by partials after flash)
//   Vt   bf16 [16][64][2048]   @ 8 MB     (4 MB)
//   Xf   bf16 [8192][256]      @ 12 MB    (4 MB)  (aliased by O1a before assemble)
//   AOt  f32  [16][64][2048]   @ 16 MB    (8 MB)  TRANSPOSED attention out
//   Wqt/Wkvt/Wpt/attnc/ML      @ 24 MB .. 25.6 MB
//   O1b/O1c bf16 (4-split only)@ 26 MB / 30 MB (needs ws >= 34 MB)

typedef __attribute__((ext_vector_type(8))) short short8_t;
typedef __attribute__((ext_vector_type(4))) float f32x4;

#define NSEQ 2048

static __device__ __forceinline__ short f2bf(float f) {
  union { float f; unsigned u; } v; v.f = f;
  unsigned u = v.u;
  unsigned r = (u + 0x7FFFu + ((u >> 16) & 1u)) >> 16;
  return (short)r;
}
static __device__ __forceinline__ float bf2f(short s) {
  union { unsigned u; float f; } v;
  v.u = ((unsigned)(unsigned short)s) << 16;
  return v.f;
}
static __device__ __forceinline__ unsigned bcu(float f) {
  return __builtin_bit_cast(unsigned, f);
}
// pack two f32 into u32 of 2 bf16 (truncation) via v_perm_b32
static __device__ __forceinline__ unsigned pkbf(float lo, float hi) {
  return __builtin_amdgcn_perm(bcu(hi), bcu(lo), 0x07060302u);
}
static __device__ __forceinline__ f32x4 vmax4(f32x4 a, f32x4 b) {
  f32x4 r;
  r[0] = fmaxf(a[0], b[0]); r[1] = fmaxf(a[1], b[1]);
  r[2] = fmaxf(a[2], b[2]); r[3] = fmaxf(a[3], b[3]);
  return r;
}

// async global->LDS, 16B per lane; lds base must be wave-uniform.
static __device__ __forceinline__ void gload_lds16(const short* src, short* ldst) {
  __builtin_amdgcn_global_load_lds(
      (const __attribute__((address_space(1))) unsigned*)src,
      (__attribute__((address_space(3))) unsigned*)ldst, 16, 0, 0);
}

// ---------------------------------------------------------------- weights
__global__ __launch_bounds__(256) void wconv(
    const float* __restrict__ Wq, const float* __restrict__ Wkv,
    const float* __restrict__ Wp, short* __restrict__ Wqt,
    short* __restrict__ Wkvt, short* __restrict__ Wpt) {
  int tid = blockIdx.x * 256 + threadIdx.x;
  if (tid < 65536) {
    int n = tid >> 8, k = tid & 255;
    Wqt[tid] = f2bf(Wq[k * 256 + n]);
  } else if (tid < 196608) {
    int i = tid - 65536;
    int n = i >> 8, k = i & 255;
    Wkvt[i] = f2bf(Wkv[k * 512 + n]);
  } else {
    int i = tid - 196608;
    int n = i >> 8, k = i & 255;
    Wpt[i] = f2bf(Wp[k * 256 + n]);
  }
}

// ------------------------------------------------- q/k GEMM body (8192x256)@(256x256)
static __device__ __forceinline__ void gemm_rowout_body(
    const float* __restrict__ A, const short* __restrict__ Bt,
    short* __restrict__ Ob) {
  int w = threadIdx.x >> 6, l = threadIdx.x & 63, lr = l & 15, lg = l >> 4;
  int m0 = blockIdx.x * 64 + w * 16;
  int n0 = blockIdx.y * 64;
  short8_t af[8];
  const float* ar = A + (size_t)(m0 + lr) * 256 + lg * 8;
#pragma unroll
  for (int ks = 0; ks < 8; ks++) {
    f32x4 v0 = *(const f32x4*)(ar + ks * 32);
    f32x4 v1 = *(const f32x4*)(ar + ks * 32 + 4);
#pragma unroll
    for (int j = 0; j < 4; j++) { af[ks][j] = f2bf(v0[j]); af[ks][4 + j] = f2bf(v1[j]); }
  }
  for (int ct = 0; ct < 4; ct++) {
    f32x4 acc = {0.f, 0.f, 0.f, 0.f};
    const short* br = Bt + (size_t)(n0 + ct * 16 + lr) * 256 + lg * 8;
#pragma unroll
    for (int ks = 0; ks < 8; ks++) {
      short8_t bf = *(const short8_t*)(br + ks * 32);
      acc = __builtin_amdgcn_mfma_f32_16x16x32_bf16(af[ks], bf, acc, 0, 0, 0);
    }
    int c = n0 + ct * 16 + lr;
    int h = c >> 6, dd = c & 63;
#pragma unroll
    for (int r = 0; r < 4; r++) {
      int m = m0 + lg * 4 + r;
      int bb = m >> 11, n = m & 2047;
      Ob[(size_t)(((bb << 2) + h) * NSEQ + n) * 64 + dd] = f2bf(acc[r]);
    }
  }
}

// ------------------------------------------- Vt GEMM body: Wv^T @ t1^T -> Vt[bh][d][n]
static __device__ __forceinline__ void gemm_vt_body(
    const float* __restrict__ T1, const short* __restrict__ Wvt,
    short* __restrict__ Vt) {
  int w = threadIdx.x >> 6, l = threadIdx.x & 63, lr = l & 15, lg = l >> 4;
  int c0 = blockIdx.y * 64 + w * 16;
  int m0 = blockIdx.x * 64;
  short8_t af[8];
  const short* ar = Wvt + (size_t)(c0 + lr) * 256 + lg * 8;
#pragma unroll
  for (int ks = 0; ks < 8; ks++) af[ks] = *(const short8_t*)(ar + ks * 32);
  for (int ct = 0; ct < 4; ct++) {
    f32x4 acc = {0.f, 0.f, 0.f, 0.f};
    const float* br = T1 + (size_t)(m0 + ct * 16 + lr) * 256 + lg * 8;
#pragma unroll
    for (int ks = 0; ks < 8; ks++) {
      f32x4 v0 = *(const f32x4*)(br + ks * 32);
      f32x4 v1 = *(const f32x4*)(br + ks * 32 + 4);
      short8_t bf;
#pragma unroll
      for (int j = 0; j < 4; j++) { bf[j] = f2bf(v0[j]); bf[4 + j] = f2bf(v1[j]); }
      acc = __builtin_amdgcn_mfma_f32_16x16x32_bf16(af[ks], bf, acc, 0, 0, 0);
    }
    int m = m0 + ct * 16 + lr;
    int bb = m >> 11, n = m & 2047;
#pragma unroll
    for (int r = 0; r < 4; r++) {
      int c = c0 + lg * 4 + r;
      int h = c >> 6, dd = c & 63;
      Vt[(size_t)(((bb << 2) + h) * 64 + dd) * NSEQ + n] = f2bf(acc[r]);
    }
  }
}

__global__ __launch_bounds__(256) void gemm_qkv(
    const float* __restrict__ t2, const float* __restrict__ t1,
    const short* __restrict__ Wqt, const short* __restrict__ Wkvt,
    short* __restrict__ Qb, short* __restrict__ Kb, short* __restrict__ Vtb) {
  if (blockIdx.z == 0) gemm_rowout_body(t2, Wqt, Qb);
  else if (blockIdx.z == 1) gemm_rowout_body(t1, Wkvt, Kb);
  else gemm_vt_body(t1, Wkvt + 65536, Vtb);
}

// ---------------------------------------------------------- flash attention
// Swapped-operand: S^T = mfma(K, Q) (lane owns one q), O^T = mfma(V, P).
// grid (32*NS, 16), 4 waves; wave: 16 q rows, KBLK=64, KITER=32/NS.
// LDS 32KB: K dbuf 16K + V single 8K + P 8K -> 5 blocks/CU.
// Counted vmcnt + raw s_barrier (prefetch never drained in-loop).
template <int NS>
__global__ __launch_bounds__(256, 5) void flash_attn_split(
    const short* __restrict__ Qb, const short* __restrict__ Kb,
    const short* __restrict__ Vt, float* __restrict__ AOt,
    short* __restrict__ O1a, short* __restrict__ O1b,
    short* __restrict__ O1c, float* __restrict__ ML) {
  constexpr int KITER = 32 / NS;
  __shared__ __align__(16) short ldsK[2][4096];
  __shared__ __align__(16) short ldsV[4096];
  __shared__ __align__(16) short ldsP[4][1024];
  int tid = threadIdx.x;
  int w = tid >> 6, l = tid & 63, lr = l & 15, lg = l >> 4;
  int bh = blockIdx.y;
  int qt = blockIdx.x / NS, split = blockIdx.x % NS;
  int q0 = qt * 64 + w * 16;
  const short* qptr = Qb + ((size_t)bh * NSEQ + q0 + lr) * 64 + lg * 8;
  short8_t qf0 = *(const short8_t*)qptr;
  short8_t qf1 = *(const short8_t*)(qptr + 32);
  const short* kbase = Kb + (size_t)bh * NSEQ * 64;  // [n][64]
  const short* vbase = Vt + (size_t)bh * 64 * NSEQ;  // [d][2048]

  // staging: 512 chunks of 16B per tile; thread covers chunks tid and tid+256.
  int r0 = tid >> 3, ch0 = (tid & 7) ^ (r0 & 7);
  int kb0 = split * KITER;
  const short* ksrc = kbase + (size_t)kb0 * 4096 + (size_t)r0 * 64 + ch0 * 8;
  const short* vsrc = vbase + (size_t)r0 * NSEQ + kb0 * 64 + ch0 * 8;
  short* ldKw0 = &ldsK[0][0] + w * 512;
  short* ldKw1 = &ldsK[1][0] + w * 512;
  short* ldVw = &ldsV[0] + w * 512;

#define STAGE_K(dst_, it_)                                  \
  {                                                         \
    const short* s_ = ksrc + (size_t)(it_) * 4096;          \
    gload_lds16(s_, dst_);                                  \
    gload_lds16(s_ + 2048, (dst_) + 2048);                  \
  }
#define STAGE_V(it_)                                        \
  {                                                         \
    const short* s_ = vsrc + (size_t)(it_) * 64;            \
    gload_lds16(s_, ldVw);                                  \
    gload_lds16(s_ + 32 * NSEQ, ldVw + 2048);               \
  }

  f32x4 o[4] = {};
  float osum = 0.f, m2 = -1e30f;
  const float C = 0.125f * 1.44269504089f;  // SCALE * log2(e)

  int sw = lr & 7;
  int rdA = (lg ^ sw) * 8;
  int rdB = ((lg + 4) ^ sw) * 8;
  short* Pw = &ldsP[w][0];
  int gh = lg >> 1, gb = lg & 1;
  short* addrPa = Pw + lr * 64 + ((0 + gh) ^ sw) * 8 + 4 * gb;
  short* addrPb = Pw + lr * 64 + ((2 + gh) ^ sw) * 8 + 4 * gb;
  short* addrPc = Pw + lr * 64 + ((4 + gh) ^ sw) * 8 + 4 * gb;
  short* addrPd = Pw + lr * 64 + ((6 + gh) ^ sw) * 8 + 4 * gb;
  const short* paddr0 = Pw + lr * 64 + ((lg) ^ sw) * 8;
  const short* paddr1 = Pw + lr * 64 + ((4 + lg) ^ sw) * 8;

  STAGE_K(ldKw0, 0);
  STAGE_V(0);
  asm volatile("s_waitcnt vmcnt(0)" ::: "memory");
  __builtin_amdgcn_s_barrier();

  for (int i = 0; i < KITER; i++) {
    if (i + 1 < KITER) {
      short* d_ = (i & 1) ? ldKw0 : ldKw1;
      STAGE_K(d_, i + 1);
    }
    const short* lK = (i & 1) ? &ldsK[1][0] : &ldsK[0][0];
    // S^T = K · Q^T  (lane: q-col = lr, kv-row = t*16 + lg*4 + r)
    f32x4 s[4];
#pragma unroll
    for (int t = 0; t < 4; t++) {
      const short* kr = lK + (t * 16 + lr) * 64;
      short8_t kf0 = *(const short8_t*)(kr + rdA);
      short8_t kf1 = *(const short8_t*)(kr + rdB);
      f32x4 z = {0.f, 0.f, 0.f, 0.f};
      z = __builtin_amdgcn_mfma_f32_16x16x32_bf16(kf0, qf0, z, 0, 0, 0);
      s[t] = __builtin_amdgcn_mfma_f32_16x16x32_bf16(kf1, qf1, s[0] * 0.f + z, 0, 0, 0);
    }
    // per-lane softmax over this tile's 64 kv (16 local + 2 shfl)
    f32x4 m4 = vmax4(vmax4(s[0], s[1]), vmax4(s[2], s[3]));
    float mx = fmaxf(fmaxf(m4[0], m4[1]), fmaxf(m4[2], m4[3]));
    mx = fmaxf(mx, __shfl_xor(mx, 16));
    mx = fmaxf(mx, __shfl_xor(mx, 32));
    mx *= C;
    float mnew = fmaxf(m2, mx);
    if (__any(mnew - m2 > 8.f)) {
      float alpha = __builtin_amdgcn_exp2f(m2 - mnew);
      m2 = mnew;
      osum *= alpha;
#pragma unroll
      for (int dt = 0; dt < 4; dt++) o[dt] *= alpha;
    }
    // P = exp2(s*C - m2); pack to bf16 pairs; write P[q][kv] (swizzled)
    float psum = 0.f;
#pragma unroll
    for (int t = 0; t < 4; t++) {
      float p0 = __builtin_amdgcn_exp2f(__builtin_fmaf(s[t][0], C, -m2));
      float p1 = __builtin_amdgcn_exp2f(__builtin_fmaf(s[t][1], C, -m2));
      float p2 = __builtin_amdgcn_exp2f(__builtin_fmaf(s[t][2], C, -m2));
      float p3 = __builtin_amdgcn_exp2f(__builtin_fmaf(s[t][3], C, -m2));
      psum += (p0 + p1) + (p2 + p3);
      unsigned ulo = pkbf(p0, p1);
      unsigned uhi = pkbf(p2, p3);
      short* ap = (t == 0) ? addrPa : (t == 1) ? addrPb : (t == 2) ? addrPc : addrPd;
      *(unsigned*)ap = ulo;
      *(unsigned*)(ap + 2) = uhi;
    }
    osum += psum;  // per-lane partial; cross-group reduce deferred to epilogue
    short8_t pB0 = *(const short8_t*)paddr0;
    short8_t pB1 = *(const short8_t*)paddr1;
    // V tile ready (issued prev iter tail / prologue); K(i+1) stays in flight
    if (i + 1 < KITER)
      asm volatile("s_waitcnt vmcnt(2)" ::: "memory");
    else
      asm volatile("s_waitcnt vmcnt(0)" ::: "memory");
    __builtin_amdgcn_s_barrier();
    // O^T += V^T · P^T
#pragma unroll
    for (int dt = 0; dt < 4; dt++) {
      const short* vr = &ldsV[0] + (dt * 16 + lr) * 64;
      short8_t vf0 = *(const short8_t*)(vr + rdA);
      short8_t vf1 = *(const short8_t*)(vr + rdB);
      o[dt] = __builtin_amdgcn_mfma_f32_16x16x32_bf16(vf0, pB0, o[dt], 0, 0, 0);
      o[dt] = __builtin_amdgcn_mfma_f32_16x16x32_bf16(vf1, pB1, o[dt], 0, 0, 0);
    }
    __builtin_amdgcn_s_barrier();  // all waves done with V tile
    if (i + 1 < KITER) {
      STAGE_V(i + 1);
      asm volatile("s_waitcnt vmcnt(2)" ::: "memory");  // K(i+1) landed
      __builtin_amdgcn_s_barrier();
    }
  }
#undef STAGE_K
#undef STAGE_V
  osum += __shfl_xor(osum, 16);
  osum += __shfl_xor(osum, 32);
  float inv = __builtin_amdgcn_rcpf(osum);
  if (split == 0) {
#pragma unroll
    for (int dt = 0; dt < 4; dt++)
#pragma unroll
      for (int r = 0; r < 4; r++)
        AOt[((size_t)bh * 64 + dt * 16 + lg * 4 + r) * NSEQ + q0 + lr] =
            o[dt][r] * inv;
  } else {
    short* op = (split == 1) ? O1a : (split == 2) ? O1b : O1c;
#pragma unroll
    for (int dt = 0; dt < 4; dt++)
#pragma unroll
      for (int r = 0; r < 4; r++)
        op[((size_t)bh * 64 + dt * 16 + lg * 4 + r) * NSEQ + q0 + lr] =
            f2bf(o[dt][r] * inv);
  }
  if (lg == 0) {
    float2 v = {m2, osum};
    *(float2*)&ML[((size_t)bh * NSEQ + q0 + lr) * 8 + split * 2] = v;
  }
}

// ------------------------------------------- merge the kv-split partials (in AOt)
template <int NS>
__global__ __launch_bounds__(256) void flash_combine(
    float* __restrict__ AOt, const short* __restrict__ O1a,
    const short* __restrict__ O1b, const short* __restrict__ O1c,
    const float* __restrict__ ML) {
  int row = blockIdx.x;  // bh*64 + d
  int bh = row >> 6;
  int nb = threadIdx.x * 8;
  size_t base = (size_t)row * NSEQ + nb;
  const float* mlb = ML + ((size_t)bh * NSEQ + nb) * 8;
  float oin[8];
  *(f32x4*)&oin[0] = *(const f32x4*)(AOt + base);
  *(f32x4*)&oin[4] = *(const f32x4*)(AOt + base + 4);
  short8_t s1 = *(const short8_t*)(O1a + base);
  short8_t s2v = {}, s3v = {};
  if (NS == 4) {
    s2v = *(const short8_t*)(O1b + base);
    s3v = *(const short8_t*)(O1c + base);
  }
  float out[8];
#pragma unroll
  for (int j = 0; j < 8; j++) {
    const float* ml = mlb + j * 8;
    f32x4 a = *(const f32x4*)ml;  // m0,s0,m1,s1
    if (NS == 2) {
      float M = fmaxf(a[0], a[2]);
      float w0 = a[1] * __builtin_amdgcn_exp2f(a[0] - M);
      float w1 = a[3] * __builtin_amdgcn_exp2f(a[2] - M);
      float iv = __builtin_amdgcn_rcpf(w0 + w1);
      out[j] = (oin[j] * w0 + bf2f(s1[j]) * w1) * iv;
    } else {
      f32x4 b = *(const f32x4*)(ml + 4);  // m2,s2,m3,s3
      float M = fmaxf(fmaxf(a[0], a[2]), fmaxf(b[0], b[2]));
      float w0 = a[1] * __builtin_amdgcn_exp2f(a[0] - M);
      float w1 = a[3] * __builtin_amdgcn_exp2f(a[2] - M);
      float w2 = b[1] * __builtin_amdgcn_exp2f(b[0] - M);
      float w3 = b[3] * __builtin_amdgcn_exp2f(b[2] - M);
      float iv = __builtin_amdgcn_rcpf(w0 + w1 + w2 + w3);
      out[j] = (oin[j] * w0 + bf2f(s1[j]) * w1 + bf2f(s2v[j]) * w2 +
                bf2f(s3v[j]) * w3) * iv;
    }
  }
  *(f32x4*)(AOt + base) = *(const f32x4*)&out[0];
  *(f32x4*)(AOt + base + 4) = *(const f32x4*)&out[4];
}

// ---------------------------------------- lam energy via MFMA (AOt rows, direct)
__global__ __launch_bounds__(256) void energy_mfma(
    const float* __restrict__ AOt, float* __restrict__ partials) {
  __shared__ __align__(16) short tileT[64][128];  // [dd][m], chunk-swizzled
  int tid = threadIdx.x;
  int b = blockIdx.y, kc = blockIdx.x;  // kc = h*16 + nblk
  int h = kc >> 4, n0 = (kc & 15) * 128;
  const float* src = AOt + ((size_t)((b << 2) + h) * 64) * NSEQ + n0;
  int row = tid >> 2, c0 = (tid & 3) * 32;
  const float* sp = src + (size_t)row * NSEQ + c0;
  int rsw = row & 15;
  short* trow = &tileT[row][0];
#pragma unroll
  for (int i = 0; i < 4; i++) {
    f32x4 v0 = *(const f32x4*)(sp + i * 8);
    f32x4 v1 = *(const f32x4*)(sp + i * 8 + 4);
    int ch = ((c0 >> 3) + i) ^ rsw;
    unsigned* dst = (unsigned*)(trow + ch * 8);
    dst[0] = pkbf(v0[0], v0[1]);
    dst[1] = pkbf(v0[2], v0[3]);
    dst[2] = pkbf(v1[0], v1[1]);
    dst[3] = pkbf(v1[2], v1[3]);
  }
  __syncthreads();
  int w = tid >> 6, lr = tid & 15, lg = (tid & 63) >> 4;
  f32x4 acc[4] = {};
#pragma unroll
  for (int ks = 0; ks < 4; ks++) {
    short8_t af = *(const short8_t*)&tileT[w * 16 + lr][((ks * 4 + lg) ^ lr) * 8];
#pragma unroll
    for (int e = 0; e < 4; e++) {
      short8_t bf = *(const short8_t*)&tileT[e * 16 + lr][((ks * 4 + lg) ^ lr) * 8];
      acc[e] = __builtin_amdgcn_mfma_f32_16x16x32_bf16(af, bf, acc[e], 0, 0, 0);
    }
  }
  float* dst = partials + ((size_t)b * 64 + kc) * 4096;
#pragma unroll
  for (int e = 0; e < 4; e++)
#pragma unroll
    for (int r = 0; r < 4; r++)
      dst[(w * 16 + lg * 4 + r) * 64 + e * 16 + lr] = acc[e][r];
}

// -------------------------------- reduce partials over kc + channel softmax
__global__ __launch_bounds__(64) void energy_reduce_softmax(
    const float* __restrict__ partials, float* __restrict__ attnc) {
  int row = blockIdx.x;  // b*64 + d
  int b = row >> 6, d = row & 63;
  int e = threadIdx.x;
  const float* src = partials + (size_t)b * 64 * 4096 + d * 64 + e;
  float s = 0.f;
#pragma unroll 8
  for (int kc = 0; kc < 64; kc++) s += src[(size_t)kc * 4096];
  float mx = s;
#pragma unroll
  for (int x = 1; x < 64; x <<= 1) mx = fmaxf(mx, __shfl_xor(mx, x, 64));
  float ev = __expf(s - mx);
  float sum = ev;
#pragma unroll
  for (int x = 1; x < 64; x <<= 1) sum += __shfl_xor(sum, x, 64);
  attnc[row * 64 + e] = ev / sum;
}

// ------------------------------------- lam apply + residuals + bf16 x assembly
__global__ __launch_bounds__(256) void assemble_x(
    const float* __restrict__ AOt, const float* __restrict__ attnc,
    const float* __restrict__ t2, const short* __restrict__ Qb,
    const float* __restrict__ gamma, short* __restrict__ Xf) {
  __shared__ f32x4 At4[1024];
  int b = blockIdx.y, tid = threadIdx.x;
  const f32x4* ac = (const f32x4*)(attnc + (size_t)b * 4096);
#pragma unroll
  for (int i = 0; i < 4; i++) At4[i * 256 + tid] = ac[i * 256 + tid];
  __syncthreads();
  int rowb = blockIdx.x * 256 + tid;
  int h = rowb >> 11, n = rowb & 2047;
  float g = gamma[0];
  const float* xop = AOt + ((size_t)((b << 2) + h) * 64) * NSEQ + n;
  f32x4 xv[16];
#pragma unroll
  for (int i = 0; i < 16; i++) {
    f32x4 t;
    t[0] = xop[(size_t)(4 * i + 0) * NSEQ];
    t[1] = xop[(size_t)(4 * i + 1) * NSEQ];
    t[2] = xop[(size_t)(4 * i + 2) * NSEQ];
    t[3] = xop[(size_t)(4 * i + 3) * NSEQ];
    xv[i] = t;
  }
  const short* qp = Qb + ((size_t)b * 8192 + rowb) * 64;
  const float* t2p = t2 + ((size_t)b * 2048 + n) * 256 + h * 64;
  short* xfp = Xf + ((size_t)b * 2048 + n) * 256 + h * 64;
#pragma unroll
  for (int dd = 0; dd < 64; dd++) {
    f32x4 a = {0.f, 0.f, 0.f, 0.f};
#pragma unroll
    for (int j = 0; j < 16; j++) a += At4[dd * 16 + j] * xv[j];
    float o = a[0] + a[1] + a[2] + a[3];
    float xdd = xv[dd >> 2][dd & 3];
    float val = t2p[dd] + g * o + xdd + bf2f(qp[dd]);
    xfp[dd] = f2bf(val);
  }
}

// -------------------------------------------------- final projection + bias
__global__ __launch_bounds__(256) void gemm_proj(
    const short* __restrict__ Xf, const short* __restrict__ Wpt,
    const float* __restrict__ bias, float* __restrict__ out) {
  int w = threadIdx.x >> 6, l = threadIdx.x & 63, lr = l & 15, lg = l >> 4;
  int m0 = blockIdx.x * 64 + w * 16;
  int n0 = blockIdx.y * 64;
  short8_t af[8];
  const short* ar = Xf + (size_t)(m0 + lr) * 256 + lg * 8;
#pragma unroll
  for (int ks = 0; ks < 8; ks++) af[ks] = *(const short8_t*)(ar + ks * 32);
  for (int ct = 0; ct < 4; ct++) {
    f32x4 acc = {0.f, 0.f, 0.f, 0.f};
    const short* br = Wpt + (size_t)(n0 + ct * 16 + lr) * 256 + lg * 8;
#pragma unroll
    for (int ks = 0; ks < 8; ks++) {
      short8_t bf = *(const short8_t*)(br + ks * 32);
      acc = __builtin_amdgcn_mfma_f32_16x16x32_bf16(af[ks], bf, acc, 0, 0, 0);
    }
    int c = n0 + ct * 16 + lr;
    float bc = bias[c];
#pragma unroll
    for (int r = 0; r < 4; r++) {
      int m = m0 + lg * 4 + r;
      out[(size_t)m * 256 + c] = acc[r] + bc;
    }
  }
}

extern "C" void kernel_launch(void* const* d_in, const int* in_sizes, int n_in,
                              void* d_out, int out_size, void* d_ws, size_t ws_size,
                              hipStream_t stream) {
  const float* t2 = (const float*)d_in[0];
  const float* t1 = (const float*)d_in[1];
  const float* Wq = (const float*)d_in[2];
  const float* Wkv = (const float*)d_in[3];
  const float* Wp = (const float*)d_in[4];
  const float* bproj = (const float*)d_in[5];
  const float* gamma = (const float*)d_in[6];
  float* out = (float*)d_out;
  char* ws = (char*)d_ws;

  const size_t MB = 1024ull * 1024ull;
  short* Qb = (short*)(ws + 0);
  short* Kb = (short*)(ws + 4 * MB);
  float* partials = (float*)(ws + 4 * MB);  // aliases Kb (dead after flash)
  short* Vt = (short*)(ws + 8 * MB);
  short* Xf = (short*)(ws + 12 * MB);
  short* O1a = (short*)(ws + 12 * MB);      // aliases Xf (dead until assemble_x)
  float* AOt = (float*)(ws + 16 * MB);
  short* Wqt = (short*)(ws + 24 * MB);
  short* Wkvt = (short*)(ws + 24 * MB + 128 * 1024);
  short* Wpt = (short*)(ws + 24 * MB + 384 * 1024);
  float* attnc = (float*)(ws + 24 * MB + 512 * 1024);
  float* ML = (float*)(ws + 24 * MB + 576 * 1024);  // 1 MB
  short* O1b = (short*)(ws + 26 * MB);
  short* O1c = (short*)(ws + 30 * MB);

  bool big = ws_size >= 34 * MB;

  wconv<<<1024, 256, 0, stream>>>(Wq, Wkv, Wp, Wqt, Wkvt, Wpt);
  gemm_qkv<<<dim3(128, 4, 3), 256, 0, stream>>>(t2, t1, Wqt, Wkvt, Qb, Kb, Vt);
  if (big) {
    flash_attn_split<4><<<dim3(128, 16), 256, 0, stream>>>(Qb, Kb, Vt, AOt, O1a,
                                                           O1b, O1c, ML);
    flash_combine<4><<<1024, 256, 0, stream>>>(AOt, O1a, O1b, O1c, ML);
  } else {
    flash_attn_split<2><<<dim3(64, 16), 256, 0, stream>>>(Qb, Kb, Vt, AOt, O1a,
                                                          O1a, O1a, ML);
    flash_combine<2><<<1024, 256, 0, stream>>>(AOt, O1a, O1a, O1a, ML);
  }
  energy_mfma<<<dim3(64, 4), 256, 0, stream>>>(AOt, partials);
  energy_reduce_softmax<<<256, 64, 0, stream>>>(partials, attnc);
  assemble_x<<<dim3(32, 4), 256, 0, stream>>>(AOt, attnc, t2, Qb, gamma, Xf);
  gemm_proj<<<dim3(128, 4), 256, 0, stream>>>(Xf, Wpt, bproj, out);
}

// Round 7
// 114.826 us; speedup vs baseline: 2.4802x; 1.2127x over previous
//
#include <hip/hip_runtime.h>
#include <hip/hip_bf16.h>

// Problem: B=4, N=2048, C=256, H=4, d=64
// Pipeline: wconv -> gemm_qkv2(y=0:q, y=1:k+v fused) -> flash_attn_split<NS>
//           -> flash_combine<NS> -> energy_mfma -> energy_reduce_softmax ->
//           assemble_x -> gemm_proj
// Workspace layout (bytes):
//   Qb   bf16 [16][2048][64]   @ 0        (4 MB)
//   Kb   bf16 [16][2048][64]   @ 4 MB     (4 MB)  (aliased by partials after flash)
//   Vt   bf16 [16][64][2048]   @ 8 MB     (4 MB)
//   Xf   bf16 [8192][256]      @ 12 MB    (4 MB)  (aliased by O1a before assemble)
//   AOt  f32  [16][64][2048]   @ 16 MB    (8 MB)  TRANSPOSED attention out
//   Wqt/Wkvt/Wpt/attnc/ML      @ 24 MB .. 25.6 MB
//   O1b/O1c bf16 (4-split only)@ 26 MB / 30 MB (needs ws >= 34 MB)

typedef __attribute__((ext_vector_type(8))) short short8_t;
typedef __attribute__((ext_vector_type(4))) float f32x4;

#define NSEQ 2048

static __device__ __forceinline__ short f2bf(float f) {
  union { float f; unsigned u; } v; v.f = f;
  unsigned u = v.u;
  unsigned r = (u + 0x7FFFu + ((u >> 16) & 1u)) >> 16;
  return (short)r;
}
static __device__ __forceinline__ float bf2f(short s) {
  union { unsigned u; float f; } v;
  v.u = ((unsigned)(unsigned short)s) << 16;
  return v.f;
}
static __device__ __forceinline__ unsigned bcu(float f) {
  return __builtin_bit_cast(unsigned, f);
}
// pack two f32 into u32 of 2 bf16 (truncation) via v_perm_b32
static __device__ __forceinline__ unsigned pkbf(float lo, float hi) {
  return __builtin_amdgcn_perm(bcu(hi), bcu(lo), 0x07060302u);
}
// hardware RNE f32->bf16 (compiler emits v_cvt_pk_bf16_f32)
static __device__ __forceinline__ short f2bf_hw(float f) {
  __hip_bfloat16 h = __float2bfloat16(f);
  return __builtin_bit_cast(short, h);
}
static __device__ __forceinline__ unsigned pk2bf_hw(float a, float b) {
  return ((unsigned)(unsigned short)__builtin_bit_cast(short, __float2bfloat16(b)) << 16) |
         (unsigned short)__builtin_bit_cast(short, __float2bfloat16(a));
}
static __device__ __forceinline__ f32x4 vmax4(f32x4 a, f32x4 b) {
  f32x4 r;
  r[0] = fmaxf(a[0], b[0]); r[1] = fmaxf(a[1], b[1]);
  r[2] = fmaxf(a[2], b[2]); r[3] = fmaxf(a[3], b[3]);
  return r;
}

// async global->LDS, 16B per lane; lds base must be wave-uniform.
static __device__ __forceinline__ void gload_lds16(const short* src, short* ldst) {
  __builtin_amdgcn_global_load_lds(
      (const __attribute__((address_space(1))) unsigned*)src,
      (__attribute__((address_space(3))) unsigned*)ldst, 16, 0, 0);
}

// ---------------------------------------------------------------- weights
__global__ __launch_bounds__(256) void wconv(
    const float* __restrict__ Wq, const float* __restrict__ Wkv,
    const float* __restrict__ Wp, short* __restrict__ Wqt,
    short* __restrict__ Wkvt, short* __restrict__ Wpt) {
  int tid = blockIdx.x * 256 + threadIdx.x;
  if (tid < 65536) {
    int n = tid >> 8, k = tid & 255;
    Wqt[tid] = f2bf(Wq[k * 256 + n]);
  } else if (tid < 196608) {
    int i = tid - 65536;
    int n = i >> 8, k = i & 255;
    Wkvt[i] = f2bf(Wkv[k * 512 + n]);
  } else {
    int i = tid - 196608;
    int n = i >> 8, k = i & 255;
    Wpt[i] = f2bf(Wp[k * 256 + n]);
  }
}

// ---------------------------- QKV projection: LDS-staged A, 32 rows per block
// y=0: q = t2 @ Wq -> Qb[bh][n][64]
// y=1: k = t1 @ Wk -> Kb[bh][n][64]; v = t1 @ Wv (swapped mfma) -> Vt[bh][d][n]
__global__ __launch_bounds__(256) void gemm_qkv2(
    const float* __restrict__ t2, const float* __restrict__ t1,
    const short* __restrict__ Wqt, const short* __restrict__ Wkvt,
    short* __restrict__ Qb, short* __restrict__ Kb, short* __restrict__ Vtb) {
  __shared__ __align__(16) short ldsA[32 * 256];  // 16 KB, chunk-swizzled
  int tid = threadIdx.x;
  int m0 = blockIdx.x * 32;
  bool isQ = (blockIdx.y == 0);
  const float* A = isQ ? t2 : t1;

  // stage A: 32 rows x 256 f32 = 2048 f32x4 chunks, fully coalesced
  const float* ap = A + (size_t)m0 * 256;
#pragma unroll
  for (int i = 0; i < 8; i++) {
    int idx = i * 256 + tid;            // f32x4 chunk id
    int row = idx >> 6, c4 = idx & 63;  // 4-float chunk within row
    f32x4 v = *(const f32x4*)(ap + (size_t)idx * 4);
    int ch8 = c4 >> 1, half = c4 & 1;   // 8-bf16 chunk, half
    int swz = ch8 ^ (row & 7);
    unsigned* dst = (unsigned*)&ldsA[row * 256 + swz * 8 + half * 4];
    dst[0] = pk2bf_hw(v[0], v[1]);
    dst[1] = pk2bf_hw(v[2], v[3]);
  }
  __syncthreads();

  int w = tid >> 6, l = tid & 63, lr = l & 15, lg = l >> 4;
  // A fragments: 2 m-tiles x 8 k-slices from LDS (swizzle-matched)
  short8_t af[2][8];
#pragma unroll
  for (int mt = 0; mt < 2; mt++)
#pragma unroll
    for (int ks = 0; ks < 8; ks++)
      af[mt][ks] = *(const short8_t*)&ldsA[(mt * 16 + lr) * 256 +
                                           (((ks * 4 + lg) ^ (lr & 7)) * 8)];

  int nphase = isQ ? 1 : 2;
  for (int ph = 0; ph < nphase; ph++) {
    const short* Bt = isQ ? Wqt : (Wkvt + ph * 65536);
    f32x4 acc[2][4] = {};
#pragma unroll
    for (int ct = 0; ct < 4; ct++) {
      const short* br = Bt + (size_t)(w * 64 + ct * 16 + lr) * 256 + lg * 8;
      short8_t bfr[8];
#pragma unroll
      for (int ks = 0; ks < 8; ks++) bfr[ks] = *(const short8_t*)(br + ks * 32);
      if (ph == 0) {
#pragma unroll
        for (int ks = 0; ks < 8; ks++) {
          acc[0][ct] = __builtin_amdgcn_mfma_f32_16x16x32_bf16(af[0][ks], bfr[ks], acc[0][ct], 0, 0, 0);
          acc[1][ct] = __builtin_amdgcn_mfma_f32_16x16x32_bf16(af[1][ks], bfr[ks], acc[1][ct], 0, 0, 0);
        }
      } else {  // swapped operands: acc rows <-> channel, cols <-> m
#pragma unroll
        for (int ks = 0; ks < 8; ks++) {
          acc[0][ct] = __builtin_amdgcn_mfma_f32_16x16x32_bf16(bfr[ks], af[0][ks], acc[0][ct], 0, 0, 0);
          acc[1][ct] = __builtin_amdgcn_mfma_f32_16x16x32_bf16(bfr[ks], af[1][ks], acc[1][ct], 0, 0, 0);
        }
      }
    }
    if (ph == 0) {
      short* Ob = isQ ? Qb : Kb;
#pragma unroll
      for (int ct = 0; ct < 4; ct++) {
        int c = w * 64 + ct * 16 + lr;
        int h = c >> 6, dd = c & 63;
#pragma unroll
        for (int mt = 0; mt < 2; mt++)
#pragma unroll
          for (int r = 0; r < 4; r++) {
            int m = m0 + mt * 16 + lg * 4 + r;
            int bb = m >> 11, n = m & 2047;
            Ob[(size_t)(((bb << 2) + h) * NSEQ + n) * 64 + dd] =
                f2bf_hw(acc[mt][ct][r]);
          }
      }
    } else {
#pragma unroll
      for (int ct = 0; ct < 4; ct++) {
        int c = w * 64 + ct * 16 + lg * 4;
#pragma unroll
        for (int mt = 0; mt < 2; mt++) {
          int m = m0 + mt * 16 + lr;
          int bb = m >> 11, n = m & 2047;
#pragma unroll
          for (int r = 0; r < 4; r++) {
            int cc = c + r;
            int h = cc >> 6, dd = cc & 63;
            Vtb[(size_t)(((bb << 2) + h) * 64 + dd) * NSEQ + n] =
                f2bf_hw(acc[mt][ct][r]);
          }
        }
      }
    }
  }
}

// ---------------------------------------------------------- flash attention
// Swapped-operand: S^T = mfma(K, Q) (lane owns one q), O^T = mfma(V, P).
// grid (32*NS, 16), 4 waves; wave: 16 q rows, KBLK=64, KITER=32/NS.
// LDS 32KB: K dbuf 16K + V single 8K + P 8K -> 5 blocks/CU.
// Counted vmcnt + raw s_barrier (prefetch never drained in-loop).
template <int NS>
__global__ __launch_bounds__(256, 5) void flash_attn_split(
    const short* __restrict__ Qb, const short* __restrict__ Kb,
    const short* __restrict__ Vt, float* __restrict__ AOt,
    short* __restrict__ O1a, short* __restrict__ O1b,
    short* __restrict__ O1c, float* __restrict__ ML) {
  constexpr int KITER = 32 / NS;
  __shared__ __align__(16) short ldsK[2][4096];
  __shared__ __align__(16) short ldsV[4096];
  __shared__ __align__(16) short ldsP[4][1024];
  int tid = threadIdx.x;
  int w = tid >> 6, l = tid & 63, lr = l & 15, lg = l >> 4;
  int bh = blockIdx.y;
  int qt = blockIdx.x / NS, split = blockIdx.x % NS;
  int q0 = qt * 64 + w * 16;
  const short* qptr = Qb + ((size_t)bh * NSEQ + q0 + lr) * 64 + lg * 8;
  short8_t qf0 = *(const short8_t*)qptr;
  short8_t qf1 = *(const short8_t*)(qptr + 32);
  const short* kbase = Kb + (size_t)bh * NSEQ * 64;  // [n][64]
  const short* vbase = Vt + (size_t)bh * 64 * NSEQ;  // [d][2048]

  // staging: 512 chunks of 16B per tile; thread covers chunks tid and tid+256.
  int r0 = tid >> 3, ch0 = (tid & 7) ^ (r0 & 7);
  int kb0 = split * KITER;
  const short* ksrc = kbase + (size_t)kb0 * 4096 + (size_t)r0 * 64 + ch0 * 8;
  const short* vsrc = vbase + (size_t)r0 * NSEQ + kb0 * 64 + ch0 * 8;
  short* ldKw0 = &ldsK[0][0] + w * 512;
  short* ldKw1 = &ldsK[1][0] + w * 512;
  short* ldVw = &ldsV[0] + w * 512;

#define STAGE_K(dst_, it_)                                  \
  {                                                         \
    const short* s_ = ksrc + (size_t)(it_) * 4096;          \
    gload_lds16(s_, dst_);                                  \
    gload_lds16(s_ + 2048, (dst_) + 2048);                  \
  }
#define STAGE_V(it_)                                        \
  {                                                         \
    const short* s_ = vsrc + (size_t)(it_) * 64;            \
    gload_lds16(s_, ldVw);                                  \
    gload_lds16(s_ + 32 * NSEQ, ldVw + 2048);               \
  }

  f32x4 o[4] = {};
  float osum = 0.f, m2 = -1e30f;
  const float C = 0.125f * 1.44269504089f;  // SCALE * log2(e)

  int sw = lr & 7;
  int rdA = (lg ^ sw) * 8;
  int rdB = ((lg + 4) ^ sw) * 8;
  short* Pw = &ldsP[w][0];
  int gh = lg >> 1, gb = lg & 1;
  short* addrPa = Pw + lr * 64 + ((0 + gh) ^ sw) * 8 + 4 * gb;
  short* addrPb = Pw + lr * 64 + ((2 + gh) ^ sw) * 8 + 4 * gb;
  short* addrPc = Pw + lr * 64 + ((4 + gh) ^ sw) * 8 + 4 * gb;
  short* addrPd = Pw + lr * 64 + ((6 + gh) ^ sw) * 8 + 4 * gb;
  const short* paddr0 = Pw + lr * 64 + ((lg) ^ sw) * 8;
  const short* paddr1 = Pw + lr * 64 + ((4 + lg) ^ sw) * 8;

  STAGE_K(ldKw0, 0);
  STAGE_V(0);
  asm volatile("s_waitcnt vmcnt(0)" ::: "memory");
  __builtin_amdgcn_s_barrier();

  for (int i = 0; i < KITER; i++) {
    if (i + 1 < KITER) {
      short* d_ = (i & 1) ? ldKw0 : ldKw1;
      STAGE_K(d_, i + 1);
    }
    const short* lK = (i & 1) ? &ldsK[1][0] : &ldsK[0][0];
    // S^T = K · Q^T  (lane: q-col = lr, kv-row = t*16 + lg*4 + r)
    f32x4 s[4];
#pragma unroll
    for (int t = 0; t < 4; t++) {
      const short* kr = lK + (t * 16 + lr) * 64;
      short8_t kf0 = *(const short8_t*)(kr + rdA);
      short8_t kf1 = *(const short8_t*)(kr + rdB);
      f32x4 z = {0.f, 0.f, 0.f, 0.f};
      z = __builtin_amdgcn_mfma_f32_16x16x32_bf16(kf0, qf0, z, 0, 0, 0);
      s[t] = __builtin_amdgcn_mfma_f32_16x16x32_bf16(kf1, qf1, s[0] * 0.f + z, 0, 0, 0);
    }
    // per-lane softmax over this tile's 64 kv (16 local + 2 shfl)
    f32x4 m4 = vmax4(vmax4(s[0], s[1]), vmax4(s[2], s[3]));
    float mx = fmaxf(fmaxf(m4[0], m4[1]), fmaxf(m4[2], m4[3]));
    mx = fmaxf(mx, __shfl_xor(mx, 16));
    mx = fmaxf(mx, __shfl_xor(mx, 32));
    mx *= C;
    float mnew = fmaxf(m2, mx);
    if (__any(mnew - m2 > 8.f)) {
      float alpha = __builtin_amdgcn_exp2f(m2 - mnew);
      m2 = mnew;
      osum *= alpha;
#pragma unroll
      for (int dt = 0; dt < 4; dt++) o[dt] *= alpha;
    }
    // P = exp2(s*C - m2); pack to bf16 pairs; write P[q][kv] (swizzled)
    float psum = 0.f;
#pragma unroll
    for (int t = 0; t < 4; t++) {
      float p0 = __builtin_amdgcn_exp2f(__builtin_fmaf(s[t][0], C, -m2));
      float p1 = __builtin_amdgcn_exp2f(__builtin_fmaf(s[t][1], C, -m2));
      float p2 = __builtin_amdgcn_exp2f(__builtin_fmaf(s[t][2], C, -m2));
      float p3 = __builtin_amdgcn_exp2f(__builtin_fmaf(s[t][3], C, -m2));
      psum += (p0 + p1) + (p2 + p3);
      unsigned ulo = pkbf(p0, p1);
      unsigned uhi = pkbf(p2, p3);
      short* ap = (t == 0) ? addrPa : (t == 1) ? addrPb : (t == 2) ? addrPc : addrPd;
      *(unsigned*)ap = ulo;
      *(unsigned*)(ap + 2) = uhi;
    }
    osum += psum;  // per-lane partial; cross-group reduce deferred to epilogue
    short8_t pB0 = *(const short8_t*)paddr0;
    short8_t pB1 = *(const short8_t*)paddr1;
    // V tile ready (issued prev iter tail / prologue); K(i+1) stays in flight
    if (i + 1 < KITER)
      asm volatile("s_waitcnt vmcnt(2)" ::: "memory");
    else
      asm volatile("s_waitcnt vmcnt(0)" ::: "memory");
    __builtin_amdgcn_s_barrier();
    // O^T += V^T · P^T
#pragma unroll
    for (int dt = 0; dt < 4; dt++) {
      const short* vr = &ldsV[0] + (dt * 16 + lr) * 64;
      short8_t vf0 = *(const short8_t*)(vr + rdA);
      short8_t vf1 = *(const short8_t*)(vr + rdB);
      o[dt] = __builtin_amdgcn_mfma_f32_16x16x32_bf16(vf0, pB0, o[dt], 0, 0, 0);
      o[dt] = __builtin_amdgcn_mfma_f32_16x16x32_bf16(vf1, pB1, o[dt], 0, 0, 0);
    }
    __builtin_amdgcn_s_barrier();  // all waves done with V tile
    if (i + 1 < KITER) {
      STAGE_V(i + 1);
      asm volatile("s_waitcnt vmcnt(2)" ::: "memory");  // K(i+1) landed
      __builtin_amdgcn_s_barrier();
    }
  }
#undef STAGE_K
#undef STAGE_V
  osum += __shfl_xor(osum, 16);
  osum += __shfl_xor(osum, 32);
  float inv = __builtin_amdgcn_rcpf(osum);
  if (split == 0) {
#pragma unroll
    for (int dt = 0; dt < 4; dt++)
#pragma unroll
      for (int r = 0; r < 4; r++)
        AOt[((size_t)bh * 64 + dt * 16 + lg * 4 + r) * NSEQ + q0 + lr] =
            o[dt][r] * inv;
  } else {
    short* op = (split == 1) ? O1a : (split == 2) ? O1b : O1c;
#pragma unroll
    for (int dt = 0; dt < 4; dt++)
#pragma unroll
      for (int r = 0; r < 4; r++)
        op[((size_t)bh * 64 + dt * 16 + lg * 4 + r) * NSEQ + q0 + lr] =
            f2bf(o[dt][r] * inv);
  }
  if (lg == 0) {
    float2 v = {m2, osum};
    *(float2*)&ML[((size_t)bh * NSEQ + q0 + lr) * 8 + split * 2] = v;
  }
}

// ------------------------------------------- merge the kv-split partials (in AOt)
template <int NS>
__global__ __launch_bounds__(256) void flash_combine(
    float* __restrict__ AOt, const short* __restrict__ O1a,
    const short* __restrict__ O1b, const short* __restrict__ O1c,
    const float* __restrict__ ML) {
  int row = blockIdx.x;  // bh*64 + d
  int bh = row >> 6;
  int nb = threadIdx.x * 8;
  size_t base = (size_t)row * NSEQ + nb;
  const float* mlb = ML + ((size_t)bh * NSEQ + nb) * 8;
  float oin[8];
  *(f32x4*)&oin[0] = *(const f32x4*)(AOt + base);
  *(f32x4*)&oin[4] = *(const f32x4*)(AOt + base + 4);
  short8_t s1 = *(const short8_t*)(O1a + base);
  short8_t s2v = {}, s3v = {};
  if (NS == 4) {
    s2v = *(const short8_t*)(O1b + base);
    s3v = *(const short8_t*)(O1c + base);
  }
  float out[8];
#pragma unroll
  for (int j = 0; j < 8; j++) {
    const float* ml = mlb + j * 8;
    f32x4 a = *(const f32x4*)ml;  // m0,s0,m1,s1
    if (NS == 2) {
      float M = fmaxf(a[0], a[2]);
      float w0 = a[1] * __builtin_amdgcn_exp2f(a[0] - M);
      float w1 = a[3] * __builtin_amdgcn_exp2f(a[2] - M);
      float iv = __builtin_amdgcn_rcpf(w0 + w1);
      out[j] = (oin[j] * w0 + bf2f(s1[j]) * w1) * iv;
    } else {
      f32x4 b = *(const f32x4*)(ml + 4);  // m2,s2,m3,s3
      float M = fmaxf(fmaxf(a[0], a[2]), fmaxf(b[0], b[2]));
      float w0 = a[1] * __builtin_amdgcn_exp2f(a[0] - M);
      float w1 = a[3] * __builtin_amdgcn_exp2f(a[2] - M);
      float w2 = b[1] * __builtin_amdgcn_exp2f(b[0] - M);
      float w3 = b[3] * __builtin_amdgcn_exp2f(b[2] - M);
      float iv = __builtin_amdgcn_rcpf(w0 + w1 + w2 + w3);
      out[j] = (oin[j] * w0 + bf2f(s1[j]) * w1 + bf2f(s2v[j]) * w2 +
                bf2f(s3v[j]) * w3) * iv;
    }
  }
  *(f32x4*)(AOt + base) = *(const f32x4*)&out[0];
  *(f32x4*)(AOt + base + 4) = *(const f32x4*)&out[4];
}

// ---------------------------------------- lam energy via MFMA (AOt rows, direct)
__global__ __launch_bounds__(256) void energy_mfma(
    const float* __restrict__ AOt, float* __restrict__ partials) {
  __shared__ __align__(16) short tileT[64][128];  // [dd][m], chunk-swizzled
  int tid = threadIdx.x;
  int b = blockIdx.y, kc = blockIdx.x;  // kc = h*16 + nblk
  int h = kc >> 4, n0 = (kc & 15) * 128;
  const float* src = AOt + ((size_t)((b << 2) + h) * 64) * NSEQ + n0;
  int row = tid >> 2, c0 = (tid & 3) * 32;
  const float* sp = src + (size_t)row * NSEQ + c0;
  int rsw = row & 15;
  short* trow = &tileT[row][0];
#pragma unroll
  for (int i = 0; i < 4; i++) {
    f32x4 v0 = *(const f32x4*)(sp + i * 8);
    f32x4 v1 = *(const f32x4*)(sp + i * 8 + 4);
    int ch = ((c0 >> 3) + i) ^ rsw;
    unsigned* dst = (unsigned*)(trow + ch * 8);
    dst[0] = pkbf(v0[0], v0[1]);
    dst[1] = pkbf(v0[2], v0[3]);
    dst[2] = pkbf(v1[0], v1[1]);
    dst[3] = pkbf(v1[2], v1[3]);
  }
  __syncthreads();
  int w = tid >> 6, lr = tid & 15, lg = (tid & 63) >> 4;
  f32x4 acc[4] = {};
#pragma unroll
  for (int ks = 0; ks < 4; ks++) {
    short8_t af = *(const short8_t*)&tileT[w * 16 + lr][((ks * 4 + lg) ^ lr) * 8];
#pragma unroll
    for (int e = 0; e < 4; e++) {
      short8_t bf = *(const short8_t*)&tileT[e * 16 + lr][((ks * 4 + lg) ^ lr) * 8];
      acc[e] = __builtin_amdgcn_mfma_f32_16x16x32_bf16(af, bf, acc[e], 0, 0, 0);
    }
  }
  float* dst = partials + ((size_t)b * 64 + kc) * 4096;
#pragma unroll
  for (int e = 0; e < 4; e++)
#pragma unroll
    for (int r = 0; r < 4; r++)
      dst[(w * 16 + lg * 4 + r) * 64 + e * 16 + lr] = acc[e][r];
}

// -------------------------------- reduce partials over kc + channel softmax
__global__ __launch_bounds__(64) void energy_reduce_softmax(
    const float* __restrict__ partials, float* __restrict__ attnc) {
  int row = blockIdx.x;  // b*64 + d
  int b = row >> 6, d = row & 63;
  int e = threadIdx.x;
  const float* src = partials + (size_t)b * 64 * 4096 + d * 64 + e;
  float s = 0.f;
#pragma unroll 8
  for (int kc = 0; kc < 64; kc++) s += src[(size_t)kc * 4096];
  float mx = s;
#pragma unroll
  for (int x = 1; x < 64; x <<= 1) mx = fmaxf(mx, __shfl_xor(mx, x, 64));
  float ev = __expf(s - mx);
  float sum = ev;
#pragma unroll
  for (int x = 1; x < 64; x <<= 1) sum += __shfl_xor(sum, x, 64);
  attnc[row * 64 + e] = ev / sum;
}

// ------------------------------------- lam apply + residuals + bf16 x assembly
__global__ __launch_bounds__(256) void assemble_x(
    const float* __restrict__ AOt, const float* __restrict__ attnc,
    const float* __restrict__ t2, const short* __restrict__ Qb,
    const float* __restrict__ gamma, short* __restrict__ Xf) {
  __shared__ f32x4 At4[1024];
  int b = blockIdx.y, tid = threadIdx.x;
  const f32x4* ac = (const f32x4*)(attnc + (size_t)b * 4096);
#pragma unroll
  for (int i = 0; i < 4; i++) At4[i * 256 + tid] = ac[i * 256 + tid];
  __syncthreads();
  int rowb = blockIdx.x * 256 + tid;
  int h = rowb >> 11, n = rowb & 2047;
  float g = gamma[0];
  const float* xop = AOt + ((size_t)((b << 2) + h) * 64) * NSEQ + n;
  f32x4 xv[16];
#pragma unroll
  for (int i = 0; i < 16; i++) {
    f32x4 t;
    t[0] = xop[(size_t)(4 * i + 0) * NSEQ];
    t[1] = xop[(size_t)(4 * i + 1) * NSEQ];
    t[2] = xop[(size_t)(4 * i + 2) * NSEQ];
    t[3] = xop[(size_t)(4 * i + 3) * NSEQ];
    xv[i] = t;
  }
  const short* qp = Qb + ((size_t)b * 8192 + rowb) * 64;
  const float* t2p = t2 + ((size_t)b * 2048 + n) * 256 + h * 64;
  short* xfp = Xf + ((size_t)b * 2048 + n) * 256 + h * 64;
#pragma unroll
  for (int dd = 0; dd < 64; dd++) {
    f32x4 a = {0.f, 0.f, 0.f, 0.f};
#pragma unroll
    for (int j = 0; j < 16; j++) a += At4[dd * 16 + j] * xv[j];
    float o = a[0] + a[1] + a[2] + a[3];
    float xdd = xv[dd >> 2][dd & 3];
    float val = t2p[dd] + g * o + xdd + bf2f(qp[dd]);
    xfp[dd] = f2bf(val);
  }
}

// -------------------------------------------------- final projection + bias
__global__ __launch_bounds__(256) void gemm_proj(
    const short* __restrict__ Xf, const short* __restrict__ Wpt,
    const float* __restrict__ bias, float* __restrict__ out) {
  int w = threadIdx.x >> 6, l = threadIdx.x & 63, lr = l & 15, lg = l >> 4;
  int m0 = blockIdx.x * 64 + w * 16;
  int n0 = blockIdx.y * 64;
  short8_t af[8];
  const short* ar = Xf + (size_t)(m0 + lr) * 256 + lg * 8;
#pragma unroll
  for (int ks = 0; ks < 8; ks++) af[ks] = *(const short8_t*)(ar + ks * 32);
  for (int ct = 0; ct < 4; ct++) {
    f32x4 acc = {0.f, 0.f, 0.f, 0.f};
    const short* br = Wpt + (size_t)(n0 + ct * 16 + lr) * 256 + lg * 8;
#pragma unroll
    for (int ks = 0; ks < 8; ks++) {
      short8_t bf = *(const short8_t*)(br + ks * 32);
      acc = __builtin_amdgcn_mfma_f32_16x16x32_bf16(af[ks], bf, acc, 0, 0, 0);
    }
    int c = n0 + ct * 16 + lr;
    float bc = bias[c];
#pragma unroll
    for (int r = 0; r < 4; r++) {
      int m = m0 + lg * 4 + r;
      out[(size_t)m * 256 + c] = acc[r] + bc;
    }
  }
}

extern "C" void kernel_launch(void* const* d_in, const int* in_sizes, int n_in,
                              void* d_out, int out_size, void* d_ws, size_t ws_size,
                              hipStream_t stream) {
  const float* t2 = (const float*)d_in[0];
  const float* t1 = (const float*)d_in[1];
  const float* Wq = (const float*)d_in[2];
  const float* Wkv = (const float*)d_in[3];
  const float* Wp = (const float*)d_in[4];
  const float* bproj = (const float*)d_in[5];
  const float* gamma = (const float*)d_in[6];
  float* out = (float*)d_out;
  char* ws = (char*)d_ws;

  const size_t MB = 1024ull * 1024ull;
  short* Qb = (short*)(ws + 0);
  short* Kb = (short*)(ws + 4 * MB);
  float* partials = (float*)(ws + 4 * MB);  // aliases Kb (dead after flash)
  short* Vt = (short*)(ws + 8 * MB);
  short* Xf = (short*)(ws + 12 * MB);
  short* O1a = (short*)(ws + 12 * MB);      // aliases Xf (dead until assemble_x)
  float* AOt = (float*)(ws + 16 * MB);
  short* Wqt = (short*)(ws + 24 * MB);
  short* Wkvt = (short*)(ws + 24 * MB + 128 * 1024);
  short* Wpt = (short*)(ws + 24 * MB + 384 * 1024);
  float* attnc = (float*)(ws + 24 * MB + 512 * 1024);
  float* ML = (float*)(ws + 24 * MB + 576 * 1024);  // 1 MB
  short* O1b = (short*)(ws + 26 * MB);
  short* O1c = (short*)(ws + 30 * MB);

  bool big = ws_size >= 34 * MB;

  wconv<<<1024, 256, 0, stream>>>(Wq, Wkv, Wp, Wqt, Wkvt, Wpt);
  gemm_qkv2<<<dim3(256, 2), 256, 0, stream>>>(t2, t1, Wqt, Wkvt, Qb, Kb, Vt);
  if (big) {
    flash_attn_split<4><<<dim3(128, 16), 256, 0, stream>>>(Qb, Kb, Vt, AOt, O1a,
                                                           O1b, O1c, ML);
    flash_combine<4><<<1024, 256, 0, stream>>>(AOt, O1a, O1b, O1c, ML);
  } else {
    flash_attn_split<2><<<dim3(64, 16), 256, 0, stream>>>(Qb, Kb, Vt, AOt, O1a,
                                                          O1a, O1a, ML);
    flash_combine<2><<<1024, 256, 0, stream>>>(AOt, O1a, O1a, O1a, ML);
  }
  energy_mfma<<<dim3(64, 4), 256, 0, stream>>>(AOt, partials);
  energy_reduce_softmax<<<256, 64, 0, stream>>>(partials, attnc);
  assemble_x<<<dim3(32, 4), 256, 0, stream>>>(AOt, attnc, t2, Qb, gamma, Xf);
  gemm_proj<<<dim3(128, 4), 256, 0, stream>>>(Xf, Wpt, bproj, out);
}

// Round 8
// 111.549 us; speedup vs baseline: 2.5531x; 1.0294x over previous
//
#include <hip/hip_runtime.h>
#include <hip/hip_bf16.h>

// Problem: B=4, N=2048, C=256, H=4, d=64
// Pipeline: wconv -> gemm_qkv2(y=0:q, y=1:k+v fused) -> flash_attn_split<NS>
//           (swapped-operand, 32q/wave, O^T out) -> flash_combine<NS> ->
//           energy_mfma -> energy_reduce_softmax -> assemble_x -> gemm_proj
// Workspace layout (bytes):
//   Qb   bf16 [16][2048][64]   @ 0        (4 MB)
//   Kb   bf16 [16][2048][64]   @ 4 MB     (4 MB)  (aliased by partials after flash)
//   Vt   bf16 [16][64][2048]   @ 8 MB     (4 MB)
//   Xf   bf16 [8192][256]      @ 12 MB    (4 MB)  (aliased by O1a before assemble)
//   AOt  f32  [16][64][2048]   @ 16 MB    (8 MB)  TRANSPOSED attention out
//   Wqt/Wkvt/Wpt/attnc/ML      @ 24 MB .. 25.6 MB
//   O1b/O1c bf16 (4-split only)@ 26 MB / 30 MB (needs ws >= 34 MB)

typedef __attribute__((ext_vector_type(8))) short short8_t;
typedef __attribute__((ext_vector_type(4))) float f32x4;
typedef __attribute__((ext_vector_type(2))) unsigned u32x2;

#define NSEQ 2048

static __device__ __forceinline__ short f2bf(float f) {
  union { float f; unsigned u; } v; v.f = f;
  unsigned u = v.u;
  unsigned r = (u + 0x7FFFu + ((u >> 16) & 1u)) >> 16;
  return (short)r;
}
static __device__ __forceinline__ float bf2f(short s) {
  union { unsigned u; float f; } v;
  v.u = ((unsigned)(unsigned short)s) << 16;
  return v.f;
}
static __device__ __forceinline__ unsigned bcu(float f) {
  return __builtin_bit_cast(unsigned, f);
}
// pack two f32 into u32 of 2 bf16 (truncation) via v_perm_b32
static __device__ __forceinline__ unsigned pkbf(float lo, float hi) {
  return __builtin_amdgcn_perm(bcu(hi), bcu(lo), 0x07060302u);
}
// hardware RNE f32->bf16
static __device__ __forceinline__ short f2bf_hw(float f) {
  __hip_bfloat16 h = __float2bfloat16(f);
  return __builtin_bit_cast(short, h);
}
static __device__ __forceinline__ unsigned pk2bf_hw(float a, float b) {
  return ((unsigned)(unsigned short)__builtin_bit_cast(short, __float2bfloat16(b)) << 16) |
         (unsigned short)__builtin_bit_cast(short, __float2bfloat16(a));
}
static __device__ __forceinline__ f32x4 vmax4(f32x4 a, f32x4 b) {
  f32x4 r;
  r[0] = fmaxf(a[0], b[0]); r[1] = fmaxf(a[1], b[1]);
  r[2] = fmaxf(a[2], b[2]); r[3] = fmaxf(a[3], b[3]);
  return r;
}

// async global->LDS, 16B per lane; lds base must be wave-uniform.
static __device__ __forceinline__ void gload_lds16(const short* src, short* ldst) {
  __builtin_amdgcn_global_load_lds(
      (const __attribute__((address_space(1))) unsigned*)src,
      (__attribute__((address_space(3))) unsigned*)ldst, 16, 0, 0);
}

// ---------------------------------------------------------------- weights
__global__ __launch_bounds__(256) void wconv(
    const float* __restrict__ Wq, const float* __restrict__ Wkv,
    const float* __restrict__ Wp, short* __restrict__ Wqt,
    short* __restrict__ Wkvt, short* __restrict__ Wpt) {
  int tid = blockIdx.x * 256 + threadIdx.x;
  if (tid < 65536) {
    int n = tid >> 8, k = tid & 255;
    Wqt[tid] = f2bf(Wq[k * 256 + n]);
  } else if (tid < 196608) {
    int i = tid - 65536;
    int n = i >> 8, k = i & 255;
    Wkvt[i] = f2bf(Wkv[k * 512 + n]);
  } else {
    int i = tid - 196608;
    int n = i >> 8, k = i & 255;
    Wpt[i] = f2bf(Wp[k * 256 + n]);
  }
}

// ---------------------------- QKV projection: LDS-staged A, 32 rows per block
__global__ __launch_bounds__(256) void gemm_qkv2(
    const float* __restrict__ t2, const float* __restrict__ t1,
    const short* __restrict__ Wqt, const short* __restrict__ Wkvt,
    short* __restrict__ Qb, short* __restrict__ Kb, short* __restrict__ Vtb) {
  __shared__ __align__(16) short ldsA[32 * 256];  // 16 KB, chunk-swizzled
  int tid = threadIdx.x;
  int m0 = blockIdx.x * 32;
  bool isQ = (blockIdx.y == 0);
  const float* A = isQ ? t2 : t1;

  const float* ap = A + (size_t)m0 * 256;
#pragma unroll
  for (int i = 0; i < 8; i++) {
    int idx = i * 256 + tid;
    int row = idx >> 6, c4 = idx & 63;
    f32x4 v = *(const f32x4*)(ap + (size_t)idx * 4);
    int ch8 = c4 >> 1, half = c4 & 1;
    int swz = ch8 ^ (row & 7);
    unsigned* dst = (unsigned*)&ldsA[row * 256 + swz * 8 + half * 4];
    dst[0] = pk2bf_hw(v[0], v[1]);
    dst[1] = pk2bf_hw(v[2], v[3]);
  }
  __syncthreads();

  int w = tid >> 6, l = tid & 63, lr = l & 15, lg = l >> 4;
  short8_t af[2][8];
#pragma unroll
  for (int mt = 0; mt < 2; mt++)
#pragma unroll
    for (int ks = 0; ks < 8; ks++)
      af[mt][ks] = *(const short8_t*)&ldsA[(mt * 16 + lr) * 256 +
                                           (((ks * 4 + lg) ^ (lr & 7)) * 8)];

  int nphase = isQ ? 1 : 2;
  for (int ph = 0; ph < nphase; ph++) {
    const short* Bt = isQ ? Wqt : (Wkvt + ph * 65536);
    f32x4 acc[2][4] = {};
#pragma unroll
    for (int ct = 0; ct < 4; ct++) {
      const short* br = Bt + (size_t)(w * 64 + ct * 16 + lr) * 256 + lg * 8;
      short8_t bfr[8];
#pragma unroll
      for (int ks = 0; ks < 8; ks++) bfr[ks] = *(const short8_t*)(br + ks * 32);
      if (ph == 0) {
#pragma unroll
        for (int ks = 0; ks < 8; ks++) {
          acc[0][ct] = __builtin_amdgcn_mfma_f32_16x16x32_bf16(af[0][ks], bfr[ks], acc[0][ct], 0, 0, 0);
          acc[1][ct] = __builtin_amdgcn_mfma_f32_16x16x32_bf16(af[1][ks], bfr[ks], acc[1][ct], 0, 0, 0);
        }
      } else {
#pragma unroll
        for (int ks = 0; ks < 8; ks++) {
          acc[0][ct] = __builtin_amdgcn_mfma_f32_16x16x32_bf16(bfr[ks], af[0][ks], acc[0][ct], 0, 0, 0);
          acc[1][ct] = __builtin_amdgcn_mfma_f32_16x16x32_bf16(bfr[ks], af[1][ks], acc[1][ct], 0, 0, 0);
        }
      }
    }
    if (ph == 0) {
      short* Ob = isQ ? Qb : Kb;
#pragma unroll
      for (int ct = 0; ct < 4; ct++) {
        int c = w * 64 + ct * 16 + lr;
        int h = c >> 6, dd = c & 63;
#pragma unroll
        for (int mt = 0; mt < 2; mt++)
#pragma unroll
          for (int r = 0; r < 4; r++) {
            int m = m0 + mt * 16 + lg * 4 + r;
            int bb = m >> 11, n = m & 2047;
            Ob[(size_t)(((bb << 2) + h) * NSEQ + n) * 64 + dd] =
                f2bf_hw(acc[mt][ct][r]);
          }
      }
    } else {
#pragma unroll
      for (int ct = 0; ct < 4; ct++) {
        int c = w * 64 + ct * 16 + lg * 4;
#pragma unroll
        for (int mt = 0; mt < 2; mt++) {
          int m = m0 + mt * 16 + lr;
          int bb = m >> 11, n = m & 2047;
#pragma unroll
          for (int r = 0; r < 4; r++) {
            int cc = c + r;
            int h = cc >> 6, dd = cc & 63;
            Vtb[(size_t)(((bb << 2) + h) * 64 + dd) * NSEQ + n] =
                f2bf_hw(acc[mt][ct][r]);
          }
        }
      }
    }
  }
}

// ---------------------------------------------------------- flash attention
// Swapped-operand, 32 q/wave: S^T = mfma(K, Q{A,B}), O^T = mfma(V, P{A,B}).
// Per wave-iter: 20 ds_read_b128 feed 32 MFMAs (was 18/16).
// grid (16*NS, 16), 4 waves; wave: 32 q rows, KBLK=64, KITER=32/NS.
// LDS 40KB (Kdbuf16 + V8 + P16) -> 4 blocks/CU; launch_bounds caps VGPR=128.
// 2 barriers/iter, counted vmcnt: V staged at iter start (hidden under QK),
// K prefetch never drained in-loop.
template <int NS>
__global__ __launch_bounds__(256, 4) void flash_attn_split(
    const short* __restrict__ Qb, const short* __restrict__ Kb,
    const short* __restrict__ Vt, float* __restrict__ AOt,
    short* __restrict__ O1a, short* __restrict__ O1b,
    short* __restrict__ O1c, float* __restrict__ ML) {
  constexpr int KITER = 32 / NS;
  __shared__ __align__(16) short ldsK[2][4096];
  __shared__ __align__(16) short ldsV[4096];
  __shared__ __align__(16) short ldsP[4][2048];  // [w][32 q rows][64 kv]
  int tid = threadIdx.x;
  int w = tid >> 6, l = tid & 63, lr = l & 15, lg = l >> 4;
  int bh = blockIdx.y;
  int qt = blockIdx.x / NS, split = blockIdx.x % NS;
  int q0 = qt * 128 + w * 32;
  const short* qpA = Qb + ((size_t)bh * NSEQ + q0 + lr) * 64 + lg * 8;
  const short* qpB = qpA + 16 * 64;
  short8_t qfA0 = *(const short8_t*)qpA;
  short8_t qfA1 = *(const short8_t*)(qpA + 32);
  short8_t qfB0 = *(const short8_t*)qpB;
  short8_t qfB1 = *(const short8_t*)(qpB + 32);
  const short* kbase = Kb + (size_t)bh * NSEQ * 64;  // [n][64]
  const short* vbase = Vt + (size_t)bh * 64 * NSEQ;  // [d][2048]

  // staging: 512 chunks of 16B per 8KB tile; thread covers chunk tid (+256).
  int r0 = tid >> 3, ch0 = (tid & 7) ^ (r0 & 7);
  int kb0 = split * KITER;
  const short* ksrc = kbase + (size_t)kb0 * 4096 + (size_t)r0 * 64 + ch0 * 8;
  const short* vsrc = vbase + (size_t)r0 * NSEQ + kb0 * 64 + ch0 * 8;
  short* ldKw0 = &ldsK[0][0] + w * 512;
  short* ldKw1 = &ldsK[1][0] + w * 512;
  short* ldVw = &ldsV[0] + w * 512;

#define STAGE_K(dst_, it_)                                  \
  {                                                         \
    const short* s_ = ksrc + (size_t)(it_) * 4096;          \
    gload_lds16(s_, dst_);                                  \
    gload_lds16(s_ + 2048, (dst_) + 2048);                  \
  }
#define STAGE_V(it_)                                        \
  {                                                         \
    const short* s_ = vsrc + (size_t)(it_) * 64;            \
    gload_lds16(s_, ldVw);                                  \
    gload_lds16(s_ + 32 * NSEQ, ldVw + 2048);               \
  }

  f32x4 oA[4] = {}, oB[4] = {};
  float osumA = 0.f, osumB = 0.f, m2A = -1e30f, m2B = -1e30f;
  const float C = 0.125f * 1.44269504089f;  // SCALE * log2(e)

  int sw = lr & 7;
  int rdA = (lg ^ sw) * 8;
  int rdB = ((lg + 4) ^ sw) * 8;
  short* Pw = &ldsP[w][0];
  // P writes: row q (lr / 16+lr), chunk (2t + (lg>>1)) ^ sw, half (lg&1)
  short* wrA = Pw + lr * 64 + (lg & 1) * 4;
  short* wrB = wrA + 16 * 64;
  int chhi = lg >> 1;
  // P reads (B-frag): row q, chunks lg and 4+lg (swizzled)
  const short* prA0 = Pw + lr * 64 + (lg ^ sw) * 8;
  const short* prA1 = Pw + lr * 64 + ((4 + lg) ^ sw) * 8;
  const short* prB0 = prA0 + 16 * 64;
  const short* prB1 = prA1 + 16 * 64;

  STAGE_K(ldKw0, 0);

  for (int i = 0; i < KITER; i++) {
    asm volatile("s_waitcnt vmcnt(0)" ::: "memory");
    __builtin_amdgcn_s_barrier();  // K(i) landed for all; V/K buffers free
    STAGE_V(i);                    // used this iter (hidden under QK+softmax)
    if (i + 1 < KITER) {
      short* d_ = (i & 1) ? ldKw0 : ldKw1;
      STAGE_K(d_, i + 1);
    }
    const short* lK = (i & 1) ? &ldsK[1][0] : &ldsK[0][0];
    // S^T = K · Q  (lane: q-col = lr (+16 for B), kv-row = t*16 + lg*4 + r)
    f32x4 sA[4], sB[4];
#pragma unroll
    for (int t = 0; t < 4; t++) {
      const short* kr = lK + (t * 16 + lr) * 64;
      short8_t kf0 = *(const short8_t*)(kr + rdA);
      short8_t kf1 = *(const short8_t*)(kr + rdB);
      f32x4 z = {0.f, 0.f, 0.f, 0.f};
      f32x4 zA = __builtin_amdgcn_mfma_f32_16x16x32_bf16(kf0, qfA0, z, 0, 0, 0);
      sA[t] = __builtin_amdgcn_mfma_f32_16x16x32_bf16(kf1, qfA1, zA, 0, 0, 0);
      f32x4 zB = __builtin_amdgcn_mfma_f32_16x16x32_bf16(kf0, qfB0, z, 0, 0, 0);
      sB[t] = __builtin_amdgcn_mfma_f32_16x16x32_bf16(kf1, qfB1, zB, 0, 0, 0);
    }
    // per-lane column softmax (16 local + 2 shfl per tile)
    f32x4 mA4 = vmax4(vmax4(sA[0], sA[1]), vmax4(sA[2], sA[3]));
    f32x4 mB4 = vmax4(vmax4(sB[0], sB[1]), vmax4(sB[2], sB[3]));
    float mxA = fmaxf(fmaxf(mA4[0], mA4[1]), fmaxf(mA4[2], mA4[3]));
    float mxB = fmaxf(fmaxf(mB4[0], mB4[1]), fmaxf(mB4[2], mB4[3]));
    mxA = fmaxf(mxA, __shfl_xor(mxA, 16));
    mxA = fmaxf(mxA, __shfl_xor(mxA, 32));
    mxB = fmaxf(mxB, __shfl_xor(mxB, 16));
    mxB = fmaxf(mxB, __shfl_xor(mxB, 32));
    mxA *= C;
    mxB *= C;
    float mnA = fmaxf(m2A, mxA), mnB = fmaxf(m2B, mxB);
    if (__any(fmaxf(mnA - m2A, mnB - m2B) > 8.f)) {
      float aA = __builtin_amdgcn_exp2f(m2A - mnA);
      float aB = __builtin_amdgcn_exp2f(m2B - mnB);
      m2A = mnA; m2B = mnB;
      osumA *= aA; osumB *= aB;
#pragma unroll
      for (int dt = 0; dt < 4; dt++) { oA[dt] *= aA; oB[dt] *= aB; }
    }
    // P = exp2(s*C - m2), truncated bf16, one b64 write per (tile, t)
    float psA = 0.f, psB = 0.f;
#pragma unroll
    for (int t = 0; t < 4; t++) {
      float a0 = __builtin_amdgcn_exp2f(__builtin_fmaf(sA[t][0], C, -m2A));
      float a1 = __builtin_amdgcn_exp2f(__builtin_fmaf(sA[t][1], C, -m2A));
      float a2 = __builtin_amdgcn_exp2f(__builtin_fmaf(sA[t][2], C, -m2A));
      float a3 = __builtin_amdgcn_exp2f(__builtin_fmaf(sA[t][3], C, -m2A));
      psA += (a0 + a1) + (a2 + a3);
      u32x2 ua = {pkbf(a0, a1), pkbf(a2, a3)};
      *(u32x2*)(wrA + ((2 * t + chhi) ^ sw) * 8) = ua;
      float b0 = __builtin_amdgcn_exp2f(__builtin_fmaf(sB[t][0], C, -m2B));
      float b1 = __builtin_amdgcn_exp2f(__builtin_fmaf(sB[t][1], C, -m2B));
      float b2 = __builtin_amdgcn_exp2f(__builtin_fmaf(sB[t][2], C, -m2B));
      float b3 = __builtin_amdgcn_exp2f(__builtin_fmaf(sB[t][3], C, -m2B));
      psB += (b0 + b1) + (b2 + b3);
      u32x2 ub = {pkbf(b0, b1), pkbf(b2, b3)};
      *(u32x2*)(wrB + ((2 * t + chhi) ^ sw) * 8) = ub;
    }
    osumA += psA;
    osumB += psB;
    short8_t pA0 = *(const short8_t*)prA0;
    short8_t pA1 = *(const short8_t*)prA1;
    short8_t pB0 = *(const short8_t*)prB0;
    short8_t pB1 = *(const short8_t*)prB1;
    // V landed? own V loads were issued before K(i+1): leave K in flight.
    if (i + 1 < KITER)
      asm volatile("s_waitcnt vmcnt(2)" ::: "memory");
    else
      asm volatile("s_waitcnt vmcnt(0)" ::: "memory");
    __builtin_amdgcn_s_barrier();  // all waves' V chunks landed
    // O^T += V · P  (vf shared across both q-tiles)
#pragma unroll
    for (int dt = 0; dt < 4; dt++) {
      const short* vr = &ldsV[0] + (dt * 16 + lr) * 64;
      short8_t vf0 = *(const short8_t*)(vr + rdA);
      short8_t vf1 = *(const short8_t*)(vr + rdB);
      oA[dt] = __builtin_amdgcn_mfma_f32_16x16x32_bf16(vf0, pA0, oA[dt], 0, 0, 0);
      oA[dt] = __builtin_amdgcn_mfma_f32_16x16x32_bf16(vf1, pA1, oA[dt], 0, 0, 0);
      oB[dt] = __builtin_amdgcn_mfma_f32_16x16x32_bf16(vf0, pB0, oB[dt], 0, 0, 0);
      oB[dt] = __builtin_amdgcn_mfma_f32_16x16x32_bf16(vf1, pB1, oB[dt], 0, 0, 0);
    }
  }
#undef STAGE_K
#undef STAGE_V
  osumA += __shfl_xor(osumA, 16);
  osumA += __shfl_xor(osumA, 32);
  osumB += __shfl_xor(osumB, 16);
  osumB += __shfl_xor(osumB, 32);
  float invA = __builtin_amdgcn_rcpf(osumA);
  float invB = __builtin_amdgcn_rcpf(osumB);
  if (split == 0) {
#pragma unroll
    for (int dt = 0; dt < 4; dt++)
#pragma unroll
      for (int r = 0; r < 4; r++) {
        size_t drow = ((size_t)bh * 64 + dt * 16 + lg * 4 + r) * NSEQ;
        AOt[drow + q0 + lr] = oA[dt][r] * invA;
        AOt[drow + q0 + 16 + lr] = oB[dt][r] * invB;
      }
  } else {
    short* op = (split == 1) ? O1a : (split == 2) ? O1b : O1c;
#pragma unroll
    for (int dt = 0; dt < 4; dt++)
#pragma unroll
      for (int r = 0; r < 4; r++) {
        size_t drow = ((size_t)bh * 64 + dt * 16 + lg * 4 + r) * NSEQ;
        op[drow + q0 + lr] = f2bf(oA[dt][r] * invA);
        op[drow + q0 + 16 + lr] = f2bf(oB[dt][r] * invB);
      }
  }
  if (lg == 0) {
    float2 vA = {m2A, osumA};
    float2 vB = {m2B, osumB};
    *(float2*)&ML[((size_t)bh * NSEQ + q0 + lr) * 8 + split * 2] = vA;
    *(float2*)&ML[((size_t)bh * NSEQ + q0 + 16 + lr) * 8 + split * 2] = vB;
  }
}

// ------------------------------------------- merge the kv-split partials (in AOt)
template <int NS>
__global__ __launch_bounds__(256) void flash_combine(
    float* __restrict__ AOt, const short* __restrict__ O1a,
    const short* __restrict__ O1b, const short* __restrict__ O1c,
    const float* __restrict__ ML) {
  int row = blockIdx.x;  // bh*64 + d
  int bh = row >> 6;
  int nb = threadIdx.x * 8;
  size_t base = (size_t)row * NSEQ + nb;
  const float* mlb = ML + ((size_t)bh * NSEQ + nb) * 8;
  float oin[8];
  *(f32x4*)&oin[0] = *(const f32x4*)(AOt + base);
  *(f32x4*)&oin[4] = *(const f32x4*)(AOt + base + 4);
  short8_t s1 = *(const short8_t*)(O1a + base);
  short8_t s2v = {}, s3v = {};
  if (NS == 4) {
    s2v = *(const short8_t*)(O1b + base);
    s3v = *(const short8_t*)(O1c + base);
  }
  float out[8];
#pragma unroll
  for (int j = 0; j < 8; j++) {
    const float* ml = mlb + j * 8;
    f32x4 a = *(const f32x4*)ml;  // m0,s0,m1,s1
    if (NS == 2) {
      float M = fmaxf(a[0], a[2]);
      float w0 = a[1] * __builtin_amdgcn_exp2f(a[0] - M);
      float w1 = a[3] * __builtin_amdgcn_exp2f(a[2] - M);
      float iv = __builtin_amdgcn_rcpf(w0 + w1);
      out[j] = (oin[j] * w0 + bf2f(s1[j]) * w1) * iv;
    } else {
      f32x4 b = *(const f32x4*)(ml + 4);  // m2,s2,m3,s3
      float M = fmaxf(fmaxf(a[0], a[2]), fmaxf(b[0], b[2]));
      float w0 = a[1] * __builtin_amdgcn_exp2f(a[0] - M);
      float w1 = a[3] * __builtin_amdgcn_exp2f(a[2] - M);
      float w2 = b[1] * __builtin_amdgcn_exp2f(b[0] - M);
      float w3 = b[3] * __builtin_amdgcn_exp2f(b[2] - M);
      float iv = __builtin_amdgcn_rcpf(w0 + w1 + w2 + w3);
      out[j] = (oin[j] * w0 + bf2f(s1[j]) * w1 + bf2f(s2v[j]) * w2 +
                bf2f(s3v[j]) * w3) * iv;
    }
  }
  *(f32x4*)(AOt + base) = *(const f32x4*)&out[0];
  *(f32x4*)(AOt + base + 4) = *(const f32x4*)&out[4];
}

// ---------------------------------------- lam energy via MFMA (AOt rows, direct)
__global__ __launch_bounds__(256) void energy_mfma(
    const float* __restrict__ AOt, float* __restrict__ partials) {
  __shared__ __align__(16) short tileT[64][128];  // [dd][m], chunk-swizzled
  int tid = threadIdx.x;
  int b = blockIdx.y, kc = blockIdx.x;  // kc = h*16 + nblk
  int h = kc >> 4, n0 = (kc & 15) * 128;
  const float* src = AOt + ((size_t)((b << 2) + h) * 64) * NSEQ + n0;
  int row = tid >> 2, c0 = (tid & 3) * 32;
  const float* sp = src + (size_t)row * NSEQ + c0;
  int rsw = row & 15;
  short* trow = &tileT[row][0];
#pragma unroll
  for (int i = 0; i < 4; i++) {
    f32x4 v0 = *(const f32x4*)(sp + i * 8);
    f32x4 v1 = *(const f32x4*)(sp + i * 8 + 4);
    int ch = ((c0 >> 3) + i) ^ rsw;
    unsigned* dst = (unsigned*)(trow + ch * 8);
    dst[0] = pkbf(v0[0], v0[1]);
    dst[1] = pkbf(v0[2], v0[3]);
    dst[2] = pkbf(v1[0], v1[1]);
    dst[3] = pkbf(v1[2], v1[3]);
  }
  __syncthreads();
  int w = tid >> 6, lr = tid & 15, lg = (tid & 63) >> 4;
  f32x4 acc[4] = {};
#pragma unroll
  for (int ks = 0; ks < 4; ks++) {
    short8_t af = *(const short8_t*)&tileT[w * 16 + lr][((ks * 4 + lg) ^ lr) * 8];
#pragma unroll
    for (int e = 0; e < 4; e++) {
      short8_t bf = *(const short8_t*)&tileT[e * 16 + lr][((ks * 4 + lg) ^ lr) * 8];
      acc[e] = __builtin_amdgcn_mfma_f32_16x16x32_bf16(af, bf, acc[e], 0, 0, 0);
    }
  }
  float* dst = partials + ((size_t)b * 64 + kc) * 4096;
#pragma unroll
  for (int e = 0; e < 4; e++)
#pragma unroll
    for (int r = 0; r < 4; r++)
      dst[(w * 16 + lg * 4 + r) * 64 + e * 16 + lr] = acc[e][r];
}

// -------------------------------- reduce partials over kc + channel softmax
__global__ __launch_bounds__(64) void energy_reduce_softmax(
    const float* __restrict__ partials, float* __restrict__ attnc) {
  int row = blockIdx.x;  // b*64 + d
  int b = row >> 6, d = row & 63;
  int e = threadIdx.x;
  const float* src = partials + (size_t)b * 64 * 4096 + d * 64 + e;
  float s = 0.f;
#pragma unroll 8
  for (int kc = 0; kc < 64; kc++) s += src[(size_t)kc * 4096];
  float mx = s;
#pragma unroll
  for (int x = 1; x < 64; x <<= 1) mx = fmaxf(mx, __shfl_xor(mx, x, 64));
  float ev = __expf(s - mx);
  float sum = ev;
#pragma unroll
  for (int x = 1; x < 64; x <<= 1) sum += __shfl_xor(sum, x, 64);
  attnc[row * 64 + e] = ev / sum;
}

// ------------------------------------- lam apply + residuals + bf16 x assembly
__global__ __launch_bounds__(256) void assemble_x(
    const float* __restrict__ AOt, const float* __restrict__ attnc,
    const float* __restrict__ t2, const short* __restrict__ Qb,
    const float* __restrict__ gamma, short* __restrict__ Xf) {
  __shared__ f32x4 At4[1024];
  int b = blockIdx.y, tid = threadIdx.x;
  const f32x4* ac = (const f32x4*)(attnc + (size_t)b * 4096);
#pragma unroll
  for (int i = 0; i < 4; i++) At4[i * 256 + tid] = ac[i * 256 + tid];
  __syncthreads();
  int rowb = blockIdx.x * 256 + tid;
  int h = rowb >> 11, n = rowb & 2047;
  float g = gamma[0];
  const float* xop = AOt + ((size_t)((b << 2) + h) * 64) * NSEQ + n;
  f32x4 xv[16];
#pragma unroll
  for (int i = 0; i < 16; i++) {
    f32x4 t;
    t[0] = xop[(size_t)(4 * i + 0) * NSEQ];
    t[1] = xop[(size_t)(4 * i + 1) * NSEQ];
    t[2] = xop[(size_t)(4 * i + 2) * NSEQ];
    t[3] = xop[(size_t)(4 * i + 3) * NSEQ];
    xv[i] = t;
  }
  const short* qp = Qb + ((size_t)b * 8192 + rowb) * 64;
  const float* t2p = t2 + ((size_t)b * 2048 + n) * 256 + h * 64;
  short* xfp = Xf + ((size_t)b * 2048 + n) * 256 + h * 64;
#pragma unroll
  for (int dd = 0; dd < 64; dd++) {
    f32x4 a = {0.f, 0.f, 0.f, 0.f};
#pragma unroll
    for (int j = 0; j < 16; j++) a += At4[dd * 16 + j] * xv[j];
    float o = a[0] + a[1] + a[2] + a[3];
    float xdd = xv[dd >> 2][dd & 3];
    float val = t2p[dd] + g * o + xdd + bf2f(qp[dd]);
    xfp[dd] = f2bf(val);
  }
}

// -------------------------------------------------- final projection + bias
__global__ __launch_bounds__(256) void gemm_proj(
    const short* __restrict__ Xf, const short* __restrict__ Wpt,
    const float* __restrict__ bias, float* __restrict__ out) {
  int w = threadIdx.x >> 6, l = threadIdx.x & 63, lr = l & 15, lg = l >> 4;
  int m0 = blockIdx.x * 64 + w * 16;
  int n0 = blockIdx.y * 64;
  short8_t af[8];
  const short* ar = Xf + (size_t)(m0 + lr) * 256 + lg * 8;
#pragma unroll
  for (int ks = 0; ks < 8; ks++) af[ks] = *(const short8_t*)(ar + ks * 32);
  for (int ct = 0; ct < 4; ct++) {
    f32x4 acc = {0.f, 0.f, 0.f, 0.f};
    const short* br = Wpt + (size_t)(n0 + ct * 16 + lr) * 256 + lg * 8;
#pragma unroll
    for (int ks = 0; ks < 8; ks++) {
      short8_t bf = *(const short8_t*)(br + ks * 32);
      acc = __builtin_amdgcn_mfma_f32_16x16x32_bf16(af[ks], bf, acc, 0, 0, 0);
    }
    int c = n0 + ct * 16 + lr;
    float bc = bias[c];
#pragma unroll
    for (int r = 0; r < 4; r++) {
      int m = m0 + lg * 4 + r;
      out[(size_t)m * 256 + c] = acc[r] + bc;
    }
  }
}

extern "C" void kernel_launch(void* const* d_in, const int* in_sizes, int n_in,
                              void* d_out, int out_size, void* d_ws, size_t ws_size,
                              hipStream_t stream) {
  const float* t2 = (const float*)d_in[0];
  const float* t1 = (const float*)d_in[1];
  const float* Wq = (const float*)d_in[2];
  const float* Wkv = (const float*)d_in[3];
  const float* Wp = (const float*)d_in[4];
  const float* bproj = (const float*)d_in[5];
  const float* gamma = (const float*)d_in[6];
  float* out = (float*)d_out;
  char* ws = (char*)d_ws;

  const size_t MB = 1024ull * 1024ull;
  short* Qb = (short*)(ws + 0);
  short* Kb = (short*)(ws + 4 * MB);
  float* partials = (float*)(ws + 4 * MB);  // aliases Kb (dead after flash)
  short* Vt = (short*)(ws + 8 * MB);
  short* Xf = (short*)(ws + 12 * MB);
  short* O1a = (short*)(ws + 12 * MB);      // aliases Xf (dead until assemble_x)
  float* AOt = (float*)(ws + 16 * MB);
  short* Wqt = (short*)(ws + 24 * MB);
  short* Wkvt = (short*)(ws + 24 * MB + 128 * 1024);
  short* Wpt = (short*)(ws + 24 * MB + 384 * 1024);
  float* attnc = (float*)(ws + 24 * MB + 512 * 1024);
  float* ML = (float*)(ws + 24 * MB + 576 * 1024);  // 1 MB
  short* O1b = (short*)(ws + 26 * MB);
  short* O1c = (short*)(ws + 30 * MB);

  bool big = ws_size >= 34 * MB;

  wconv<<<1024, 256, 0, stream>>>(Wq, Wkv, Wp, Wqt, Wkvt, Wpt);
  gemm_qkv2<<<dim3(256, 2), 256, 0, stream>>>(t2, t1, Wqt, Wkvt, Qb, Kb, Vt);
  if (big) {
    flash_attn_split<4><<<dim3(64, 16), 256, 0, stream>>>(Qb, Kb, Vt, AOt, O1a,
                                                          O1b, O1c, ML);
    flash_combine<4><<<1024, 256, 0, stream>>>(AOt, O1a, O1b, O1c, ML);
  } else {
    flash_attn_split<2><<<dim3(32, 16), 256, 0, stream>>>(Qb, Kb, Vt, AOt, O1a,
                                                          O1a, O1a, ML);
    flash_combine<2><<<1024, 256, 0, stream>>>(AOt, O1a, O1a, O1a, ML);
  }
  energy_mfma<<<dim3(64, 4), 256, 0, stream>>>(AOt, partials);
  energy_reduce_softmax<<<256, 64, 0, stream>>>(partials, attnc);
  assemble_x<<<dim3(32, 4), 256, 0, stream>>>(AOt, attnc, t2, Qb, gamma, Xf);
  gemm_proj<<<dim3(128, 4), 256, 0, stream>>>(Xf, Wpt, bproj, out);
}